// Round 5
// baseline (1452.055 us; speedup 1.0000x reference)
//
#include <hip/hip_runtime.h>
#include <cstddef>

// Problem constants
#define BATCH 8
#define LSEQ 1024
#define DMODEL 512
#define DINNER 1024
#define DSTATE 16
#define DTRANK 32
#define NHEAD 8
#define DHEAD 64
#define DFF 2048
#define MTOK 8192   // BATCH*LSEQ
#define NCHUNK 16
#define CLEN 64     // LSEQ / NCHUNK

typedef __attribute__((ext_vector_type(8))) short bfrag;          // 8 bf16 = 16 B
typedef __attribute__((ext_vector_type(4))) float f32x4;          // MFMA acc
typedef __attribute__((ext_vector_type(4))) unsigned short us4;
typedef unsigned short ushort_t;

__device__ __forceinline__ float silu_f(float x) { return x / (1.f + __expf(-x)); }

__device__ __forceinline__ unsigned short f2bf(float f) {  // RNE fp32->bf16
  unsigned u = __float_as_uint(f);
  return (unsigned short)((u + 0x7FFFu + ((u >> 16) & 1u)) >> 16);
}

// ---------------------------------------------------------------------------
// fp32 -> bf16 bulk convert (vectorized x4). n4 = element count / 4.
// ---------------------------------------------------------------------------
__global__ __launch_bounds__(256) void cvt_bf16(const float* __restrict__ s,
                                                ushort_t* __restrict__ d, int n4) {
  int i = blockIdx.x * 256 + threadIdx.x;
  if (i >= n4) return;
  float4 v = ((const float4*)s)[i];
  us4 o = {f2bf(v.x), f2bf(v.y), f2bf(v.z), f2bf(v.w)};
  ((us4*)d)[i] = o;
}

// ---------------------------------------------------------------------------
// Input projection: h[b,l,d] = sum_c x[b,c,l] * pw[d,c] + pb[d]; also bf16 copy.
// ---------------------------------------------------------------------------
__global__ __launch_bounds__(256) void proj_kernel(const float* __restrict__ x,
                                                   const float* __restrict__ pw,
                                                   const float* __restrict__ pb,
                                                   float* __restrict__ h,
                                                   ushort_t* __restrict__ hbf) {
  int idx = blockIdx.x * 256 + threadIdx.x;        // ((b*L)+l)*512 + d
  int d = idx & 511;
  int l = (idx >> 9) & 1023;
  int b = idx >> 19;
  const float* xb = x + (size_t)b * 3 * 1024 + l;
  float v = pb[d] + xb[0] * pw[d * 3] + xb[1024] * pw[d * 3 + 1] + xb[2048] * pw[d * 3 + 2];
  h[idx] = v;
  hbf[idx] = f2bf(v);
}

// ---------------------------------------------------------------------------
// bf16 MFMA GEMM: C[m,n] = act( sum_k A[m,k]*W[n,k] + bias[n] )
// A, W bf16 (row-major, leading dims lda / K). Tile 128 x BN, BK=32.
// BN=128: 4 waves 2x2 (64x64 each). BN=64: 4 waves 4x1 (32x64 each).
// ACT: 0 none, 1 relu. CBF: 1 -> store bf16, 0 -> store fp32.
// LDS chunk-swizzle: chunk s of row r stored at s ^ ((r>>1)&3)  (2-way, free).
// ---------------------------------------------------------------------------
template <int ACT, int BN, int CBF>
__global__ __launch_bounds__(256) void gemm_bf(const ushort_t* __restrict__ A,
                                               const ushort_t* __restrict__ W,
                                               const float* __restrict__ bias,
                                               void* __restrict__ Cp,
                                               int K, int lda, int ldc) {
  __shared__ bfrag Abuf[512];          // 128 rows x 4 chunks
  __shared__ bfrag Bbuf[BN * 4];       // BN rows x 4 chunks
  const int bm = blockIdx.y * 128, bn = blockIdx.x * BN;
  const int tid = threadIdx.x;
  const int wid = tid >> 6, lane = tid & 63;
  constexpr int MREP = (BN == 128) ? 4 : 2;
  const int wrb = (BN == 128) ? (wid >> 1) * 64 : wid * 32;  // wave row base
  const int wcb = (BN == 128) ? (wid & 1) * 64 : 0;          // wave col base
  const int lr = lane & 15, ls = lane >> 4;
  const int sw = ls ^ ((lr >> 1) & 3);

  f32x4 acc[MREP][4];
#pragma unroll
  for (int i = 0; i < MREP; ++i)
#pragma unroll
    for (int j = 0; j < 4; ++j) acc[i][j] = (f32x4)(0.f);

  for (int k0 = 0; k0 < K; k0 += 32) {
    if (k0) __syncthreads();
#pragma unroll
    for (int c = tid; c < 512; c += 256) {
      int r = c >> 2, s = c & 3;
      Abuf[(r << 2) + (s ^ ((r >> 1) & 3))] =
          *(const bfrag*)(A + (size_t)(bm + r) * lda + k0 + s * 8);
    }
#pragma unroll
    for (int c = tid; c < BN * 4; c += 256) {
      int r = c >> 2, s = c & 3;
      Bbuf[(r << 2) + (s ^ ((r >> 1) & 3))] =
          *(const bfrag*)(W + (size_t)(bn + r) * K + k0 + s * 8);
    }
    __syncthreads();

    bfrag af[MREP], bf[4];
#pragma unroll
    for (int mi = 0; mi < MREP; ++mi) {
      int row = wrb + mi * 16 + lr;
      af[mi] = Abuf[(row << 2) + sw];
    }
#pragma unroll
    for (int nj = 0; nj < 4; ++nj) {
      int col = wcb + nj * 16 + lr;
      bf[nj] = Bbuf[(col << 2) + sw];
    }
#pragma unroll
    for (int mi = 0; mi < MREP; ++mi)
#pragma unroll
      for (int nj = 0; nj < 4; ++nj)
        acc[mi][nj] = __builtin_amdgcn_mfma_f32_16x16x32_bf16(af[mi], bf[nj], acc[mi][nj], 0, 0, 0);
  }

  // epilogue: C/D layout col=lane&15, row=(lane>>4)*4+reg
#pragma unroll
  for (int nj = 0; nj < 4; ++nj) {
    int col = bn + wcb + nj * 16 + lr;
    float bv = bias ? bias[col] : 0.f;
#pragma unroll
    for (int mi = 0; mi < MREP; ++mi) {
      int row0 = bm + wrb + mi * 16 + ls * 4;
#pragma unroll
      for (int r = 0; r < 4; ++r) {
        float v = acc[mi][nj][r] + bv;
        if (ACT == 1) v = fmaxf(v, 0.f);
        if (CBF)
          ((ushort_t*)Cp)[(size_t)(row0 + r) * ldc + col] = f2bf(v);
        else
          ((float*)Cp)[(size_t)(row0 + r) * ldc + col] = v;
      }
    }
  }
}

// ---------------------------------------------------------------------------
// Generic fp32 tiled SGEMM (small shapes: xproj N=64, dt K=32)
// ACT: 0 none, 2 softplus
// ---------------------------------------------------------------------------
template <int ACT>
__global__ __launch_bounds__(256) void gemm_tn(const float* __restrict__ A,
                                               const float* __restrict__ W,
                                               const float* __restrict__ bias,
                                               float* __restrict__ C,
                                               int M, int N, int K, int lda, int ldc) {
  __shared__ float As[16][65];
  __shared__ float Ws[16][65];
  const int bm = blockIdx.y * 64, bn = blockIdx.x * 64;
  const int tid = threadIdx.x;
  const int lk = tid & 15, lr = tid >> 4;
  const int tx = tid & 15, ty = tid >> 4;
  float acc[4][4] = {};
  for (int k0 = 0; k0 < K; k0 += 16) {
#pragma unroll
    for (int i = 0; i < 4; ++i) {
      As[lk][lr + 16 * i] = A[(size_t)(bm + lr + 16 * i) * lda + k0 + lk];
      Ws[lk][lr + 16 * i] = W[(size_t)(bn + lr + 16 * i) * K + k0 + lk];
    }
    __syncthreads();
#pragma unroll
    for (int kk = 0; kk < 16; ++kk) {
      float a[4], w[4];
#pragma unroll
      for (int i = 0; i < 4; ++i) a[i] = As[kk][ty + 16 * i];
#pragma unroll
      for (int j = 0; j < 4; ++j) w[j] = Ws[kk][tx + 16 * j];
#pragma unroll
      for (int i = 0; i < 4; ++i)
#pragma unroll
        for (int j = 0; j < 4; ++j) acc[i][j] += a[i] * w[j];
    }
    __syncthreads();
  }
#pragma unroll
  for (int i = 0; i < 4; ++i) {
    int r = bm + ty + 16 * i;
#pragma unroll
    for (int j = 0; j < 4; ++j) {
      int c = bn + tx + 16 * j;
      float v = acc[i][j];
      if (bias) v += bias[c];
      if (ACT == 2) v = (v > 20.f) ? v : log1pf(__expf(v));
      C[(size_t)r * ldc + c] = v;
    }
  }
}

// ---------------------------------------------------------------------------
// Depthwise causal conv (width 4) + SiLU.  xm = xz[:, :DINNER] (row stride 2048)
// ---------------------------------------------------------------------------
__global__ __launch_bounds__(256) void conv_silu_kernel(const float* __restrict__ xz,
                                                        const float* __restrict__ cw,
                                                        const float* __restrict__ cb,
                                                        float* __restrict__ xc) {
  int idx = blockIdx.x * 256 + threadIdx.x;        // ((b*L)+t)*1024 + d
  int d = idx & 1023;
  int t = (idx >> 10) & 1023;
  int b = idx >> 20;
  float acc = cb[d];
#pragma unroll
  for (int w = 0; w < 4; ++w) {
    int tt = t - 3 + w;
    if (tt >= 0) acc += xz[(((size_t)(b * 1024 + tt)) << 11) + d] * cw[d * 4 + w];
  }
  xc[idx] = silu_f(acc);
}

// ---------------------------------------------------------------------------
// Chunked selective scan, pass 1: per (b,d,chunk) scan 64 steps with init=0.
// ---------------------------------------------------------------------------
__global__ __launch_bounds__(256) void scan_pass1(const float* __restrict__ dt,
                                                  const float* __restrict__ xdb,
                                                  const float* __restrict__ xc,
                                                  const float* __restrict__ Alog,
                                                  float* __restrict__ scrP,
                                                  float* __restrict__ scrL) {
  int idx = blockIdx.x * 256 + threadIdx.x;        // ((b*16 + c)*1024 + d)
  int d = idx & 1023;
  int c = (idx >> 10) & 15;
  int b = idx >> 14;
  float A[16], st[16], P[16];
#pragma unroll
  for (int s = 0; s < 16; ++s) {
    A[s] = -__expf(Alog[d * 16 + s]);
    st[s] = 0.f;
    P[s] = 1.f;
  }
  int t0 = c * CLEN;
  for (int t = t0; t < t0 + CLEN; ++t) {
    size_t base = (((size_t)(b * 1024 + t)) << 10) + d;
    float dtv = dt[base];
    float xv = xc[base];
    size_t xrow = (size_t)(b * 1024 + t) * 64;
    float dx = dtv * xv;
#pragma unroll
    for (int s = 0; s < 16; ++s) {
      float e = __expf(dtv * A[s]);
      st[s] = st[s] * e + dx * xdb[xrow + 32 + s];
      P[s] *= e;
    }
  }
  size_t pbase = (((size_t)((b * 16 + c) * 16)) << 10) + d;
#pragma unroll
  for (int s = 0; s < 16; ++s) {
    scrP[pbase + ((size_t)s << 10)] = P[s];
    scrL[pbase + ((size_t)s << 10)] = st[s];
  }
}

// ---------------------------------------------------------------------------
// Pass 2: combine chunks serially per (b,d,s).
// ---------------------------------------------------------------------------
__global__ __launch_bounds__(256) void scan_pass2(const float* __restrict__ scrP,
                                                  float* __restrict__ scrL) {
  int idx = blockIdx.x * 256 + threadIdx.x;        // ((b*16 + s)*1024 + d)
  int d = idx & 1023;
  int s = (idx >> 10) & 15;
  int b = idx >> 14;
  float cur = 0.f;
  for (int c = 0; c < 16; ++c) {
    size_t o = (((size_t)(((b * 16 + c) * 16) + s)) << 10) + d;
    float P = scrP[o];
    float loc = scrL[o];
    scrL[o] = cur;
    cur = cur * P + loc;
  }
}

// ---------------------------------------------------------------------------
// Pass 3: rescan with correct init; write gated y as bf16 into ybf (B,L,DI).
// ---------------------------------------------------------------------------
__global__ __launch_bounds__(256) void scan_pass3(const float* __restrict__ dt,
                                                  const float* __restrict__ xdb,
                                                  const float* __restrict__ xc,
                                                  const float* __restrict__ xz,
                                                  ushort_t* __restrict__ ybf,
                                                  const float* __restrict__ Alog,
                                                  const float* __restrict__ Dp,
                                                  const float* __restrict__ scrL) {
  int idx = blockIdx.x * 256 + threadIdx.x;        // ((b*16 + c)*1024 + d)
  int d = idx & 1023;
  int c = (idx >> 10) & 15;
  int b = idx >> 14;
  float A[16], st[16];
  size_t pbase = (((size_t)((b * 16 + c) * 16)) << 10) + d;
#pragma unroll
  for (int s = 0; s < 16; ++s) {
    A[s] = -__expf(Alog[d * 16 + s]);
    st[s] = scrL[pbase + ((size_t)s << 10)];
  }
  float Dv = Dp[d];
  int t0 = c * CLEN;
  for (int t = t0; t < t0 + CLEN; ++t) {
    size_t base = (((size_t)(b * 1024 + t)) << 10) + d;
    float dtv = dt[base];
    float xv = xc[base];
    size_t xrow = (size_t)(b * 1024 + t) * 64;
    float dx = dtv * xv;
    float acc = 0.f;
#pragma unroll
    for (int s = 0; s < 16; ++s) {
      float e = __expf(dtv * A[s]);
      st[s] = st[s] * e + dx * xdb[xrow + 32 + s];
      acc += st[s] * xdb[xrow + 48 + s];
    }
    size_t zrow = ((size_t)(b * 1024 + t)) << 11;
    float zv = xz[zrow + 1024 + d];
    ybf[base] = f2bf((acc + Dv * xv) * silu_f(zv));
  }
}

// ---------------------------------------------------------------------------
// Residual + LayerNorm. add / out_bf may be nullptr.
// ---------------------------------------------------------------------------
__global__ __launch_bounds__(128) void resid_ln_kernel(const float* __restrict__ x,
                                                       const float* __restrict__ add,
                                                       const float* __restrict__ w,
                                                       const float* __restrict__ bias,
                                                       float* __restrict__ out,
                                                       ushort_t* __restrict__ out_bf) {
  int row = blockIdx.x, tid = threadIdx.x;
  float4 v = ((const float4*)(x + (size_t)row * 512))[tid];
  if (add) {
    float4 a = ((const float4*)(add + (size_t)row * 512))[tid];
    v.x += a.x; v.y += a.y; v.z += a.z; v.w += a.w;
  }
  float s = v.x + v.y + v.z + v.w;
  float ss = v.x * v.x + v.y * v.y + v.z * v.z + v.w * v.w;
#pragma unroll
  for (int o = 32; o; o >>= 1) {
    s += __shfl_xor(s, o);
    ss += __shfl_xor(ss, o);
  }
  __shared__ float red[4];
  int wid = tid >> 6;
  if ((tid & 63) == 0) { red[wid] = s; red[2 + wid] = ss; }
  __syncthreads();
  s = red[0] + red[1];
  ss = red[2] + red[3];
  float mean = s * (1.f / 512.f);
  float var = ss * (1.f / 512.f) - mean * mean;
  float inv = rsqrtf(var + 1e-5f);
  float4 wv = ((const float4*)w)[tid];
  float4 bv = ((const float4*)bias)[tid];
  float4 ov;
  ov.x = (v.x - mean) * inv * wv.x + bv.x;
  ov.y = (v.y - mean) * inv * wv.y + bv.y;
  ov.z = (v.z - mean) * inv * wv.z + bv.z;
  ov.w = (v.w - mean) * inv * wv.w + bv.w;
  ((float4*)(out + (size_t)row * 512))[tid] = ov;
  if (out_bf) {
    us4 ob = {f2bf(ov.x), f2bf(ov.y), f2bf(ov.z), f2bf(ov.w)};
    ((us4*)(out_bf + (size_t)row * 512))[tid] = ob;
  }
}

// ---------------------------------------------------------------------------
// Sinusoidal positional encoding add (in-place on h, refresh hbf)
// ---------------------------------------------------------------------------
__global__ __launch_bounds__(256) void posenc_kernel(float* __restrict__ h,
                                                     ushort_t* __restrict__ hbf) {
  int idx = blockIdx.x * 256 + threadIdx.x;
  int d = idx & 511;
  int l = (idx >> 9) & 1023;
  float freq = __expf(-(float)(d & ~1) * (9.210340371976184f / 512.f));
  float ang = (float)l * freq;
  float v = h[idx] + ((d & 1) ? cosf(ang) : sinf(ang));
  h[idx] = v;
  hbf[idx] = f2bf(v);
}

// ---------------------------------------------------------------------------
// MFMA flash attention, bf16 qkv input. One block = (b, head, 64 q-rows).
// LDS swizzle: elem (row,col) at row*64 + (((col>>3) ^ (row&7))<<3) + (col&7).
// 1/sqrt(d) folded into S after the QK^T MFMA. Output bf16.
// ---------------------------------------------------------------------------
__global__ __launch_bounds__(256) void attn_mfma(const ushort_t* __restrict__ qkv,
                                                 ushort_t* __restrict__ ao) {
  __shared__ unsigned short Qs[4096];
  __shared__ unsigned short Ks[4096];
  __shared__ unsigned short Vt[4096];
  __shared__ unsigned short Ps[4096];
  const int tid = threadIdx.x;
  const int blk = blockIdx.x;                    // ((b*8 + h)*16 + qt)
  const int qt = blk & 15, hh = (blk >> 4) & 7, b = blk >> 7;
  const int l0 = qt * 64;
  const size_t bb = (size_t)b * 1024 * 1536;

  const int srow = tid >> 2;                     // staging row 0..63
  const int sdb = (tid & 3) << 4;                // staging d-block 0/16/32/48
  const int sc0 = sdb >> 3;

  // stage Q (bf16 passthrough)
  {
    const ushort_t* qp = qkv + bb + (size_t)(l0 + srow) * 1536 + hh * 64 + sdb;
    *(bfrag*)&Qs[srow * 64 + ((sc0 ^ (srow & 7)) << 3)] = *(const bfrag*)qp;
    *(bfrag*)&Qs[srow * 64 + (((sc0 + 1) ^ (srow & 7)) << 3)] = *(const bfrag*)(qp + 8);
  }

  const int wid = tid >> 6, lane = tid & 63;
  const int l15 = lane & 15, rg = lane >> 4;
  const int l7 = l15 & 7;
  float m[4], lsum[4];
  f32x4 oacc[4];
#pragma unroll
  for (int r = 0; r < 4; ++r) { m[r] = -1e30f; lsum[r] = 0.f; }
#pragma unroll
  for (int nt = 0; nt < 4; ++nt) oacc[nt] = (f32x4)(0.f);

  for (int jt = 0; jt < 16; ++jt) {
    // stage K row-major, V transposed
    {
      const ushort_t* kp = qkv + bb + (size_t)(jt * 64 + srow) * 1536 + hh * 64 + 512 + sdb;
      *(bfrag*)&Ks[srow * 64 + ((sc0 ^ (srow & 7)) << 3)] = *(const bfrag*)kp;
      *(bfrag*)&Ks[srow * 64 + (((sc0 + 1) ^ (srow & 7)) << 3)] = *(const bfrag*)(kp + 8);
      const ushort_t* vp = kp + 512;
      unsigned short vv[16];
      *(bfrag*)&vv[0] = *(const bfrag*)vp;
      *(bfrag*)&vv[8] = *(const bfrag*)(vp + 8);
#pragma unroll
      for (int j = 0; j < 16; ++j) {
        int dd = sdb + j;
        Vt[dd * 64 + (((srow >> 3) ^ (dd & 7)) << 3) + (srow & 7)] = vv[j];
      }
    }
    __syncthreads();

    // S = Q K^T (scaled after MFMA)
    bfrag aq[2];
#pragma unroll
    for (int ks = 0; ks < 2; ++ks)
      aq[ks] = *(const bfrag*)&Qs[(wid * 16 + l15) * 64 + (((ks * 4 + rg) ^ l7) << 3)];
    f32x4 sc[4];
#pragma unroll
    for (int nt = 0; nt < 4; ++nt) {
      f32x4 s = (f32x4)(0.f);
#pragma unroll
      for (int ks = 0; ks < 2; ++ks) {
        bfrag bk = *(const bfrag*)&Ks[(nt * 16 + l15) * 64 + (((ks * 4 + rg) ^ l7) << 3)];
        s = __builtin_amdgcn_mfma_f32_16x16x32_bf16(aq[ks], bk, s, 0, 0, 0);
      }
      sc[nt] = s * 0.125f;
    }

    // online softmax; P -> bf16 LDS (per-wave private region)
#pragma unroll
    for (int r = 0; r < 4; ++r) {
      float mc = fmaxf(fmaxf(sc[0][r], sc[1][r]), fmaxf(sc[2][r], sc[3][r]));
#pragma unroll
      for (int o = 8; o; o >>= 1) mc = fmaxf(mc, __shfl_xor(mc, o));
      float mn = fmaxf(m[r], mc);
      float al = __expf(m[r] - mn);
      m[r] = mn;
      int prow = rg * 4 + r;
      float ps = 0.f;
#pragma unroll
      for (int nt = 0; nt < 4; ++nt) {
        float p = __expf(sc[nt][r] - mn);
        ps += p;
        int col = nt * 16 + l15;
        Ps[wid * 1024 + prow * 64 + ((((col >> 3) ^ (prow & 7))) << 3) + (col & 7)] = f2bf(p);
      }
#pragma unroll
      for (int o = 8; o; o >>= 1) ps += __shfl_xor(ps, o);
      lsum[r] = lsum[r] * al + ps;
#pragma unroll
      for (int nt = 0; nt < 4; ++nt) oacc[nt][r] *= al;
    }

    // O += P V
    bfrag ap[2];
#pragma unroll
    for (int ks = 0; ks < 2; ++ks)
      ap[ks] = *(const bfrag*)&Ps[wid * 1024 + l15 * 64 + (((ks * 4 + rg) ^ l7) << 3)];
#pragma unroll
    for (int nt = 0; nt < 4; ++nt) {
#pragma unroll
      for (int ks = 0; ks < 2; ++ks) {
        bfrag bv = *(const bfrag*)&Vt[(nt * 16 + l15) * 64 + (((ks * 4 + rg) ^ l7) << 3)];
        oacc[nt] = __builtin_amdgcn_mfma_f32_16x16x32_bf16(ap[ks], bv, oacc[nt], 0, 0, 0);
      }
    }
    __syncthreads();
  }

  // epilogue: O /= lsum, write bf16
#pragma unroll
  for (int r = 0; r < 4; ++r) {
    float inv = 1.f / lsum[r];
    int row = l0 + wid * 16 + rg * 4 + r;
    ushort_t* op = ao + ((size_t)(b * 1024 + row)) * 512 + hh * 64;
#pragma unroll
    for (int nt = 0; nt < 4; ++nt) op[nt * 16 + l15] = f2bf(oacc[nt][r] * inv);
  }
}

// ---------------------------------------------------------------------------
// Mean over L: out2[b,d] = mean_l hout[b,l,d]
// ---------------------------------------------------------------------------
__global__ __launch_bounds__(256) void mean_kernel(const float* __restrict__ hout,
                                                   float* __restrict__ out2) {
  int idx = blockIdx.x * 256 + threadIdx.x;
  int b = idx >> 9, d = idx & 511;
  float s = 0.f;
  for (int l = 0; l < 1024; ++l) s += hout[(((size_t)(b * 1024 + l)) << 9) + d];
  out2[idx] = s * (1.f / 1024.f);
}

// ---------------------------------------------------------------------------
extern "C" void kernel_launch(void* const* d_in, const int* in_sizes, int n_in,
                              void* d_out, int out_size, void* d_ws, size_t ws_size,
                              hipStream_t stream) {
  const float* x        = (const float*)d_in[0];
  const float* proj_w   = (const float*)d_in[1];
  const float* proj_b   = (const float*)d_in[2];
  const float* m_in_w   = (const float*)d_in[3];
  const float* m_conv_w = (const float*)d_in[4];
  const float* m_conv_b = (const float*)d_in[5];
  const float* m_xproj_w= (const float*)d_in[6];
  const float* m_dt_w   = (const float*)d_in[7];
  const float* m_dt_b   = (const float*)d_in[8];
  const float* m_Alog   = (const float*)d_in[9];
  const float* m_D      = (const float*)d_in[10];
  const float* m_out_w  = (const float*)d_in[11];
  const float* m_ln_w   = (const float*)d_in[12];
  const float* m_ln_b   = (const float*)d_in[13];
  const float* t_qkv_w  = (const float*)d_in[14];
  const float* t_qkv_b  = (const float*)d_in[15];
  const float* t_ow     = (const float*)d_in[16];
  const float* t_ob     = (const float*)d_in[17];
  const float* t_l1w    = (const float*)d_in[18];
  const float* t_l1b    = (const float*)d_in[19];
  const float* t_l2w    = (const float*)d_in[20];
  const float* t_l2b    = (const float*)d_in[21];
  const float* t_ln1w   = (const float*)d_in[22];
  const float* t_ln1b   = (const float*)d_in[23];
  const float* t_ln2w   = (const float*)d_in[24];
  const float* t_ln2b   = (const float*)d_in[25];
  const float* no_w     = (const float*)d_in[26];
  const float* no_b     = (const float*)d_in[27];

  float* ws   = (float*)d_ws;
  float* h    = ws;                                   //  4M f
  ushort_t* h_bf = (ushort_t*)(ws + 4194304);         //  4M us (2M f)
  float* bufA = ws + 6291456;                         // 16M f (xz f32 / qkv_bf / ff1_bf)
  float* bufB = bufA + 16777216;                      //  8M f (xc f32 / ao_bf)
  float* bufC = bufB + 8388608;                       //  8M f (dt)
  float* bufE = bufC + 8388608;                       //  4M f (scan scratch / f32 GEMM out)
  float* bufF = bufE + 4194304;                       //  0.5M f (xdb)
  ushort_t* y_bf = (ushort_t*)(bufF + 524288);        //  8M us (4M f)
  ushort_t* wbf  = (ushort_t*)(bufF + 524288 + 4194304);  // 9.44M us
  float* scrP = bufE;
  float* scrL = bufE + 2097152;
  const int M = MTOK;

  // bf16 weight pool offsets (ushort units)
  ushort_t* wIN  = wbf;                 // 2 x 2048 x 512
  ushort_t* wOUT = wbf + 2097152;       // 2 x 512 x 1024
  ushort_t* wQKV = wbf + 3145728;       // 2 x 1536 x 512
  ushort_t* wOW  = wbf + 4718592;       // 2 x 512 x 512
  ushort_t* wL1  = wbf + 5242880;       // 2 x 2048 x 512
  ushort_t* wL2  = wbf + 7340032;       // 2 x 512 x 2048

  cvt_bf16<<<2048, 256, 0, stream>>>(m_in_w,  wIN,  524288);
  cvt_bf16<<<1024, 256, 0, stream>>>(m_out_w, wOUT, 262144);
  cvt_bf16<<<1536, 256, 0, stream>>>(t_qkv_w, wQKV, 393216);
  cvt_bf16<<< 512, 256, 0, stream>>>(t_ow,    wOW,  131072);
  cvt_bf16<<<2048, 256, 0, stream>>>(t_l1w,   wL1,  524288);
  cvt_bf16<<<2048, 256, 0, stream>>>(t_l2w,   wL2,  524288);

  proj_kernel<<<16384, 256, 0, stream>>>(x, proj_w, proj_b, h, h_bf);

  for (int i = 0; i < 2; ++i) {
    // xz = h @ in_w^T   (8192 x 2048, K=512) -> fp32
    gemm_bf<0, 128, 0><<<dim3(16, 64), 256, 0, stream>>>(
        h_bf, wIN + (size_t)i * 1048576, nullptr, bufA, DMODEL, DMODEL, 2 * DINNER);
    // xc = silu(causal_conv(xm))
    conv_silu_kernel<<<32768, 256, 0, stream>>>(bufA, m_conv_w + i * DINNER * 4,
                                                m_conv_b + i * DINNER, bufB);
    // xdb = xc @ xp_w^T  (8192 x 64, K=1024) fp32
    gemm_tn<0><<<dim3(1, M / 64), 256, 0, stream>>>(
        bufB, m_xproj_w + (size_t)i * 64 * DINNER, nullptr, bufF,
        M, 64, DINNER, DINNER, 64);
    // dt = softplus(xdb[:, :32] @ dt_w^T + dt_b) fp32
    gemm_tn<2><<<dim3(DINNER / 64, M / 64), 256, 0, stream>>>(
        bufF, m_dt_w + (size_t)i * DINNER * DTRANK, m_dt_b + i * DINNER, bufC,
        M, DINNER, DTRANK, 64, DINNER);
    // chunked selective scan -> y_bf (bf16)
    scan_pass1<<<512, 256, 0, stream>>>(bufC, bufF, bufB,
                                        m_Alog + (size_t)i * DINNER * DSTATE, scrP, scrL);
    scan_pass2<<<512, 256, 0, stream>>>(scrP, scrL);
    scan_pass3<<<512, 256, 0, stream>>>(bufC, bufF, bufB, bufA, y_bf,
                                        m_Alog + (size_t)i * DINNER * DSTATE,
                                        m_D + i * DINNER, scrL);
    // mamba_out = y @ out_w^T  (8192 x 512, K=1024) -> fp32
    gemm_bf<0, 64, 0><<<dim3(8, 64), 256, 0, stream>>>(
        y_bf, wOUT + (size_t)i * 524288, nullptr, bufE, DINNER, DINNER, DMODEL);
    // h = LN(h + mamba_out), refresh h_bf
    resid_ln_kernel<<<8192, 128, 0, stream>>>(h, bufE, m_ln_w + i * DMODEL,
                                              m_ln_b + i * DMODEL, h, h_bf);
  }

  posenc_kernel<<<16384, 256, 0, stream>>>(h, h_bf);

  for (int i = 0; i < 2; ++i) {
    // qkv = h @ qkv_w^T + qkv_b  (8192 x 1536, K=512) -> bf16
    gemm_bf<0, 128, 1><<<dim3(12, 64), 256, 0, stream>>>(
        h_bf, wQKV + (size_t)i * 786432, t_qkv_b + i * 3 * DMODEL, bufA,
        DMODEL, DMODEL, 3 * DMODEL);
    // MFMA flash attention -> ao bf16
    attn_mfma<<<1024, 256, 0, stream>>>((const ushort_t*)bufA, (ushort_t*)bufB);
    // attn_proj = ao @ ow^T + ob  (8192 x 512, K=512) -> fp32
    gemm_bf<0, 64, 0><<<dim3(8, 64), 256, 0, stream>>>(
        (const ushort_t*)bufB, wOW + (size_t)i * 262144, t_ob + i * DMODEL, bufE,
        DMODEL, DMODEL, DMODEL);
    // h = LN(h + attn_proj)
    resid_ln_kernel<<<8192, 128, 0, stream>>>(h, bufE, t_ln1w + i * DMODEL,
                                              t_ln1b + i * DMODEL, h, h_bf);
    // ff1 = relu(h @ l1w^T + l1b)  (8192 x 2048, K=512) -> bf16
    gemm_bf<1, 128, 1><<<dim3(16, 64), 256, 0, stream>>>(
        h_bf, wL1 + (size_t)i * 1048576, t_l1b + i * DFF, bufA,
        DMODEL, DMODEL, DFF);
    // ff2 = ff1 @ l2w^T + l2b  (8192 x 512, K=2048) -> fp32
    gemm_bf<0, 64, 0><<<dim3(8, 64), 256, 0, stream>>>(
        (const ushort_t*)bufA, wL2 + (size_t)i * 1048576, t_l2b + i * DMODEL, bufE,
        DFF, DFF, DMODEL);
    // h = LN(h + ff2)
    resid_ln_kernel<<<8192, 128, 0, stream>>>(h, bufE, t_ln2w + i * DMODEL,
                                              t_ln2b + i * DMODEL, h, h_bf);
  }

  // final LN -> d_out, then mean over L -> d_out tail
  float* out_h = (float*)d_out;
  resid_ln_kernel<<<8192, 128, 0, stream>>>(h, nullptr, no_w, no_b, out_h, nullptr);
  mean_kernel<<<16, 256, 0, stream>>>(out_h, out_h + 4194304);
}

// Round 6
// 1314.011 us; speedup vs baseline: 1.1051x; 1.1051x over previous
//
#include <hip/hip_runtime.h>
#include <cstddef>

// Problem constants
#define BATCH 8
#define LSEQ 1024
#define DMODEL 512
#define DINNER 1024
#define DSTATE 16
#define DTRANK 32
#define NHEAD 8
#define DHEAD 64
#define DFF 2048
#define MTOK 8192   // BATCH*LSEQ
#define NCHUNK 16
#define CLEN 64     // LSEQ / NCHUNK

typedef __attribute__((ext_vector_type(8))) short bfrag;          // 8 bf16 = 16 B
typedef __attribute__((ext_vector_type(4))) float f32x4;          // MFMA acc
typedef __attribute__((ext_vector_type(4))) unsigned short us4;
typedef unsigned short ushort_t;

__device__ __forceinline__ float silu_f(float x) { return x / (1.f + __expf(-x)); }

__device__ __forceinline__ unsigned short f2bf(float f) {  // RNE fp32->bf16
  unsigned u = __float_as_uint(f);
  return (unsigned short)((u + 0x7FFFu + ((u >> 16) & 1u)) >> 16);
}

// async global->LDS, 16B per lane. LDS dest = wave-uniform base + lane*16.
__device__ __forceinline__ void gll16(const ushort_t* g, ushort_t* l) {
  __builtin_amdgcn_global_load_lds(
      (const __attribute__((address_space(1))) unsigned int*)g,
      (__attribute__((address_space(3))) unsigned int*)l, 16, 0, 0);
}

// ---------------------------------------------------------------------------
// fp32 -> bf16 bulk convert (vectorized x4). n4 = element count / 4.
// ---------------------------------------------------------------------------
__global__ __launch_bounds__(256) void cvt_bf16(const float* __restrict__ s,
                                                ushort_t* __restrict__ d, int n4) {
  int i = blockIdx.x * 256 + threadIdx.x;
  if (i >= n4) return;
  float4 v = ((const float4*)s)[i];
  us4 o = {f2bf(v.x), f2bf(v.y), f2bf(v.z), f2bf(v.w)};
  ((us4*)d)[i] = o;
}

// ---------------------------------------------------------------------------
// Input projection: h[b,l,d] = sum_c x[b,c,l] * pw[d,c] + pb[d]; also bf16 copy.
// ---------------------------------------------------------------------------
__global__ __launch_bounds__(256) void proj_kernel(const float* __restrict__ x,
                                                   const float* __restrict__ pw,
                                                   const float* __restrict__ pb,
                                                   float* __restrict__ h,
                                                   ushort_t* __restrict__ hbf) {
  int idx = blockIdx.x * 256 + threadIdx.x;        // ((b*L)+l)*512 + d
  int d = idx & 511;
  int l = (idx >> 9) & 1023;
  int b = idx >> 19;
  const float* xb = x + (size_t)b * 3 * 1024 + l;
  float v = pb[d] + xb[0] * pw[d * 3] + xb[1024] * pw[d * 3 + 1] + xb[2048] * pw[d * 3 + 2];
  h[idx] = v;
  hbf[idx] = f2bf(v);
}

// ---------------------------------------------------------------------------
// bf16 MFMA GEMM, global_load_lds + double-buffered prefetch.
// C[m,n] = act( sum_k A[m,k]*W[n,k] + bias[n] ).  Tile 128x128, BK=32.
// ACT: 0 none, 1 relu. CBF: 1 bf16 C, 0 fp32 C.
// SPLITK: 1 direct; 2 -> fp32 partials at Cp + z*8192*ldc (no bias/act).
// LDS layout: 512 chunks of 16B; chunk for (row r, k-chunk s) at slot
//   r*4 + (s ^ ((r>>1)&3)); gll writes linearly, source address pre-swizzled.
// ---------------------------------------------------------------------------
template <int ACT, int CBF, int SPLITK>
__global__ __launch_bounds__(256) void gemm_gll(const ushort_t* __restrict__ A,
                                                const ushort_t* __restrict__ W,
                                                const float* __restrict__ bias,
                                                void* __restrict__ Cp,
                                                int K, int lda, int ldc) {
  __shared__ ushort_t sA[2][4096];
  __shared__ ushort_t sB[2][4096];
  const int bm = blockIdx.y * 128, bn = blockIdx.x * 128;
  const int tid = threadIdx.x;
  const int wid = tid >> 6, lane = tid & 63;
  const int wr = wid >> 1, wc = wid & 1;
  const int lr = lane & 15, ls = lane >> 4;
  const int sw = ls ^ ((lr >> 1) & 3);

  const int kseg = K / SPLITK;
  const int kbeg = (SPLITK > 1) ? blockIdx.z * kseg : 0;

  // per-lane pre-swizzled global sources for the wave's 2 A-writes + 2 B-writes
  const int c0 = wid * 128 + lane;
  const int c1 = c0 + 64;
  const int r0 = c0 >> 2, s0 = (c0 & 3) ^ ((r0 >> 1) & 3);
  const int r1 = c1 >> 2, s1 = (c1 & 3) ^ ((r1 >> 1) & 3);
  const ushort_t* gA0 = A + (size_t)(bm + r0) * lda + kbeg + s0 * 8;
  const ushort_t* gA1 = A + (size_t)(bm + r1) * lda + kbeg + s1 * 8;
  const ushort_t* gB0 = W + (size_t)(bn + r0) * K + kbeg + s0 * 8;
  const ushort_t* gB1 = W + (size_t)(bn + r1) * K + kbeg + s1 * 8;

  f32x4 acc[4][4];
#pragma unroll
  for (int i = 0; i < 4; ++i)
#pragma unroll
    for (int j = 0; j < 4; ++j) acc[i][j] = (f32x4)(0.f);

#define STAGE(buf, step)                                           \
  do {                                                             \
    gll16(gA0 + (step) * 32, &sA[buf][wid * 1024]);                \
    gll16(gA1 + (step) * 32, &sA[buf][wid * 1024 + 512]);          \
    gll16(gB0 + (step) * 32, &sB[buf][wid * 1024]);                \
    gll16(gB1 + (step) * 32, &sB[buf][wid * 1024 + 512]);          \
  } while (0)

  const int NT = kseg / 32;
  STAGE(0, 0);
  for (int t = 0; t < NT; ++t) {
    const int cur = t & 1;
    if (t + 1 < NT) {
      STAGE(cur ^ 1, t + 1);
      asm volatile("s_waitcnt vmcnt(4)" ::: "memory");
    } else {
      asm volatile("s_waitcnt vmcnt(0)" ::: "memory");
    }
    __builtin_amdgcn_sched_barrier(0);
    __builtin_amdgcn_s_barrier();
    __builtin_amdgcn_sched_barrier(0);

    bfrag af[4], bf[4];
#pragma unroll
    for (int mi = 0; mi < 4; ++mi) {
      int row = wr * 64 + mi * 16 + lr;
      af[mi] = *(const bfrag*)&sA[cur][(size_t)((row << 2) + sw) * 8];
    }
#pragma unroll
    for (int nj = 0; nj < 4; ++nj) {
      int col = wc * 64 + nj * 16 + lr;
      bf[nj] = *(const bfrag*)&sB[cur][(size_t)((col << 2) + sw) * 8];
    }
#pragma unroll
    for (int mi = 0; mi < 4; ++mi)
#pragma unroll
      for (int nj = 0; nj < 4; ++nj)
        acc[mi][nj] = __builtin_amdgcn_mfma_f32_16x16x32_bf16(af[mi], bf[nj], acc[mi][nj], 0, 0, 0);

    __builtin_amdgcn_s_barrier();
    __builtin_amdgcn_sched_barrier(0);
  }
#undef STAGE

  // epilogue: C/D layout col=lane&15, row=(lane>>4)*4+reg
  if (SPLITK > 1) {
    float* Cz = (float*)Cp + (size_t)blockIdx.z * 8192 * ldc;
#pragma unroll
    for (int nj = 0; nj < 4; ++nj) {
      int col = bn + wc * 64 + nj * 16 + lr;
#pragma unroll
      for (int mi = 0; mi < 4; ++mi) {
        int row0 = bm + wr * 64 + mi * 16 + ls * 4;
#pragma unroll
        for (int r = 0; r < 4; ++r)
          Cz[(size_t)(row0 + r) * ldc + col] = acc[mi][nj][r];
      }
    }
  } else {
#pragma unroll
    for (int nj = 0; nj < 4; ++nj) {
      int col = bn + wc * 64 + nj * 16 + lr;
      float bv = bias ? bias[col] : 0.f;
#pragma unroll
      for (int mi = 0; mi < 4; ++mi) {
        int row0 = bm + wr * 64 + mi * 16 + ls * 4;
#pragma unroll
        for (int r = 0; r < 4; ++r) {
          float v = acc[mi][nj][r] + bv;
          if (ACT == 1) v = fmaxf(v, 0.f);
          if (CBF)
            ((ushort_t*)Cp)[(size_t)(row0 + r) * ldc + col] = f2bf(v);
          else
            ((float*)Cp)[(size_t)(row0 + r) * ldc + col] = v;
        }
      }
    }
  }
}

// ---------------------------------------------------------------------------
// split-K=2 reduce: out = p[0..]+p[4M..] + bias (N=512 shapes only)
// ---------------------------------------------------------------------------
__global__ __launch_bounds__(256) void splitk_reduce(const float* __restrict__ p,
                                                     const float* __restrict__ bias,
                                                     float* __restrict__ out) {
  int i = blockIdx.x * 256 + threadIdx.x;            // float4 index, 1M total
  float4 a = ((const float4*)p)[i];
  float4 b = ((const float4*)p)[i + 1048576];
  float4 o = {a.x + b.x, a.y + b.y, a.z + b.z, a.w + b.w};
  if (bias) {
    float4 bb = ((const float4*)bias)[i & 127];
    o.x += bb.x; o.y += bb.y; o.z += bb.z; o.w += bb.w;
  }
  ((float4*)out)[i] = o;
}

// ---------------------------------------------------------------------------
// Generic fp32 tiled SGEMM (small shapes: xproj N=64, dt K=32)
// ACT: 0 none, 2 softplus
// ---------------------------------------------------------------------------
template <int ACT>
__global__ __launch_bounds__(256) void gemm_tn(const float* __restrict__ A,
                                               const float* __restrict__ W,
                                               const float* __restrict__ bias,
                                               float* __restrict__ C,
                                               int M, int N, int K, int lda, int ldc) {
  __shared__ float As[16][65];
  __shared__ float Ws[16][65];
  const int bm = blockIdx.y * 64, bn = blockIdx.x * 64;
  const int tid = threadIdx.x;
  const int lk = tid & 15, lr = tid >> 4;
  const int tx = tid & 15, ty = tid >> 4;
  float acc[4][4] = {};
  for (int k0 = 0; k0 < K; k0 += 16) {
#pragma unroll
    for (int i = 0; i < 4; ++i) {
      As[lk][lr + 16 * i] = A[(size_t)(bm + lr + 16 * i) * lda + k0 + lk];
      Ws[lk][lr + 16 * i] = W[(size_t)(bn + lr + 16 * i) * K + k0 + lk];
    }
    __syncthreads();
#pragma unroll
    for (int kk = 0; kk < 16; ++kk) {
      float a[4], w[4];
#pragma unroll
      for (int i = 0; i < 4; ++i) a[i] = As[kk][ty + 16 * i];
#pragma unroll
      for (int j = 0; j < 4; ++j) w[j] = Ws[kk][tx + 16 * j];
#pragma unroll
      for (int i = 0; i < 4; ++i)
#pragma unroll
        for (int j = 0; j < 4; ++j) acc[i][j] += a[i] * w[j];
    }
    __syncthreads();
  }
#pragma unroll
  for (int i = 0; i < 4; ++i) {
    int r = bm + ty + 16 * i;
#pragma unroll
    for (int j = 0; j < 4; ++j) {
      int c = bn + tx + 16 * j;
      float v = acc[i][j];
      if (bias) v += bias[c];
      if (ACT == 2) v = (v > 20.f) ? v : log1pf(__expf(v));
      C[(size_t)r * ldc + c] = v;
    }
  }
}

// ---------------------------------------------------------------------------
// Depthwise causal conv (width 4) + SiLU.  xm = xz[:, :DINNER] (row stride 2048)
// ---------------------------------------------------------------------------
__global__ __launch_bounds__(256) void conv_silu_kernel(const float* __restrict__ xz,
                                                        const float* __restrict__ cw,
                                                        const float* __restrict__ cb,
                                                        float* __restrict__ xc) {
  int idx = blockIdx.x * 256 + threadIdx.x;        // ((b*L)+t)*1024 + d
  int d = idx & 1023;
  int t = (idx >> 10) & 1023;
  int b = idx >> 20;
  float acc = cb[d];
#pragma unroll
  for (int w = 0; w < 4; ++w) {
    int tt = t - 3 + w;
    if (tt >= 0) acc += xz[(((size_t)(b * 1024 + tt)) << 11) + d] * cw[d * 4 + w];
  }
  xc[idx] = silu_f(acc);
}

// ---------------------------------------------------------------------------
// Chunked selective scan, pass 1: per (b,d,chunk) scan 64 steps, init=0.
// Software-pipelined dt/xc loads; xdb B-row via float4.
// ---------------------------------------------------------------------------
__global__ __launch_bounds__(256) void scan_pass1(const float* __restrict__ dt,
                                                  const float* __restrict__ xdb,
                                                  const float* __restrict__ xc,
                                                  const float* __restrict__ Alog,
                                                  float* __restrict__ scrP,
                                                  float* __restrict__ scrL) {
  int idx = blockIdx.x * 256 + threadIdx.x;        // ((b*16 + c)*1024 + d)
  int d = idx & 1023;
  int c = (idx >> 10) & 15;
  int b = idx >> 14;
  float A[16], st[16], P[16];
#pragma unroll
  for (int s = 0; s < 16; ++s) {
    A[s] = -__expf(Alog[d * 16 + s]);
    st[s] = 0.f;
    P[s] = 1.f;
  }
  int t0 = c * CLEN;
  size_t base = (((size_t)(b * 1024 + t0)) << 10) + d;
  const float* xb = xdb + (size_t)(b * 1024 + t0) * 64;
  float dtv = dt[base], xv = xc[base];
  for (int t = 0; t < CLEN; ++t) {
    float dtn = 0.f, xvn = 0.f;
    if (t + 1 < CLEN) { dtn = dt[base + 1024]; xvn = xc[base + 1024]; }
    float Bv[16];
    *(float4*)&Bv[0]  = *(const float4*)(xb + 32);
    *(float4*)&Bv[4]  = *(const float4*)(xb + 36);
    *(float4*)&Bv[8]  = *(const float4*)(xb + 40);
    *(float4*)&Bv[12] = *(const float4*)(xb + 44);
    float dx = dtv * xv;
#pragma unroll
    for (int s = 0; s < 16; ++s) {
      float e = __expf(dtv * A[s]);
      st[s] = st[s] * e + dx * Bv[s];
      P[s] *= e;
    }
    base += 1024; xb += 64;
    dtv = dtn; xv = xvn;
  }
  size_t pbase = (((size_t)((b * 16 + c) * 16)) << 10) + d;
#pragma unroll
  for (int s = 0; s < 16; ++s) {
    scrP[pbase + ((size_t)s << 10)] = P[s];
    scrL[pbase + ((size_t)s << 10)] = st[s];
  }
}

// ---------------------------------------------------------------------------
// Pass 2: combine chunks serially per (b,d,s).
// ---------------------------------------------------------------------------
__global__ __launch_bounds__(256) void scan_pass2(const float* __restrict__ scrP,
                                                  float* __restrict__ scrL) {
  int idx = blockIdx.x * 256 + threadIdx.x;        // ((b*16 + s)*1024 + d)
  int d = idx & 1023;
  int s = (idx >> 10) & 15;
  int b = idx >> 14;
  float cur = 0.f;
  for (int c = 0; c < 16; ++c) {
    size_t o = (((size_t)(((b * 16 + c) * 16) + s)) << 10) + d;
    float P = scrP[o];
    float loc = scrL[o];
    scrL[o] = cur;
    cur = cur * P + loc;
  }
}

// ---------------------------------------------------------------------------
// Pass 3: rescan with correct init; gated y -> bf16 ybf. Pipelined loads.
// ---------------------------------------------------------------------------
__global__ __launch_bounds__(256) void scan_pass3(const float* __restrict__ dt,
                                                  const float* __restrict__ xdb,
                                                  const float* __restrict__ xc,
                                                  const float* __restrict__ xz,
                                                  ushort_t* __restrict__ ybf,
                                                  const float* __restrict__ Alog,
                                                  const float* __restrict__ Dp,
                                                  const float* __restrict__ scrL) {
  int idx = blockIdx.x * 256 + threadIdx.x;        // ((b*16 + c)*1024 + d)
  int d = idx & 1023;
  int c = (idx >> 10) & 15;
  int b = idx >> 14;
  float A[16], st[16];
  size_t pbase = (((size_t)((b * 16 + c) * 16)) << 10) + d;
#pragma unroll
  for (int s = 0; s < 16; ++s) {
    A[s] = -__expf(Alog[d * 16 + s]);
    st[s] = scrL[pbase + ((size_t)s << 10)];
  }
  float Dv = Dp[d];
  int t0 = c * CLEN;
  size_t base = (((size_t)(b * 1024 + t0)) << 10) + d;
  size_t zoff = ((((size_t)(b * 1024 + t0)) << 11)) + 1024 + d;
  const float* xb = xdb + (size_t)(b * 1024 + t0) * 64;
  float dtv = dt[base], xv = xc[base], zv = xz[zoff];
  for (int t = 0; t < CLEN; ++t) {
    float dtn = 0.f, xvn = 0.f, zvn = 0.f;
    if (t + 1 < CLEN) {
      dtn = dt[base + 1024]; xvn = xc[base + 1024]; zvn = xz[zoff + 2048];
    }
    float Bv[16], Cv[16];
    *(float4*)&Bv[0]  = *(const float4*)(xb + 32);
    *(float4*)&Bv[4]  = *(const float4*)(xb + 36);
    *(float4*)&Bv[8]  = *(const float4*)(xb + 40);
    *(float4*)&Bv[12] = *(const float4*)(xb + 44);
    *(float4*)&Cv[0]  = *(const float4*)(xb + 48);
    *(float4*)&Cv[4]  = *(const float4*)(xb + 52);
    *(float4*)&Cv[8]  = *(const float4*)(xb + 56);
    *(float4*)&Cv[12] = *(const float4*)(xb + 60);
    float dx = dtv * xv;
    float acc = 0.f;
#pragma unroll
    for (int s = 0; s < 16; ++s) {
      float e = __expf(dtv * A[s]);
      st[s] = st[s] * e + dx * Bv[s];
      acc += st[s] * Cv[s];
    }
    ybf[base] = f2bf((acc + Dv * xv) * silu_f(zv));
    base += 1024; zoff += 2048; xb += 64;
    dtv = dtn; xv = xvn; zv = zvn;
  }
}

// ---------------------------------------------------------------------------
// Residual + LayerNorm. add / out_bf may be nullptr.
// ---------------------------------------------------------------------------
__global__ __launch_bounds__(128) void resid_ln_kernel(const float* __restrict__ x,
                                                       const float* __restrict__ add,
                                                       const float* __restrict__ w,
                                                       const float* __restrict__ bias,
                                                       float* __restrict__ out,
                                                       ushort_t* __restrict__ out_bf) {
  int row = blockIdx.x, tid = threadIdx.x;
  float4 v = ((const float4*)(x + (size_t)row * 512))[tid];
  if (add) {
    float4 a = ((const float4*)(add + (size_t)row * 512))[tid];
    v.x += a.x; v.y += a.y; v.z += a.z; v.w += a.w;
  }
  float s = v.x + v.y + v.z + v.w;
  float ss = v.x * v.x + v.y * v.y + v.z * v.z + v.w * v.w;
#pragma unroll
  for (int o = 32; o; o >>= 1) {
    s += __shfl_xor(s, o);
    ss += __shfl_xor(ss, o);
  }
  __shared__ float red[4];
  int wid = tid >> 6;
  if ((tid & 63) == 0) { red[wid] = s; red[2 + wid] = ss; }
  __syncthreads();
  s = red[0] + red[1];
  ss = red[2] + red[3];
  float mean = s * (1.f / 512.f);
  float var = ss * (1.f / 512.f) - mean * mean;
  float inv = rsqrtf(var + 1e-5f);
  float4 wv = ((const float4*)w)[tid];
  float4 bv = ((const float4*)bias)[tid];
  float4 ov;
  ov.x = (v.x - mean) * inv * wv.x + bv.x;
  ov.y = (v.y - mean) * inv * wv.y + bv.y;
  ov.z = (v.z - mean) * inv * wv.z + bv.z;
  ov.w = (v.w - mean) * inv * wv.w + bv.w;
  ((float4*)(out + (size_t)row * 512))[tid] = ov;
  if (out_bf) {
    us4 ob = {f2bf(ov.x), f2bf(ov.y), f2bf(ov.z), f2bf(ov.w)};
    ((us4*)(out_bf + (size_t)row * 512))[tid] = ob;
  }
}

// ---------------------------------------------------------------------------
// Sinusoidal positional encoding add (in-place on h, refresh hbf)
// ---------------------------------------------------------------------------
__global__ __launch_bounds__(256) void posenc_kernel(float* __restrict__ h,
                                                     ushort_t* __restrict__ hbf) {
  int idx = blockIdx.x * 256 + threadIdx.x;
  int d = idx & 511;
  int l = (idx >> 9) & 1023;
  float freq = __expf(-(float)(d & ~1) * (9.210340371976184f / 512.f));
  float ang = (float)l * freq;
  float v = h[idx] + ((d & 1) ? cosf(ang) : sinf(ang));
  h[idx] = v;
  hbf[idx] = f2bf(v);
}

// ---------------------------------------------------------------------------
// MFMA flash attention, bf16 qkv input. One block = (b, head, 64 q-rows).
// ---------------------------------------------------------------------------
__global__ __launch_bounds__(256) void attn_mfma(const ushort_t* __restrict__ qkv,
                                                 ushort_t* __restrict__ ao) {
  __shared__ unsigned short Qs[4096];
  __shared__ unsigned short Ks[4096];
  __shared__ unsigned short Vt[4096];
  __shared__ unsigned short Ps[4096];
  const int tid = threadIdx.x;
  const int blk = blockIdx.x;                    // ((b*8 + h)*16 + qt)
  const int qt = blk & 15, hh = (blk >> 4) & 7, b = blk >> 7;
  const int l0 = qt * 64;
  const size_t bb = (size_t)b * 1024 * 1536;

  const int srow = tid >> 2;                     // staging row 0..63
  const int sdb = (tid & 3) << 4;                // staging d-block 0/16/32/48
  const int sc0 = sdb >> 3;

  {
    const ushort_t* qp = qkv + bb + (size_t)(l0 + srow) * 1536 + hh * 64 + sdb;
    *(bfrag*)&Qs[srow * 64 + ((sc0 ^ (srow & 7)) << 3)] = *(const bfrag*)qp;
    *(bfrag*)&Qs[srow * 64 + (((sc0 + 1) ^ (srow & 7)) << 3)] = *(const bfrag*)(qp + 8);
  }

  const int wid = tid >> 6, lane = tid & 63;
  const int l15 = lane & 15, rg = lane >> 4;
  const int l7 = l15 & 7;
  float m[4], lsum[4];
  f32x4 oacc[4];
#pragma unroll
  for (int r = 0; r < 4; ++r) { m[r] = -1e30f; lsum[r] = 0.f; }
#pragma unroll
  for (int nt = 0; nt < 4; ++nt) oacc[nt] = (f32x4)(0.f);

  for (int jt = 0; jt < 16; ++jt) {
    {
      const ushort_t* kp = qkv + bb + (size_t)(jt * 64 + srow) * 1536 + hh * 64 + 512 + sdb;
      *(bfrag*)&Ks[srow * 64 + ((sc0 ^ (srow & 7)) << 3)] = *(const bfrag*)kp;
      *(bfrag*)&Ks[srow * 64 + (((sc0 + 1) ^ (srow & 7)) << 3)] = *(const bfrag*)(kp + 8);
      const ushort_t* vp = kp + 512;
      unsigned short vv[16];
      *(bfrag*)&vv[0] = *(const bfrag*)vp;
      *(bfrag*)&vv[8] = *(const bfrag*)(vp + 8);
#pragma unroll
      for (int j = 0; j < 16; ++j) {
        int dd = sdb + j;
        Vt[dd * 64 + (((srow >> 3) ^ (dd & 7)) << 3) + (srow & 7)] = vv[j];
      }
    }
    __syncthreads();

    bfrag aq[2];
#pragma unroll
    for (int ks = 0; ks < 2; ++ks)
      aq[ks] = *(const bfrag*)&Qs[(wid * 16 + l15) * 64 + (((ks * 4 + rg) ^ l7) << 3)];
    f32x4 sc[4];
#pragma unroll
    for (int nt = 0; nt < 4; ++nt) {
      f32x4 s = (f32x4)(0.f);
#pragma unroll
      for (int ks = 0; ks < 2; ++ks) {
        bfrag bk = *(const bfrag*)&Ks[(nt * 16 + l15) * 64 + (((ks * 4 + rg) ^ l7) << 3)];
        s = __builtin_amdgcn_mfma_f32_16x16x32_bf16(aq[ks], bk, s, 0, 0, 0);
      }
      sc[nt] = s * 0.125f;
    }

#pragma unroll
    for (int r = 0; r < 4; ++r) {
      float mc = fmaxf(fmaxf(sc[0][r], sc[1][r]), fmaxf(sc[2][r], sc[3][r]));
#pragma unroll
      for (int o = 8; o; o >>= 1) mc = fmaxf(mc, __shfl_xor(mc, o));
      float mn = fmaxf(m[r], mc);
      float al = __expf(m[r] - mn);
      m[r] = mn;
      int prow = rg * 4 + r;
      float ps = 0.f;
#pragma unroll
      for (int nt = 0; nt < 4; ++nt) {
        float p = __expf(sc[nt][r] - mn);
        ps += p;
        int col = nt * 16 + l15;
        Ps[wid * 1024 + prow * 64 + ((((col >> 3) ^ (prow & 7))) << 3) + (col & 7)] = f2bf(p);
      }
#pragma unroll
      for (int o = 8; o; o >>= 1) ps += __shfl_xor(ps, o);
      lsum[r] = lsum[r] * al + ps;
#pragma unroll
      for (int nt = 0; nt < 4; ++nt) oacc[nt][r] *= al;
    }

    bfrag ap[2];
#pragma unroll
    for (int ks = 0; ks < 2; ++ks)
      ap[ks] = *(const bfrag*)&Ps[wid * 1024 + l15 * 64 + (((ks * 4 + rg) ^ l7) << 3)];
#pragma unroll
    for (int nt = 0; nt < 4; ++nt) {
#pragma unroll
      for (int ks = 0; ks < 2; ++ks) {
        bfrag bv = *(const bfrag*)&Vt[(nt * 16 + l15) * 64 + (((ks * 4 + rg) ^ l7) << 3)];
        oacc[nt] = __builtin_amdgcn_mfma_f32_16x16x32_bf16(ap[ks], bv, oacc[nt], 0, 0, 0);
      }
    }
    __syncthreads();
  }

#pragma unroll
  for (int r = 0; r < 4; ++r) {
    float inv = 1.f / lsum[r];
    int row = l0 + wid * 16 + rg * 4 + r;
    ushort_t* op = ao + ((size_t)(b * 1024 + row)) * 512 + hh * 64;
#pragma unroll
    for (int nt = 0; nt < 4; ++nt) op[nt * 16 + l15] = f2bf(oacc[nt][r] * inv);
  }
}

// ---------------------------------------------------------------------------
// Mean over L, two-pass. part[(b*16+lc)][d] then final sum.
// ---------------------------------------------------------------------------
__global__ __launch_bounds__(512) void mean_part(const float* __restrict__ h,
                                                 float* __restrict__ part) {
  int blk = blockIdx.x;                       // b*16 + lc
  int b = blk >> 4, lc = blk & 15, d = threadIdx.x;
  float s = 0.f;
  int l0 = lc * 64;
  for (int l = l0; l < l0 + 64; ++l) s += h[(((size_t)(b * 1024 + l)) << 9) + d];
  part[((size_t)blk << 9) + d] = s;
}
__global__ __launch_bounds__(256) void mean_final(const float* __restrict__ part,
                                                  float* __restrict__ out2) {
  int i = blockIdx.x * 256 + threadIdx.x;     // b*512 + d
  int b = i >> 9, d = i & 511;
  float s = 0.f;
#pragma unroll
  for (int c = 0; c < 16; ++c) s += part[(((size_t)(b * 16 + c)) << 9) + d];
  out2[i] = s * (1.f / 1024.f);
}

// ---------------------------------------------------------------------------
extern "C" void kernel_launch(void* const* d_in, const int* in_sizes, int n_in,
                              void* d_out, int out_size, void* d_ws, size_t ws_size,
                              hipStream_t stream) {
  const float* x        = (const float*)d_in[0];
  const float* proj_w   = (const float*)d_in[1];
  const float* proj_b   = (const float*)d_in[2];
  const float* m_in_w   = (const float*)d_in[3];
  const float* m_conv_w = (const float*)d_in[4];
  const float* m_conv_b = (const float*)d_in[5];
  const float* m_xproj_w= (const float*)d_in[6];
  const float* m_dt_w   = (const float*)d_in[7];
  const float* m_dt_b   = (const float*)d_in[8];
  const float* m_Alog   = (const float*)d_in[9];
  const float* m_D      = (const float*)d_in[10];
  const float* m_out_w  = (const float*)d_in[11];
  const float* m_ln_w   = (const float*)d_in[12];
  const float* m_ln_b   = (const float*)d_in[13];
  const float* t_qkv_w  = (const float*)d_in[14];
  const float* t_qkv_b  = (const float*)d_in[15];
  const float* t_ow     = (const float*)d_in[16];
  const float* t_ob     = (const float*)d_in[17];
  const float* t_l1w    = (const float*)d_in[18];
  const float* t_l1b    = (const float*)d_in[19];
  const float* t_l2w    = (const float*)d_in[20];
  const float* t_l2b    = (const float*)d_in[21];
  const float* t_ln1w   = (const float*)d_in[22];
  const float* t_ln1b   = (const float*)d_in[23];
  const float* t_ln2w   = (const float*)d_in[24];
  const float* t_ln2b   = (const float*)d_in[25];
  const float* no_w     = (const float*)d_in[26];
  const float* no_b     = (const float*)d_in[27];

  float* ws   = (float*)d_ws;
  float* h    = ws;                                   //  4M f
  ushort_t* h_bf = (ushort_t*)(ws + 4194304);         //  4M us (2M f)
  float* bufA = ws + 6291456;                         // 16M f (xz f32 / qkv_bf / ff1_bf)
  float* bufB = bufA + 16777216;                      //  8M f (xc f32 / ao_bf)
  float* bufC = bufB + 8388608;                       //  8M f (dt / split-K partials)
  float* bufE = bufC + 8388608;                       //  4M f (scan scratch / GEMM out)
  float* bufF = bufE + 4194304;                       //  0.5M f (xdb / mean partials)
  ushort_t* y_bf = (ushort_t*)(bufF + 524288);        //  8M us (4M f)
  ushort_t* wbf  = (ushort_t*)(bufF + 524288 + 4194304);  // 9.44M us
  float* scrP = bufE;
  float* scrL = bufE + 2097152;
  const int M = MTOK;

  // bf16 weight pool offsets (ushort units)
  ushort_t* wIN  = wbf;                 // 2 x 2048 x 512
  ushort_t* wOUT = wbf + 2097152;       // 2 x 512 x 1024
  ushort_t* wQKV = wbf + 3145728;       // 2 x 1536 x 512
  ushort_t* wOW  = wbf + 4718592;       // 2 x 512 x 512
  ushort_t* wL1  = wbf + 5242880;       // 2 x 2048 x 512
  ushort_t* wL2  = wbf + 7340032;       // 2 x 512 x 2048

  cvt_bf16<<<2048, 256, 0, stream>>>(m_in_w,  wIN,  524288);
  cvt_bf16<<<1024, 256, 0, stream>>>(m_out_w, wOUT, 262144);
  cvt_bf16<<<1536, 256, 0, stream>>>(t_qkv_w, wQKV, 393216);
  cvt_bf16<<< 512, 256, 0, stream>>>(t_ow,    wOW,  131072);
  cvt_bf16<<<2048, 256, 0, stream>>>(t_l1w,   wL1,  524288);
  cvt_bf16<<<2048, 256, 0, stream>>>(t_l2w,   wL2,  524288);

  proj_kernel<<<16384, 256, 0, stream>>>(x, proj_w, proj_b, h, h_bf);

  for (int i = 0; i < 2; ++i) {
    // xz = h @ in_w^T   (8192 x 2048, K=512) -> fp32
    gemm_gll<0, 0, 1><<<dim3(16, 64), 256, 0, stream>>>(
        h_bf, wIN + (size_t)i * 1048576, nullptr, bufA, DMODEL, DMODEL, 2 * DINNER);
    // xc = silu(causal_conv(xm))
    conv_silu_kernel<<<32768, 256, 0, stream>>>(bufA, m_conv_w + i * DINNER * 4,
                                                m_conv_b + i * DINNER, bufB);
    // xdb = xc @ xp_w^T  (8192 x 64, K=1024) fp32
    gemm_tn<0><<<dim3(1, M / 64), 256, 0, stream>>>(
        bufB, m_xproj_w + (size_t)i * 64 * DINNER, nullptr, bufF,
        M, 64, DINNER, DINNER, 64);
    // dt = softplus(xdb[:, :32] @ dt_w^T + dt_b) fp32
    gemm_tn<2><<<dim3(DINNER / 64, M / 64), 256, 0, stream>>>(
        bufF, m_dt_w + (size_t)i * DINNER * DTRANK, m_dt_b + i * DINNER, bufC,
        M, DINNER, DTRANK, 64, DINNER);
    // chunked selective scan -> y_bf (bf16)
    scan_pass1<<<512, 256, 0, stream>>>(bufC, bufF, bufB,
                                        m_Alog + (size_t)i * DINNER * DSTATE, scrP, scrL);
    scan_pass2<<<512, 256, 0, stream>>>(scrP, scrL);
    scan_pass3<<<512, 256, 0, stream>>>(bufC, bufF, bufB, bufA, y_bf,
                                        m_Alog + (size_t)i * DINNER * DSTATE,
                                        m_D + i * DINNER, scrL);
    // mamba_out = y @ out_w^T  (8192 x 512, K=1024), split-K=2 (dt is dead)
    gemm_gll<0, 0, 2><<<dim3(4, 64, 2), 256, 0, stream>>>(
        y_bf, wOUT + (size_t)i * 524288, nullptr, bufC, DINNER, DINNER, DMODEL);
    splitk_reduce<<<4096, 256, 0, stream>>>(bufC, nullptr, bufE);
    // h = LN(h + mamba_out), refresh h_bf
    resid_ln_kernel<<<8192, 128, 0, stream>>>(h, bufE, m_ln_w + i * DMODEL,
                                              m_ln_b + i * DMODEL, h, h_bf);
  }

  posenc_kernel<<<16384, 256, 0, stream>>>(h, h_bf);

  for (int i = 0; i < 2; ++i) {
    // qkv = h @ qkv_w^T + qkv_b  (8192 x 1536, K=512) -> bf16
    gemm_gll<0, 1, 1><<<dim3(12, 64), 256, 0, stream>>>(
        h_bf, wQKV + (size_t)i * 786432, t_qkv_b + i * 3 * DMODEL, bufA,
        DMODEL, DMODEL, 3 * DMODEL);
    // MFMA flash attention -> ao bf16
    attn_mfma<<<1024, 256, 0, stream>>>((const ushort_t*)bufA, (ushort_t*)bufB);
    // attn_proj = ao @ ow^T + ob  (8192 x 512, K=512), split-K=2
    gemm_gll<0, 0, 2><<<dim3(4, 64, 2), 256, 0, stream>>>(
        (const ushort_t*)bufB, wOW + (size_t)i * 262144, nullptr, bufC,
        DMODEL, DMODEL, DMODEL);
    splitk_reduce<<<4096, 256, 0, stream>>>(bufC, t_ob + i * DMODEL, bufE);
    // h = LN(h + attn_proj)
    resid_ln_kernel<<<8192, 128, 0, stream>>>(h, bufE, t_ln1w + i * DMODEL,
                                              t_ln1b + i * DMODEL, h, h_bf);
    // ff1 = relu(h @ l1w^T + l1b)  (8192 x 2048, K=512) -> bf16
    gemm_gll<1, 1, 1><<<dim3(16, 64), 256, 0, stream>>>(
        h_bf, wL1 + (size_t)i * 1048576, t_l1b + i * DFF, bufA,
        DMODEL, DMODEL, DFF);
    // ff2 = ff1 @ l2w^T + l2b  (8192 x 512, K=2048), split-K=2
    gemm_gll<0, 0, 2><<<dim3(4, 64, 2), 256, 0, stream>>>(
        (const ushort_t*)bufA, wL2 + (size_t)i * 1048576, nullptr, bufC,
        DFF, DFF, DMODEL);
    splitk_reduce<<<4096, 256, 0, stream>>>(bufC, t_l2b + i * DMODEL, bufE);
    // h = LN(h + ff2)
    resid_ln_kernel<<<8192, 128, 0, stream>>>(h, bufE, t_ln2w + i * DMODEL,
                                              t_ln2b + i * DMODEL, h, h_bf);
  }

  // final LN -> d_out, then mean over L -> d_out tail
  float* out_h = (float*)d_out;
  resid_ln_kernel<<<8192, 128, 0, stream>>>(h, nullptr, no_w, no_b, out_h, nullptr);
  mean_part<<<128, 512, 0, stream>>>(out_h, bufF);
  mean_final<<<16, 256, 0, stream>>>(bufF, out_h + 4194304);
}

// Round 7
// 1144.557 us; speedup vs baseline: 1.2687x; 1.1481x over previous
//
#include <hip/hip_runtime.h>
#include <cstddef>

// Problem constants
#define BATCH 8
#define LSEQ 1024
#define DMODEL 512
#define DINNER 1024
#define DSTATE 16
#define DTRANK 32
#define NHEAD 8
#define DHEAD 64
#define DFF 2048
#define MTOK 8192   // BATCH*LSEQ
#define NCHUNK 16
#define CLEN 64     // LSEQ / NCHUNK

typedef __attribute__((ext_vector_type(8))) short bfrag;          // 8 bf16 = 16 B
typedef __attribute__((ext_vector_type(4))) float f32x4;          // MFMA acc
typedef __attribute__((ext_vector_type(4))) unsigned short us4;
typedef unsigned short ushort_t;

__device__ __forceinline__ float silu_f(float x) { return x / (1.f + __expf(-x)); }

__device__ __forceinline__ unsigned short f2bf(float f) {  // RNE fp32->bf16
  unsigned u = __float_as_uint(f);
  return (unsigned short)((u + 0x7FFFu + ((u >> 16) & 1u)) >> 16);
}

// async global->LDS, 16B per lane. LDS dest = wave-uniform base + lane*16.
__device__ __forceinline__ void gll16(const ushort_t* g, ushort_t* l) {
  __builtin_amdgcn_global_load_lds(
      (const __attribute__((address_space(1))) unsigned int*)g,
      (__attribute__((address_space(3))) unsigned int*)l, 16, 0, 0);
}

// ---------------------------------------------------------------------------
// fp32 -> bf16 bulk convert (vectorized x4). n4 = element count / 4.
// ---------------------------------------------------------------------------
__global__ __launch_bounds__(256) void cvt_bf16(const float* __restrict__ s,
                                                ushort_t* __restrict__ d, int n4) {
  int i = blockIdx.x * 256 + threadIdx.x;
  if (i >= n4) return;
  float4 v = ((const float4*)s)[i];
  us4 o = {f2bf(v.x), f2bf(v.y), f2bf(v.z), f2bf(v.w)};
  ((us4*)d)[i] = o;
}

// ---------------------------------------------------------------------------
// Input projection: h[b,l,d] = sum_c x[b,c,l] * pw[d,c] + pb[d]; also bf16 copy.
// ---------------------------------------------------------------------------
__global__ __launch_bounds__(256) void proj_kernel(const float* __restrict__ x,
                                                   const float* __restrict__ pw,
                                                   const float* __restrict__ pb,
                                                   float* __restrict__ h,
                                                   ushort_t* __restrict__ hbf) {
  int idx = blockIdx.x * 256 + threadIdx.x;        // ((b*L)+l)*512 + d
  int d = idx & 511;
  int l = (idx >> 9) & 1023;
  int b = idx >> 19;
  const float* xb = x + (size_t)b * 3 * 1024 + l;
  float v = pb[d] + xb[0] * pw[d * 3] + xb[1024] * pw[d * 3 + 1] + xb[2048] * pw[d * 3 + 2];
  h[idx] = v;
  hbf[idx] = f2bf(v);
}

// ---------------------------------------------------------------------------
// bf16 MFMA GEMM, global_load_lds + double-buffered prefetch.
// C[m,n] = act( sum_k A[m,k]*W[n,k] + bias[n] ).  Tile 128x128, BK=32.
// ACT: 0 none, 1 relu. CBF: 1 bf16 C, 0 fp32 C.
// SPLITK: 1 direct; 2 -> fp32 partials at Cp + z*8192*ldc (no bias/act).
// ---------------------------------------------------------------------------
template <int ACT, int CBF, int SPLITK>
__global__ __launch_bounds__(256) void gemm_gll(const ushort_t* __restrict__ A,
                                                const ushort_t* __restrict__ W,
                                                const float* __restrict__ bias,
                                                void* __restrict__ Cp,
                                                int K, int lda, int ldc) {
  __shared__ ushort_t sA[2][4096];
  __shared__ ushort_t sB[2][4096];
  const int bm = blockIdx.y * 128, bn = blockIdx.x * 128;
  const int tid = threadIdx.x;
  const int wid = tid >> 6, lane = tid & 63;
  const int wr = wid >> 1, wc = wid & 1;
  const int lr = lane & 15, ls = lane >> 4;
  const int sw = ls ^ ((lr >> 1) & 3);

  const int kseg = K / SPLITK;
  const int kbeg = (SPLITK > 1) ? blockIdx.z * kseg : 0;

  const int c0 = wid * 128 + lane;
  const int c1 = c0 + 64;
  const int r0 = c0 >> 2, s0 = (c0 & 3) ^ ((r0 >> 1) & 3);
  const int r1 = c1 >> 2, s1 = (c1 & 3) ^ ((r1 >> 1) & 3);
  const ushort_t* gA0 = A + (size_t)(bm + r0) * lda + kbeg + s0 * 8;
  const ushort_t* gA1 = A + (size_t)(bm + r1) * lda + kbeg + s1 * 8;
  const ushort_t* gB0 = W + (size_t)(bn + r0) * K + kbeg + s0 * 8;
  const ushort_t* gB1 = W + (size_t)(bn + r1) * K + kbeg + s1 * 8;

  f32x4 acc[4][4];
#pragma unroll
  for (int i = 0; i < 4; ++i)
#pragma unroll
    for (int j = 0; j < 4; ++j) acc[i][j] = (f32x4)(0.f);

#define STAGE(buf, step)                                           \
  do {                                                             \
    gll16(gA0 + (step) * 32, &sA[buf][wid * 1024]);                \
    gll16(gA1 + (step) * 32, &sA[buf][wid * 1024 + 512]);          \
    gll16(gB0 + (step) * 32, &sB[buf][wid * 1024]);                \
    gll16(gB1 + (step) * 32, &sB[buf][wid * 1024 + 512]);          \
  } while (0)

  const int NT = kseg / 32;
  STAGE(0, 0);
  for (int t = 0; t < NT; ++t) {
    const int cur = t & 1;
    if (t + 1 < NT) {
      STAGE(cur ^ 1, t + 1);
      asm volatile("s_waitcnt vmcnt(4)" ::: "memory");
    } else {
      asm volatile("s_waitcnt vmcnt(0)" ::: "memory");
    }
    __builtin_amdgcn_sched_barrier(0);
    __builtin_amdgcn_s_barrier();
    __builtin_amdgcn_sched_barrier(0);

    bfrag af[4], bf[4];
#pragma unroll
    for (int mi = 0; mi < 4; ++mi) {
      int row = wr * 64 + mi * 16 + lr;
      af[mi] = *(const bfrag*)&sA[cur][(size_t)((row << 2) + sw) * 8];
    }
#pragma unroll
    for (int nj = 0; nj < 4; ++nj) {
      int col = wc * 64 + nj * 16 + lr;
      bf[nj] = *(const bfrag*)&sB[cur][(size_t)((col << 2) + sw) * 8];
    }
#pragma unroll
    for (int mi = 0; mi < 4; ++mi)
#pragma unroll
      for (int nj = 0; nj < 4; ++nj)
        acc[mi][nj] = __builtin_amdgcn_mfma_f32_16x16x32_bf16(af[mi], bf[nj], acc[mi][nj], 0, 0, 0);

    __builtin_amdgcn_s_barrier();
    __builtin_amdgcn_sched_barrier(0);
  }
#undef STAGE

  if (SPLITK > 1) {
    float* Cz = (float*)Cp + (size_t)blockIdx.z * 8192 * ldc;
#pragma unroll
    for (int nj = 0; nj < 4; ++nj) {
      int col = bn + wc * 64 + nj * 16 + lr;
#pragma unroll
      for (int mi = 0; mi < 4; ++mi) {
        int row0 = bm + wr * 64 + mi * 16 + ls * 4;
#pragma unroll
        for (int r = 0; r < 4; ++r)
          Cz[(size_t)(row0 + r) * ldc + col] = acc[mi][nj][r];
      }
    }
  } else {
#pragma unroll
    for (int nj = 0; nj < 4; ++nj) {
      int col = bn + wc * 64 + nj * 16 + lr;
      float bv = bias ? bias[col] : 0.f;
#pragma unroll
      for (int mi = 0; mi < 4; ++mi) {
        int row0 = bm + wr * 64 + mi * 16 + ls * 4;
#pragma unroll
        for (int r = 0; r < 4; ++r) {
          float v = acc[mi][nj][r] + bv;
          if (ACT == 1) v = fmaxf(v, 0.f);
          if (CBF)
            ((ushort_t*)Cp)[(size_t)(row0 + r) * ldc + col] = f2bf(v);
          else
            ((float*)Cp)[(size_t)(row0 + r) * ldc + col] = v;
        }
      }
    }
  }
}

// ---------------------------------------------------------------------------
// split-K=2 reduce: out = p[0..]+p[4M..] + bias (N=512 shapes only)
// ---------------------------------------------------------------------------
__global__ __launch_bounds__(256) void splitk_reduce(const float* __restrict__ p,
                                                     const float* __restrict__ bias,
                                                     float* __restrict__ out) {
  int i = blockIdx.x * 256 + threadIdx.x;            // float4 index, 1M total
  float4 a = ((const float4*)p)[i];
  float4 b = ((const float4*)p)[i + 1048576];
  float4 o = {a.x + b.x, a.y + b.y, a.z + b.z, a.w + b.w};
  if (bias) {
    float4 bb = ((const float4*)bias)[i & 127];
    o.x += bb.x; o.y += bb.y; o.z += bb.z; o.w += bb.w;
  }
  ((float4*)out)[i] = o;
}

// ---------------------------------------------------------------------------
// Generic fp32 tiled SGEMM (small shapes: xproj N=64, dt K=32)
// ACT: 0 none, 2 softplus
// ---------------------------------------------------------------------------
template <int ACT>
__global__ __launch_bounds__(256) void gemm_tn(const float* __restrict__ A,
                                               const float* __restrict__ W,
                                               const float* __restrict__ bias,
                                               float* __restrict__ C,
                                               int M, int N, int K, int lda, int ldc) {
  __shared__ float As[16][65];
  __shared__ float Ws[16][65];
  const int bm = blockIdx.y * 64, bn = blockIdx.x * 64;
  const int tid = threadIdx.x;
  const int lk = tid & 15, lr = tid >> 4;
  const int tx = tid & 15, ty = tid >> 4;
  float acc[4][4] = {};
  for (int k0 = 0; k0 < K; k0 += 16) {
#pragma unroll
    for (int i = 0; i < 4; ++i) {
      As[lk][lr + 16 * i] = A[(size_t)(bm + lr + 16 * i) * lda + k0 + lk];
      Ws[lk][lr + 16 * i] = W[(size_t)(bn + lr + 16 * i) * K + k0 + lk];
    }
    __syncthreads();
#pragma unroll
    for (int kk = 0; kk < 16; ++kk) {
      float a[4], w[4];
#pragma unroll
      for (int i = 0; i < 4; ++i) a[i] = As[kk][ty + 16 * i];
#pragma unroll
      for (int j = 0; j < 4; ++j) w[j] = Ws[kk][tx + 16 * j];
#pragma unroll
      for (int i = 0; i < 4; ++i)
#pragma unroll
        for (int j = 0; j < 4; ++j) acc[i][j] += a[i] * w[j];
    }
    __syncthreads();
  }
#pragma unroll
  for (int i = 0; i < 4; ++i) {
    int r = bm + ty + 16 * i;
#pragma unroll
    for (int j = 0; j < 4; ++j) {
      int c = bn + tx + 16 * j;
      float v = acc[i][j];
      if (bias) v += bias[c];
      if (ACT == 2) v = (v > 20.f) ? v : log1pf(__expf(v));
      C[(size_t)r * ldc + c] = v;
    }
  }
}

// ---------------------------------------------------------------------------
// Depthwise causal conv (width 4) + SiLU.  xm = xz[:, :DINNER] (row stride 2048)
// ---------------------------------------------------------------------------
__global__ __launch_bounds__(256) void conv_silu_kernel(const float* __restrict__ xz,
                                                        const float* __restrict__ cw,
                                                        const float* __restrict__ cb,
                                                        float* __restrict__ xc) {
  int idx = blockIdx.x * 256 + threadIdx.x;        // ((b*L)+t)*1024 + d
  int d = idx & 1023;
  int t = (idx >> 10) & 1023;
  int b = idx >> 20;
  float acc = cb[d];
#pragma unroll
  for (int w = 0; w < 4; ++w) {
    int tt = t - 3 + w;
    if (tt >= 0) acc += xz[(((size_t)(b * 1024 + tt)) << 11) + d] * cw[d * 4 + w];
  }
  xc[idx] = silu_f(acc);
}

// ---------------------------------------------------------------------------
// Chunked selective scan, STATE-SPLIT x4: thread handles 4 of 16 states.
// idx bits: [1:0]=sh (state quarter), [11:2]=d, [15:12]=c, [18:16]=b.
// Lane-quad (sh=0..3) shares (b,c,d); dt/xc/z loads broadcast; B/C float4.
// ---------------------------------------------------------------------------
__global__ __launch_bounds__(256) void scan_pass1(const float* __restrict__ dt,
                                                  const float* __restrict__ xdb,
                                                  const float* __restrict__ xc,
                                                  const float* __restrict__ Alog,
                                                  float* __restrict__ scrP,
                                                  float* __restrict__ scrL) {
  int idx = blockIdx.x * 256 + threadIdx.x;
  int sh = idx & 3;
  int d = (idx >> 2) & 1023;
  int c = (idx >> 12) & 15;
  int b = idx >> 16;
  float A[4], st[4], P[4];
#pragma unroll
  for (int s = 0; s < 4; ++s) {
    A[s] = -__expf(Alog[d * 16 + sh * 4 + s]);
    st[s] = 0.f;
    P[s] = 1.f;
  }
  int t0 = c * CLEN;
  size_t base = (((size_t)(b * 1024 + t0)) << 10) + d;
  const float* xb = xdb + (size_t)(b * 1024 + t0) * 64 + 32 + sh * 4;
  float dtv = dt[base], xv = xc[base];
  for (int t = 0; t < CLEN; ++t) {
    float dtn = 0.f, xvn = 0.f;
    if (t + 1 < CLEN) { dtn = dt[base + 1024]; xvn = xc[base + 1024]; }
    float4 Bv = *(const float4*)xb;
    float dx = dtv * xv;
    float e0 = __expf(dtv * A[0]), e1 = __expf(dtv * A[1]);
    float e2 = __expf(dtv * A[2]), e3 = __expf(dtv * A[3]);
    st[0] = st[0] * e0 + dx * Bv.x; P[0] *= e0;
    st[1] = st[1] * e1 + dx * Bv.y; P[1] *= e1;
    st[2] = st[2] * e2 + dx * Bv.z; P[2] *= e2;
    st[3] = st[3] * e3 + dx * Bv.w; P[3] *= e3;
    base += 1024; xb += 64;
    dtv = dtn; xv = xvn;
  }
  size_t pbase = (((size_t)((b * 16 + c) * 16 + sh * 4)) << 10) + d;
#pragma unroll
  for (int s = 0; s < 4; ++s) {
    scrP[pbase + ((size_t)s << 10)] = P[s];
    scrL[pbase + ((size_t)s << 10)] = st[s];
  }
}

// ---------------------------------------------------------------------------
// Pass 2: combine chunks serially per (b,d,s).
// ---------------------------------------------------------------------------
__global__ __launch_bounds__(256) void scan_pass2(const float* __restrict__ scrP,
                                                  float* __restrict__ scrL) {
  int idx = blockIdx.x * 256 + threadIdx.x;        // ((b*16 + s)*1024 + d)
  int d = idx & 1023;
  int s = (idx >> 10) & 15;
  int b = idx >> 14;
  float cur = 0.f;
  for (int c = 0; c < 16; ++c) {
    size_t o = (((size_t)(((b * 16 + c) * 16) + s)) << 10) + d;
    float P = scrP[o];
    float loc = scrL[o];
    scrL[o] = cur;
    cur = cur * P + loc;
  }
}

// ---------------------------------------------------------------------------
// Pass 3: state-split x4 rescan; lane-quad reduces acc via shfl_xor(1,2);
// sh==0 lane applies D*x + SiLU(z) gate and writes bf16 y.
// ---------------------------------------------------------------------------
__global__ __launch_bounds__(256) void scan_pass3(const float* __restrict__ dt,
                                                  const float* __restrict__ xdb,
                                                  const float* __restrict__ xc,
                                                  const float* __restrict__ xz,
                                                  ushort_t* __restrict__ ybf,
                                                  const float* __restrict__ Alog,
                                                  const float* __restrict__ Dp,
                                                  const float* __restrict__ scrL) {
  int idx = blockIdx.x * 256 + threadIdx.x;
  int sh = idx & 3;
  int d = (idx >> 2) & 1023;
  int c = (idx >> 12) & 15;
  int b = idx >> 16;
  float A[4], st[4];
  size_t pbase = (((size_t)((b * 16 + c) * 16 + sh * 4)) << 10) + d;
#pragma unroll
  for (int s = 0; s < 4; ++s) {
    A[s] = -__expf(Alog[d * 16 + sh * 4 + s]);
    st[s] = scrL[pbase + ((size_t)s << 10)];
  }
  float Dv = Dp[d];
  int t0 = c * CLEN;
  size_t base = (((size_t)(b * 1024 + t0)) << 10) + d;
  size_t zoff = ((((size_t)(b * 1024 + t0)) << 11)) + 1024 + d;
  const float* xb = xdb + (size_t)(b * 1024 + t0) * 64 + 32 + sh * 4;
  float dtv = dt[base], xv = xc[base], zv = xz[zoff];
  for (int t = 0; t < CLEN; ++t) {
    float dtn = 0.f, xvn = 0.f, zvn = 0.f;
    if (t + 1 < CLEN) {
      dtn = dt[base + 1024]; xvn = xc[base + 1024]; zvn = xz[zoff + 2048];
    }
    float4 Bv = *(const float4*)xb;
    float4 Cv = *(const float4*)(xb + 16);
    float dx = dtv * xv;
    float e0 = __expf(dtv * A[0]), e1 = __expf(dtv * A[1]);
    float e2 = __expf(dtv * A[2]), e3 = __expf(dtv * A[3]);
    st[0] = st[0] * e0 + dx * Bv.x;
    st[1] = st[1] * e1 + dx * Bv.y;
    st[2] = st[2] * e2 + dx * Bv.z;
    st[3] = st[3] * e3 + dx * Bv.w;
    float acc = st[0] * Cv.x + st[1] * Cv.y + st[2] * Cv.z + st[3] * Cv.w;
    acc += __shfl_xor(acc, 1);
    acc += __shfl_xor(acc, 2);
    if (sh == 0)
      ybf[base] = f2bf((acc + Dv * xv) * silu_f(zv));
    base += 1024; zoff += 2048; xb += 64;
    dtv = dtn; xv = xvn; zv = zvn;
  }
}

// ---------------------------------------------------------------------------
// Residual + LayerNorm. add / out_bf may be nullptr.
// ---------------------------------------------------------------------------
__global__ __launch_bounds__(128) void resid_ln_kernel(const float* __restrict__ x,
                                                       const float* __restrict__ add,
                                                       const float* __restrict__ w,
                                                       const float* __restrict__ bias,
                                                       float* __restrict__ out,
                                                       ushort_t* __restrict__ out_bf) {
  int row = blockIdx.x, tid = threadIdx.x;
  float4 v = ((const float4*)(x + (size_t)row * 512))[tid];
  if (add) {
    float4 a = ((const float4*)(add + (size_t)row * 512))[tid];
    v.x += a.x; v.y += a.y; v.z += a.z; v.w += a.w;
  }
  float s = v.x + v.y + v.z + v.w;
  float ss = v.x * v.x + v.y * v.y + v.z * v.z + v.w * v.w;
#pragma unroll
  for (int o = 32; o; o >>= 1) {
    s += __shfl_xor(s, o);
    ss += __shfl_xor(ss, o);
  }
  __shared__ float red[4];
  int wid = tid >> 6;
  if ((tid & 63) == 0) { red[wid] = s; red[2 + wid] = ss; }
  __syncthreads();
  s = red[0] + red[1];
  ss = red[2] + red[3];
  float mean = s * (1.f / 512.f);
  float var = ss * (1.f / 512.f) - mean * mean;
  float inv = rsqrtf(var + 1e-5f);
  float4 wv = ((const float4*)w)[tid];
  float4 bv = ((const float4*)bias)[tid];
  float4 ov;
  ov.x = (v.x - mean) * inv * wv.x + bv.x;
  ov.y = (v.y - mean) * inv * wv.y + bv.y;
  ov.z = (v.z - mean) * inv * wv.z + bv.z;
  ov.w = (v.w - mean) * inv * wv.w + bv.w;
  ((float4*)(out + (size_t)row * 512))[tid] = ov;
  if (out_bf) {
    us4 ob = {f2bf(ov.x), f2bf(ov.y), f2bf(ov.z), f2bf(ov.w)};
    ((us4*)(out_bf + (size_t)row * 512))[tid] = ob;
  }
}

// ---------------------------------------------------------------------------
// Sinusoidal positional encoding add (in-place on h, refresh hbf)
// ---------------------------------------------------------------------------
__global__ __launch_bounds__(256) void posenc_kernel(float* __restrict__ h,
                                                     ushort_t* __restrict__ hbf) {
  int idx = blockIdx.x * 256 + threadIdx.x;
  int d = idx & 511;
  int l = (idx >> 9) & 1023;
  float freq = __expf(-(float)(d & ~1) * (9.210340371976184f / 512.f));
  float ang = (float)l * freq;
  float v = h[idx] + ((d & 1) ? cosf(ang) : sinf(ang));
  h[idx] = v;
  hbf[idx] = f2bf(v);
}

// ---------------------------------------------------------------------------
// MFMA flash attention, bf16 qkv input. One block = (b, head, 64 q-rows).
// ---------------------------------------------------------------------------
__global__ __launch_bounds__(256) void attn_mfma(const ushort_t* __restrict__ qkv,
                                                 ushort_t* __restrict__ ao) {
  __shared__ unsigned short Qs[4096];
  __shared__ unsigned short Ks[4096];
  __shared__ unsigned short Vt[4096];
  __shared__ unsigned short Ps[4096];
  const int tid = threadIdx.x;
  const int blk = blockIdx.x;                    // ((b*8 + h)*16 + qt)
  const int qt = blk & 15, hh = (blk >> 4) & 7, b = blk >> 7;
  const int l0 = qt * 64;
  const size_t bb = (size_t)b * 1024 * 1536;

  const int srow = tid >> 2;                     // staging row 0..63
  const int sdb = (tid & 3) << 4;                // staging d-block 0/16/32/48
  const int sc0 = sdb >> 3;

  {
    const ushort_t* qp = qkv + bb + (size_t)(l0 + srow) * 1536 + hh * 64 + sdb;
    *(bfrag*)&Qs[srow * 64 + ((sc0 ^ (srow & 7)) << 3)] = *(const bfrag*)qp;
    *(bfrag*)&Qs[srow * 64 + (((sc0 + 1) ^ (srow & 7)) << 3)] = *(const bfrag*)(qp + 8);
  }

  const int wid = tid >> 6, lane = tid & 63;
  const int l15 = lane & 15, rg = lane >> 4;
  const int l7 = l15 & 7;
  float m[4], lsum[4];
  f32x4 oacc[4];
#pragma unroll
  for (int r = 0; r < 4; ++r) { m[r] = -1e30f; lsum[r] = 0.f; }
#pragma unroll
  for (int nt = 0; nt < 4; ++nt) oacc[nt] = (f32x4)(0.f);

  for (int jt = 0; jt < 16; ++jt) {
    {
      const ushort_t* kp = qkv + bb + (size_t)(jt * 64 + srow) * 1536 + hh * 64 + 512 + sdb;
      *(bfrag*)&Ks[srow * 64 + ((sc0 ^ (srow & 7)) << 3)] = *(const bfrag*)kp;
      *(bfrag*)&Ks[srow * 64 + (((sc0 + 1) ^ (srow & 7)) << 3)] = *(const bfrag*)(kp + 8);
      const ushort_t* vp = kp + 512;
      unsigned short vv[16];
      *(bfrag*)&vv[0] = *(const bfrag*)vp;
      *(bfrag*)&vv[8] = *(const bfrag*)(vp + 8);
#pragma unroll
      for (int j = 0; j < 16; ++j) {
        int dd = sdb + j;
        Vt[dd * 64 + (((srow >> 3) ^ (dd & 7)) << 3) + (srow & 7)] = vv[j];
      }
    }
    __syncthreads();

    bfrag aq[2];
#pragma unroll
    for (int ks = 0; ks < 2; ++ks)
      aq[ks] = *(const bfrag*)&Qs[(wid * 16 + l15) * 64 + (((ks * 4 + rg) ^ l7) << 3)];
    f32x4 sc[4];
#pragma unroll
    for (int nt = 0; nt < 4; ++nt) {
      f32x4 s = (f32x4)(0.f);
#pragma unroll
      for (int ks = 0; ks < 2; ++ks) {
        bfrag bk = *(const bfrag*)&Ks[(nt * 16 + l15) * 64 + (((ks * 4 + rg) ^ l7) << 3)];
        s = __builtin_amdgcn_mfma_f32_16x16x32_bf16(aq[ks], bk, s, 0, 0, 0);
      }
      sc[nt] = s * 0.125f;
    }

#pragma unroll
    for (int r = 0; r < 4; ++r) {
      float mc = fmaxf(fmaxf(sc[0][r], sc[1][r]), fmaxf(sc[2][r], sc[3][r]));
#pragma unroll
      for (int o = 8; o; o >>= 1) mc = fmaxf(mc, __shfl_xor(mc, o));
      float mn = fmaxf(m[r], mc);
      float al = __expf(m[r] - mn);
      m[r] = mn;
      int prow = rg * 4 + r;
      float ps = 0.f;
#pragma unroll
      for (int nt = 0; nt < 4; ++nt) {
        float p = __expf(sc[nt][r] - mn);
        ps += p;
        int col = nt * 16 + l15;
        Ps[wid * 1024 + prow * 64 + ((((col >> 3) ^ (prow & 7))) << 3) + (col & 7)] = f2bf(p);
      }
#pragma unroll
      for (int o = 8; o; o >>= 1) ps += __shfl_xor(ps, o);
      lsum[r] = lsum[r] * al + ps;
#pragma unroll
      for (int nt = 0; nt < 4; ++nt) oacc[nt][r] *= al;
    }

    bfrag ap[2];
#pragma unroll
    for (int ks = 0; ks < 2; ++ks)
      ap[ks] = *(const bfrag*)&Ps[wid * 1024 + l15 * 64 + (((ks * 4 + rg) ^ l7) << 3)];
#pragma unroll
    for (int nt = 0; nt < 4; ++nt) {
#pragma unroll
      for (int ks = 0; ks < 2; ++ks) {
        bfrag bv = *(const bfrag*)&Vt[(nt * 16 + l15) * 64 + (((ks * 4 + rg) ^ l7) << 3)];
        oacc[nt] = __builtin_amdgcn_mfma_f32_16x16x32_bf16(ap[ks], bv, oacc[nt], 0, 0, 0);
      }
    }
    __syncthreads();
  }

#pragma unroll
  for (int r = 0; r < 4; ++r) {
    float inv = 1.f / lsum[r];
    int row = l0 + wid * 16 + rg * 4 + r;
    ushort_t* op = ao + ((size_t)(b * 1024 + row)) * 512 + hh * 64;
#pragma unroll
    for (int nt = 0; nt < 4; ++nt) op[nt * 16 + l15] = f2bf(oacc[nt][r] * inv);
  }
}

// ---------------------------------------------------------------------------
// Mean over L, two-pass. part[(b*16+lc)][d] then final sum.
// ---------------------------------------------------------------------------
__global__ __launch_bounds__(512) void mean_part(const float* __restrict__ h,
                                                 float* __restrict__ part) {
  int blk = blockIdx.x;                       // b*16 + lc
  int b = blk >> 4, lc = blk & 15, d = threadIdx.x;
  float s = 0.f;
  int l0 = lc * 64;
  for (int l = l0; l < l0 + 64; ++l) s += h[(((size_t)(b * 1024 + l)) << 9) + d];
  part[((size_t)blk << 9) + d] = s;
}
__global__ __launch_bounds__(256) void mean_final(const float* __restrict__ part,
                                                  float* __restrict__ out2) {
  int i = blockIdx.x * 256 + threadIdx.x;     // b*512 + d
  int b = i >> 9, d = i & 511;
  float s = 0.f;
#pragma unroll
  for (int c = 0; c < 16; ++c) s += part[(((size_t)(b * 16 + c)) << 9) + d];
  out2[i] = s * (1.f / 1024.f);
}

// ---------------------------------------------------------------------------
extern "C" void kernel_launch(void* const* d_in, const int* in_sizes, int n_in,
                              void* d_out, int out_size, void* d_ws, size_t ws_size,
                              hipStream_t stream) {
  const float* x        = (const float*)d_in[0];
  const float* proj_w   = (const float*)d_in[1];
  const float* proj_b   = (const float*)d_in[2];
  const float* m_in_w   = (const float*)d_in[3];
  const float* m_conv_w = (const float*)d_in[4];
  const float* m_conv_b = (const float*)d_in[5];
  const float* m_xproj_w= (const float*)d_in[6];
  const float* m_dt_w   = (const float*)d_in[7];
  const float* m_dt_b   = (const float*)d_in[8];
  const float* m_Alog   = (const float*)d_in[9];
  const float* m_D      = (const float*)d_in[10];
  const float* m_out_w  = (const float*)d_in[11];
  const float* m_ln_w   = (const float*)d_in[12];
  const float* m_ln_b   = (const float*)d_in[13];
  const float* t_qkv_w  = (const float*)d_in[14];
  const float* t_qkv_b  = (const float*)d_in[15];
  const float* t_ow     = (const float*)d_in[16];
  const float* t_ob     = (const float*)d_in[17];
  const float* t_l1w    = (const float*)d_in[18];
  const float* t_l1b    = (const float*)d_in[19];
  const float* t_l2w    = (const float*)d_in[20];
  const float* t_l2b    = (const float*)d_in[21];
  const float* t_ln1w   = (const float*)d_in[22];
  const float* t_ln1b   = (const float*)d_in[23];
  const float* t_ln2w   = (const float*)d_in[24];
  const float* t_ln2b   = (const float*)d_in[25];
  const float* no_w     = (const float*)d_in[26];
  const float* no_b     = (const float*)d_in[27];

  float* ws   = (float*)d_ws;
  float* h    = ws;                                   //  4M f
  ushort_t* h_bf = (ushort_t*)(ws + 4194304);         //  4M us (2M f)
  float* bufA = ws + 6291456;                         // 16M f (xz f32 / qkv_bf / ff1_bf)
  float* bufB = bufA + 16777216;                      //  8M f (xc f32 / ao_bf)
  float* bufC = bufB + 8388608;                       //  8M f (dt / split-K partials)
  float* bufE = bufC + 8388608;                       //  4M f (scan scratch / GEMM out)
  float* bufF = bufE + 4194304;                       //  0.5M f (xdb / mean partials)
  ushort_t* y_bf = (ushort_t*)(bufF + 524288);        //  8M us (4M f)
  ushort_t* wbf  = (ushort_t*)(bufF + 524288 + 4194304);  // 9.44M us
  float* scrP = bufE;
  float* scrL = bufE + 2097152;
  const int M = MTOK;

  // bf16 weight pool offsets (ushort units)
  ushort_t* wIN  = wbf;                 // 2 x 2048 x 512
  ushort_t* wOUT = wbf + 2097152;       // 2 x 512 x 1024
  ushort_t* wQKV = wbf + 3145728;       // 2 x 1536 x 512
  ushort_t* wOW  = wbf + 4718592;       // 2 x 512 x 512
  ushort_t* wL1  = wbf + 5242880;       // 2 x 2048 x 512
  ushort_t* wL2  = wbf + 7340032;       // 2 x 512 x 2048

  cvt_bf16<<<2048, 256, 0, stream>>>(m_in_w,  wIN,  524288);
  cvt_bf16<<<1024, 256, 0, stream>>>(m_out_w, wOUT, 262144);
  cvt_bf16<<<1536, 256, 0, stream>>>(t_qkv_w, wQKV, 393216);
  cvt_bf16<<< 512, 256, 0, stream>>>(t_ow,    wOW,  131072);
  cvt_bf16<<<2048, 256, 0, stream>>>(t_l1w,   wL1,  524288);
  cvt_bf16<<<2048, 256, 0, stream>>>(t_l2w,   wL2,  524288);

  proj_kernel<<<16384, 256, 0, stream>>>(x, proj_w, proj_b, h, h_bf);

  for (int i = 0; i < 2; ++i) {
    // xz = h @ in_w^T   (8192 x 2048, K=512) -> fp32
    gemm_gll<0, 0, 1><<<dim3(16, 64), 256, 0, stream>>>(
        h_bf, wIN + (size_t)i * 1048576, nullptr, bufA, DMODEL, DMODEL, 2 * DINNER);
    // xc = silu(causal_conv(xm))
    conv_silu_kernel<<<32768, 256, 0, stream>>>(bufA, m_conv_w + i * DINNER * 4,
                                                m_conv_b + i * DINNER, bufB);
    // xdb = xc @ xp_w^T  (8192 x 64, K=1024) fp32
    gemm_tn<0><<<dim3(1, M / 64), 256, 0, stream>>>(
        bufB, m_xproj_w + (size_t)i * 64 * DINNER, nullptr, bufF,
        M, 64, DINNER, DINNER, 64);
    // dt = softplus(xdb[:, :32] @ dt_w^T + dt_b) fp32
    gemm_tn<2><<<dim3(DINNER / 64, M / 64), 256, 0, stream>>>(
        bufF, m_dt_w + (size_t)i * DINNER * DTRANK, m_dt_b + i * DINNER, bufC,
        M, DINNER, DTRANK, 64, DINNER);
    // chunked selective scan (state-split x4) -> y_bf (bf16)
    scan_pass1<<<2048, 256, 0, stream>>>(bufC, bufF, bufB,
                                         m_Alog + (size_t)i * DINNER * DSTATE, scrP, scrL);
    scan_pass2<<<512, 256, 0, stream>>>(scrP, scrL);
    scan_pass3<<<2048, 256, 0, stream>>>(bufC, bufF, bufB, bufA, y_bf,
                                         m_Alog + (size_t)i * DINNER * DSTATE,
                                         m_D + i * DINNER, scrL);
    // mamba_out = y @ out_w^T  (8192 x 512, K=1024), split-K=2 (dt is dead)
    gemm_gll<0, 0, 2><<<dim3(4, 64, 2), 256, 0, stream>>>(
        y_bf, wOUT + (size_t)i * 524288, nullptr, bufC, DINNER, DINNER, DMODEL);
    splitk_reduce<<<4096, 256, 0, stream>>>(bufC, nullptr, bufE);
    // h = LN(h + mamba_out), refresh h_bf
    resid_ln_kernel<<<8192, 128, 0, stream>>>(h, bufE, m_ln_w + i * DMODEL,
                                              m_ln_b + i * DMODEL, h, h_bf);
  }

  posenc_kernel<<<16384, 256, 0, stream>>>(h, h_bf);

  for (int i = 0; i < 2; ++i) {
    // qkv = h @ qkv_w^T + qkv_b  (8192 x 1536, K=512) -> bf16
    gemm_gll<0, 1, 1><<<dim3(12, 64), 256, 0, stream>>>(
        h_bf, wQKV + (size_t)i * 786432, t_qkv_b + i * 3 * DMODEL, bufA,
        DMODEL, DMODEL, 3 * DMODEL);
    // MFMA flash attention -> ao bf16
    attn_mfma<<<1024, 256, 0, stream>>>((const ushort_t*)bufA, (ushort_t*)bufB);
    // attn_proj = ao @ ow^T + ob  (8192 x 512, K=512), split-K=2
    gemm_gll<0, 0, 2><<<dim3(4, 64, 2), 256, 0, stream>>>(
        (const ushort_t*)bufB, wOW + (size_t)i * 262144, nullptr, bufC,
        DMODEL, DMODEL, DMODEL);
    splitk_reduce<<<4096, 256, 0, stream>>>(bufC, t_ob + i * DMODEL, bufE);
    // h = LN(h + attn_proj)
    resid_ln_kernel<<<8192, 128, 0, stream>>>(h, bufE, t_ln1w + i * DMODEL,
                                              t_ln1b + i * DMODEL, h, h_bf);
    // ff1 = relu(h @ l1w^T + l1b)  (8192 x 2048, K=512) -> bf16
    gemm_gll<1, 1, 1><<<dim3(16, 64), 256, 0, stream>>>(
        h_bf, wL1 + (size_t)i * 1048576, t_l1b + i * DFF, bufA,
        DMODEL, DMODEL, DFF);
    // ff2 = ff1 @ l2w^T + l2b  (8192 x 512, K=2048), split-K=2
    gemm_gll<0, 0, 2><<<dim3(4, 64, 2), 256, 0, stream>>>(
        (const ushort_t*)bufA, wL2 + (size_t)i * 1048576, nullptr, bufC,
        DFF, DFF, DMODEL);
    splitk_reduce<<<4096, 256, 0, stream>>>(bufC, t_l2b + i * DMODEL, bufE);
    // h = LN(h + ff2)
    resid_ln_kernel<<<8192, 128, 0, stream>>>(h, bufE, t_ln2w + i * DMODEL,
                                              t_ln2b + i * DMODEL, h, h_bf);
  }

  // final LN -> d_out, then mean over L -> d_out tail
  float* out_h = (float*)d_out;
  resid_ln_kernel<<<8192, 128, 0, stream>>>(h, nullptr, no_w, no_b, out_h, nullptr);
  mean_part<<<128, 512, 0, stream>>>(out_h, bufF);
  mean_final<<<16, 256, 0, stream>>>(bufF, out_h + 4194304);
}

// Round 8
// 987.425 us; speedup vs baseline: 1.4705x; 1.1591x over previous
//
#include <hip/hip_runtime.h>
#include <cstddef>

// Problem constants
#define BATCH 8
#define LSEQ 1024
#define DMODEL 512
#define DINNER 1024
#define DSTATE 16
#define DTRANK 32
#define NHEAD 8
#define DHEAD 64
#define DFF 2048
#define MTOK 8192   // BATCH*LSEQ
#define NCHUNK 16
#define CLEN 64     // LSEQ / NCHUNK

typedef __attribute__((ext_vector_type(8))) short bfrag;          // 8 bf16 = 16 B
typedef __attribute__((ext_vector_type(4))) float f32x4;          // MFMA acc
typedef __attribute__((ext_vector_type(4))) unsigned short us4;
typedef unsigned short ushort_t;

__device__ __forceinline__ float silu_f(float x) { return x / (1.f + __expf(-x)); }

__device__ __forceinline__ unsigned short f2bf(float f) {  // RNE fp32->bf16
  unsigned u = __float_as_uint(f);
  return (unsigned short)((u + 0x7FFFu + ((u >> 16) & 1u)) >> 16);
}
__device__ __forceinline__ float bf2f(ushort_t u) {
  return __uint_as_float((unsigned)u << 16);
}

// async global->LDS, 16B per lane. LDS dest = wave-uniform base + lane*16.
__device__ __forceinline__ void gll16(const ushort_t* g, ushort_t* l) {
  __builtin_amdgcn_global_load_lds(
      (const __attribute__((address_space(1))) unsigned int*)g,
      (__attribute__((address_space(3))) unsigned int*)l, 16, 0, 0);
}

// ---------------------------------------------------------------------------
// fp32 -> bf16 bulk convert (vectorized x4). n4 = element count / 4.
// ---------------------------------------------------------------------------
__global__ __launch_bounds__(256) void cvt_bf16(const float* __restrict__ s,
                                                ushort_t* __restrict__ d, int n4) {
  int i = blockIdx.x * 256 + threadIdx.x;
  if (i >= n4) return;
  float4 v = ((const float4*)s)[i];
  us4 o = {f2bf(v.x), f2bf(v.y), f2bf(v.z), f2bf(v.w)};
  ((us4*)d)[i] = o;
}

// ---------------------------------------------------------------------------
// Input projection: h[b,l,d] = sum_c x[b,c,l] * pw[d,c] + pb[d]; also bf16 copy.
// ---------------------------------------------------------------------------
__global__ __launch_bounds__(256) void proj_kernel(const float* __restrict__ x,
                                                   const float* __restrict__ pw,
                                                   const float* __restrict__ pb,
                                                   float* __restrict__ h,
                                                   ushort_t* __restrict__ hbf) {
  int idx = blockIdx.x * 256 + threadIdx.x;        // ((b*L)+l)*512 + d
  int d = idx & 511;
  int l = (idx >> 9) & 1023;
  int b = idx >> 19;
  const float* xb = x + (size_t)b * 3 * 1024 + l;
  float v = pb[d] + xb[0] * pw[d * 3] + xb[1024] * pw[d * 3 + 1] + xb[2048] * pw[d * 3 + 2];
  h[idx] = v;
  hbf[idx] = f2bf(v);
}

// ---------------------------------------------------------------------------
// bf16 MFMA GEMM, global_load_lds + double-buffered prefetch.
// C[m,n] = act( sum_k A[m,k]*W[n,k] + bias[n] ).  Tile 128 x BN, BK=32.
// BN=128: 4 waves 2x2 (64x64). BN=64: 4 waves 4x1 (32x64), 3 glls/stage.
// ACT: 0 none, 1 relu, 2 softplus. CBF: 1 bf16 C, 0 fp32 C.
// SPLITK: 1 direct; >1 -> fp32 partials at Cp + z*8192*ldc (no bias/act).
// ---------------------------------------------------------------------------
template <int ACT, int CBF, int SPLITK, int BN>
__global__ __launch_bounds__(256) void gemm_gll(const ushort_t* __restrict__ A,
                                                const ushort_t* __restrict__ W,
                                                const float* __restrict__ bias,
                                                void* __restrict__ Cp,
                                                int K, int lda, int ldc) {
  __shared__ ushort_t sA[2][4096];
  __shared__ ushort_t sB[2][BN * 32];
  constexpr int MREP = (BN == 128) ? 4 : 2;
  const int bm = blockIdx.y * 128, bn = blockIdx.x * BN;
  const int tid = threadIdx.x;
  const int wid = tid >> 6, lane = tid & 63;
  const int wrb = (BN == 128) ? (wid >> 1) * 64 : wid * 32;
  const int wcb = (BN == 128) ? (wid & 1) * 64 : 0;
  const int lr = lane & 15, ls = lane >> 4;
  const int sw = ls ^ ((lr >> 1) & 3);

  const int kseg = K / SPLITK;
  const int kbeg = (SPLITK > 1) ? blockIdx.z * kseg : 0;

  const int c0 = wid * 128 + lane;
  const int c1 = c0 + 64;
  const int r0 = c0 >> 2, s0 = (c0 & 3) ^ ((r0 >> 1) & 3);
  const int r1 = c1 >> 2, s1 = (c1 & 3) ^ ((r1 >> 1) & 3);
  const ushort_t* gA0 = A + (size_t)(bm + r0) * lda + kbeg + s0 * 8;
  const ushort_t* gA1 = A + (size_t)(bm + r1) * lda + kbeg + s1 * 8;
  const ushort_t* gB0;
  const ushort_t* gB1 = nullptr;
  if constexpr (BN == 128) {
    gB0 = W + (size_t)(bn + r0) * K + kbeg + s0 * 8;
    gB1 = W + (size_t)(bn + r1) * K + kbeg + s1 * 8;
  } else {
    const int cb = wid * 64 + lane;
    const int rb = cb >> 2, sb2 = (cb & 3) ^ ((rb >> 1) & 3);
    gB0 = W + (size_t)(bn + rb) * K + kbeg + sb2 * 8;
  }

  f32x4 acc[MREP][4];
#pragma unroll
  for (int i = 0; i < MREP; ++i)
#pragma unroll
    for (int j = 0; j < 4; ++j) acc[i][j] = (f32x4)(0.f);

#define STAGE(buf, step)                                             \
  do {                                                               \
    gll16(gA0 + (step) * 32, &sA[buf][wid * 1024]);                  \
    gll16(gA1 + (step) * 32, &sA[buf][wid * 1024 + 512]);            \
    if constexpr (BN == 128) {                                       \
      gll16(gB0 + (step) * 32, &sB[buf][wid * 1024]);                \
      gll16(gB1 + (step) * 32, &sB[buf][wid * 1024 + 512]);          \
    } else {                                                         \
      gll16(gB0 + (step) * 32, &sB[buf][wid * 512]);                 \
    }                                                                \
  } while (0)

  const int NT = kseg / 32;
  STAGE(0, 0);
  for (int t = 0; t < NT; ++t) {
    const int cur = t & 1;
    if (t + 1 < NT) {
      STAGE(cur ^ 1, t + 1);
      if constexpr (BN == 128)
        asm volatile("s_waitcnt vmcnt(4)" ::: "memory");
      else
        asm volatile("s_waitcnt vmcnt(3)" ::: "memory");
    } else {
      asm volatile("s_waitcnt vmcnt(0)" ::: "memory");
    }
    __builtin_amdgcn_sched_barrier(0);
    __builtin_amdgcn_s_barrier();
    __builtin_amdgcn_sched_barrier(0);

    bfrag af[MREP], bf[4];
#pragma unroll
    for (int mi = 0; mi < MREP; ++mi) {
      int row = wrb + mi * 16 + lr;
      af[mi] = *(const bfrag*)&sA[cur][(size_t)((row << 2) + sw) * 8];
    }
#pragma unroll
    for (int nj = 0; nj < 4; ++nj) {
      int col = wcb + nj * 16 + lr;
      bf[nj] = *(const bfrag*)&sB[cur][(size_t)((col << 2) + sw) * 8];
    }
#pragma unroll
    for (int mi = 0; mi < MREP; ++mi)
#pragma unroll
      for (int nj = 0; nj < 4; ++nj)
        acc[mi][nj] = __builtin_amdgcn_mfma_f32_16x16x32_bf16(af[mi], bf[nj], acc[mi][nj], 0, 0, 0);

    __builtin_amdgcn_s_barrier();
    __builtin_amdgcn_sched_barrier(0);
  }
#undef STAGE

  if (SPLITK > 1) {
    float* Cz = (float*)Cp + (size_t)blockIdx.z * 8192 * ldc;
#pragma unroll
    for (int nj = 0; nj < 4; ++nj) {
      int col = bn + wcb + nj * 16 + lr;
#pragma unroll
      for (int mi = 0; mi < MREP; ++mi) {
        int row0 = bm + wrb + mi * 16 + ls * 4;
#pragma unroll
        for (int r = 0; r < 4; ++r)
          Cz[(size_t)(row0 + r) * ldc + col] = acc[mi][nj][r];
      }
    }
  } else {
#pragma unroll
    for (int nj = 0; nj < 4; ++nj) {
      int col = bn + wcb + nj * 16 + lr;
      float bv = bias ? bias[col] : 0.f;
#pragma unroll
      for (int mi = 0; mi < MREP; ++mi) {
        int row0 = bm + wrb + mi * 16 + ls * 4;
#pragma unroll
        for (int r = 0; r < 4; ++r) {
          float v = acc[mi][nj][r] + bv;
          if (ACT == 1) v = fmaxf(v, 0.f);
          if (ACT == 2) v = (v > 20.f) ? v : log1pf(__expf(v));
          if (CBF)
            ((ushort_t*)Cp)[(size_t)(row0 + r) * ldc + col] = f2bf(v);
          else
            ((float*)Cp)[(size_t)(row0 + r) * ldc + col] = v;
        }
      }
    }
  }
}

// ---------------------------------------------------------------------------
// split-K=2 reduce for N=512 GEMMs: out = p[0..]+p[4M..] + bias
// ---------------------------------------------------------------------------
__global__ __launch_bounds__(256) void splitk_reduce(const float* __restrict__ p,
                                                     const float* __restrict__ bias,
                                                     float* __restrict__ out) {
  int i = blockIdx.x * 256 + threadIdx.x;            // float4 index, 1M total
  float4 a = ((const float4*)p)[i];
  float4 b = ((const float4*)p)[i + 1048576];
  float4 o = {a.x + b.x, a.y + b.y, a.z + b.z, a.w + b.w};
  if (bias) {
    float4 bb = ((const float4*)bias)[i & 127];
    o.x += bb.x; o.y += bb.y; o.z += bb.z; o.w += bb.w;
  }
  ((float4*)out)[i] = o;
}

// ---------------------------------------------------------------------------
// split-K=8 reduce for xproj: xdb fp32 + bf16 copy. 131072 float4 groups.
// ---------------------------------------------------------------------------
__global__ __launch_bounds__(256) void reduce8_xdb(const float* __restrict__ p,
                                                   float* __restrict__ xdb,
                                                   ushort_t* __restrict__ xdb_bf) {
  int i = blockIdx.x * 256 + threadIdx.x;
  float4 a = ((const float4*)p)[i];
#pragma unroll
  for (int z = 1; z < 8; ++z) {
    float4 b = ((const float4*)p)[i + z * 131072];
    a.x += b.x; a.y += b.y; a.z += b.z; a.w += b.w;
  }
  ((float4*)xdb)[i] = a;
  us4 o = {f2bf(a.x), f2bf(a.y), f2bf(a.z), f2bf(a.w)};
  ((us4*)xdb_bf)[i] = o;
}

// ---------------------------------------------------------------------------
// Depthwise causal conv (width 4) + SiLU -> bf16 xc.
// ---------------------------------------------------------------------------
__global__ __launch_bounds__(256) void conv_silu_kernel(const float* __restrict__ xz,
                                                        const float* __restrict__ cw,
                                                        const float* __restrict__ cb,
                                                        ushort_t* __restrict__ xc) {
  int idx = blockIdx.x * 256 + threadIdx.x;        // ((b*L)+t)*1024 + d
  int d = idx & 1023;
  int t = (idx >> 10) & 1023;
  int b = idx >> 20;
  float acc = cb[d];
#pragma unroll
  for (int w = 0; w < 4; ++w) {
    int tt = t - 3 + w;
    if (tt >= 0) acc += xz[(((size_t)(b * 1024 + tt)) << 11) + d] * cw[d * 4 + w];
  }
  xc[idx] = f2bf(silu_f(acc));
}

// ---------------------------------------------------------------------------
// Chunked selective scan, STATE-SPLIT x4. xc is bf16 now.
// ---------------------------------------------------------------------------
__global__ __launch_bounds__(256) void scan_pass1(const float* __restrict__ dt,
                                                  const float* __restrict__ xdb,
                                                  const ushort_t* __restrict__ xc,
                                                  const float* __restrict__ Alog,
                                                  float* __restrict__ scrP,
                                                  float* __restrict__ scrL) {
  int idx = blockIdx.x * 256 + threadIdx.x;
  int sh = idx & 3;
  int d = (idx >> 2) & 1023;
  int c = (idx >> 12) & 15;
  int b = idx >> 16;
  float A[4], st[4], P[4];
#pragma unroll
  for (int s = 0; s < 4; ++s) {
    A[s] = -__expf(Alog[d * 16 + sh * 4 + s]);
    st[s] = 0.f;
    P[s] = 1.f;
  }
  int t0 = c * CLEN;
  size_t base = (((size_t)(b * 1024 + t0)) << 10) + d;
  const float* xb = xdb + (size_t)(b * 1024 + t0) * 64 + 32 + sh * 4;
  float dtv = dt[base], xv = bf2f(xc[base]);
  for (int t = 0; t < CLEN; ++t) {
    float dtn = 0.f, xvn = 0.f;
    if (t + 1 < CLEN) { dtn = dt[base + 1024]; xvn = bf2f(xc[base + 1024]); }
    float4 Bv = *(const float4*)xb;
    float dx = dtv * xv;
    float e0 = __expf(dtv * A[0]), e1 = __expf(dtv * A[1]);
    float e2 = __expf(dtv * A[2]), e3 = __expf(dtv * A[3]);
    st[0] = st[0] * e0 + dx * Bv.x; P[0] *= e0;
    st[1] = st[1] * e1 + dx * Bv.y; P[1] *= e1;
    st[2] = st[2] * e2 + dx * Bv.z; P[2] *= e2;
    st[3] = st[3] * e3 + dx * Bv.w; P[3] *= e3;
    base += 1024; xb += 64;
    dtv = dtn; xv = xvn;
  }
  size_t pbase = (((size_t)((b * 16 + c) * 16 + sh * 4)) << 10) + d;
#pragma unroll
  for (int s = 0; s < 4; ++s) {
    scrP[pbase + ((size_t)s << 10)] = P[s];
    scrL[pbase + ((size_t)s << 10)] = st[s];
  }
}

// ---------------------------------------------------------------------------
// Pass 2: combine chunks serially per (b,d,s).
// ---------------------------------------------------------------------------
__global__ __launch_bounds__(256) void scan_pass2(const float* __restrict__ scrP,
                                                  float* __restrict__ scrL) {
  int idx = blockIdx.x * 256 + threadIdx.x;        // ((b*16 + s)*1024 + d)
  int d = idx & 1023;
  int s = (idx >> 10) & 15;
  int b = idx >> 14;
  float cur = 0.f;
  for (int c = 0; c < 16; ++c) {
    size_t o = (((size_t)(((b * 16 + c) * 16) + s)) << 10) + d;
    float P = scrP[o];
    float loc = scrL[o];
    scrL[o] = cur;
    cur = cur * P + loc;
  }
}

// ---------------------------------------------------------------------------
// Pass 3: state-split x4 rescan; quad-reduce via shfl_xor; bf16 y out.
// ---------------------------------------------------------------------------
__global__ __launch_bounds__(256) void scan_pass3(const float* __restrict__ dt,
                                                  const float* __restrict__ xdb,
                                                  const ushort_t* __restrict__ xc,
                                                  const float* __restrict__ xz,
                                                  ushort_t* __restrict__ ybf,
                                                  const float* __restrict__ Alog,
                                                  const float* __restrict__ Dp,
                                                  const float* __restrict__ scrL) {
  int idx = blockIdx.x * 256 + threadIdx.x;
  int sh = idx & 3;
  int d = (idx >> 2) & 1023;
  int c = (idx >> 12) & 15;
  int b = idx >> 16;
  float A[4], st[4];
  size_t pbase = (((size_t)((b * 16 + c) * 16 + sh * 4)) << 10) + d;
#pragma unroll
  for (int s = 0; s < 4; ++s) {
    A[s] = -__expf(Alog[d * 16 + sh * 4 + s]);
    st[s] = scrL[pbase + ((size_t)s << 10)];
  }
  float Dv = Dp[d];
  int t0 = c * CLEN;
  size_t base = (((size_t)(b * 1024 + t0)) << 10) + d;
  size_t zoff = ((((size_t)(b * 1024 + t0)) << 11)) + 1024 + d;
  const float* xb = xdb + (size_t)(b * 1024 + t0) * 64 + 32 + sh * 4;
  float dtv = dt[base], xv = bf2f(xc[base]), zv = xz[zoff];
  for (int t = 0; t < CLEN; ++t) {
    float dtn = 0.f, xvn = 0.f, zvn = 0.f;
    if (t + 1 < CLEN) {
      dtn = dt[base + 1024]; xvn = bf2f(xc[base + 1024]); zvn = xz[zoff + 2048];
    }
    float4 Bv = *(const float4*)xb;
    float4 Cv = *(const float4*)(xb + 16);
    float dx = dtv * xv;
    float e0 = __expf(dtv * A[0]), e1 = __expf(dtv * A[1]);
    float e2 = __expf(dtv * A[2]), e3 = __expf(dtv * A[3]);
    st[0] = st[0] * e0 + dx * Bv.x;
    st[1] = st[1] * e1 + dx * Bv.y;
    st[2] = st[2] * e2 + dx * Bv.z;
    st[3] = st[3] * e3 + dx * Bv.w;
    float acc = st[0] * Cv.x + st[1] * Cv.y + st[2] * Cv.z + st[3] * Cv.w;
    acc += __shfl_xor(acc, 1);
    acc += __shfl_xor(acc, 2);
    if (sh == 0)
      ybf[base] = f2bf((acc + Dv * xv) * silu_f(zv));
    base += 1024; zoff += 2048; xb += 64;
    dtv = dtn; xv = xvn; zv = zvn;
  }
}

// ---------------------------------------------------------------------------
// Residual + LayerNorm. add / out_bf may be nullptr.
// ---------------------------------------------------------------------------
__global__ __launch_bounds__(128) void resid_ln_kernel(const float* __restrict__ x,
                                                       const float* __restrict__ add,
                                                       const float* __restrict__ w,
                                                       const float* __restrict__ bias,
                                                       float* __restrict__ out,
                                                       ushort_t* __restrict__ out_bf) {
  int row = blockIdx.x, tid = threadIdx.x;
  float4 v = ((const float4*)(x + (size_t)row * 512))[tid];
  if (add) {
    float4 a = ((const float4*)(add + (size_t)row * 512))[tid];
    v.x += a.x; v.y += a.y; v.z += a.z; v.w += a.w;
  }
  float s = v.x + v.y + v.z + v.w;
  float ss = v.x * v.x + v.y * v.y + v.z * v.z + v.w * v.w;
#pragma unroll
  for (int o = 32; o; o >>= 1) {
    s += __shfl_xor(s, o);
    ss += __shfl_xor(ss, o);
  }
  __shared__ float red[4];
  int wid = tid >> 6;
  if ((tid & 63) == 0) { red[wid] = s; red[2 + wid] = ss; }
  __syncthreads();
  s = red[0] + red[1];
  ss = red[2] + red[3];
  float mean = s * (1.f / 512.f);
  float var = ss * (1.f / 512.f) - mean * mean;
  float inv = rsqrtf(var + 1e-5f);
  float4 wv = ((const float4*)w)[tid];
  float4 bv = ((const float4*)bias)[tid];
  float4 ov;
  ov.x = (v.x - mean) * inv * wv.x + bv.x;
  ov.y = (v.y - mean) * inv * wv.y + bv.y;
  ov.z = (v.z - mean) * inv * wv.z + bv.z;
  ov.w = (v.w - mean) * inv * wv.w + bv.w;
  ((float4*)(out + (size_t)row * 512))[tid] = ov;
  if (out_bf) {
    us4 ob = {f2bf(ov.x), f2bf(ov.y), f2bf(ov.z), f2bf(ov.w)};
    ((us4*)(out_bf + (size_t)row * 512))[tid] = ob;
  }
}

// ---------------------------------------------------------------------------
// Sinusoidal positional encoding add (in-place on h, refresh hbf)
// ---------------------------------------------------------------------------
__global__ __launch_bounds__(256) void posenc_kernel(float* __restrict__ h,
                                                     ushort_t* __restrict__ hbf) {
  int idx = blockIdx.x * 256 + threadIdx.x;
  int d = idx & 511;
  int l = (idx >> 9) & 1023;
  float freq = __expf(-(float)(d & ~1) * (9.210340371976184f / 512.f));
  float ang = (float)l * freq;
  float v = h[idx] + ((d & 1) ? cosf(ang) : sinf(ang));
  h[idx] = v;
  hbf[idx] = f2bf(v);
}

// ---------------------------------------------------------------------------
// MFMA flash attention, bf16 qkv input. One block = (b, head, 64 q-rows).
// ---------------------------------------------------------------------------
__global__ __launch_bounds__(256) void attn_mfma(const ushort_t* __restrict__ qkv,
                                                 ushort_t* __restrict__ ao) {
  __shared__ unsigned short Qs[4096];
  __shared__ unsigned short Ks[4096];
  __shared__ unsigned short Vt[4096];
  __shared__ unsigned short Ps[4096];
  const int tid = threadIdx.x;
  const int blk = blockIdx.x;                    // ((b*8 + h)*16 + qt)
  const int qt = blk & 15, hh = (blk >> 4) & 7, b = blk >> 7;
  const int l0 = qt * 64;
  const size_t bb = (size_t)b * 1024 * 1536;

  const int srow = tid >> 2;                     // staging row 0..63
  const int sdb = (tid & 3) << 4;                // staging d-block 0/16/32/48
  const int sc0 = sdb >> 3;

  {
    const ushort_t* qp = qkv + bb + (size_t)(l0 + srow) * 1536 + hh * 64 + sdb;
    *(bfrag*)&Qs[srow * 64 + ((sc0 ^ (srow & 7)) << 3)] = *(const bfrag*)qp;
    *(bfrag*)&Qs[srow * 64 + (((sc0 + 1) ^ (srow & 7)) << 3)] = *(const bfrag*)(qp + 8);
  }

  const int wid = tid >> 6, lane = tid & 63;
  const int l15 = lane & 15, rg = lane >> 4;
  const int l7 = l15 & 7;
  float m[4], lsum[4];
  f32x4 oacc[4];
#pragma unroll
  for (int r = 0; r < 4; ++r) { m[r] = -1e30f; lsum[r] = 0.f; }
#pragma unroll
  for (int nt = 0; nt < 4; ++nt) oacc[nt] = (f32x4)(0.f);

  for (int jt = 0; jt < 16; ++jt) {
    {
      const ushort_t* kp = qkv + bb + (size_t)(jt * 64 + srow) * 1536 + hh * 64 + 512 + sdb;
      *(bfrag*)&Ks[srow * 64 + ((sc0 ^ (srow & 7)) << 3)] = *(const bfrag*)kp;
      *(bfrag*)&Ks[srow * 64 + (((sc0 + 1) ^ (srow & 7)) << 3)] = *(const bfrag*)(kp + 8);
      const ushort_t* vp = kp + 512;
      unsigned short vv[16];
      *(bfrag*)&vv[0] = *(const bfrag*)vp;
      *(bfrag*)&vv[8] = *(const bfrag*)(vp + 8);
#pragma unroll
      for (int j = 0; j < 16; ++j) {
        int dd = sdb + j;
        Vt[dd * 64 + (((srow >> 3) ^ (dd & 7)) << 3) + (srow & 7)] = vv[j];
      }
    }
    __syncthreads();

    bfrag aq[2];
#pragma unroll
    for (int ks = 0; ks < 2; ++ks)
      aq[ks] = *(const bfrag*)&Qs[(wid * 16 + l15) * 64 + (((ks * 4 + rg) ^ l7) << 3)];
    f32x4 sc[4];
#pragma unroll
    for (int nt = 0; nt < 4; ++nt) {
      f32x4 s = (f32x4)(0.f);
#pragma unroll
      for (int ks = 0; ks < 2; ++ks) {
        bfrag bk = *(const bfrag*)&Ks[(nt * 16 + l15) * 64 + (((ks * 4 + rg) ^ l7) << 3)];
        s = __builtin_amdgcn_mfma_f32_16x16x32_bf16(aq[ks], bk, s, 0, 0, 0);
      }
      sc[nt] = s * 0.125f;
    }

#pragma unroll
    for (int r = 0; r < 4; ++r) {
      float mc = fmaxf(fmaxf(sc[0][r], sc[1][r]), fmaxf(sc[2][r], sc[3][r]));
#pragma unroll
      for (int o = 8; o; o >>= 1) mc = fmaxf(mc, __shfl_xor(mc, o));
      float mn = fmaxf(m[r], mc);
      float al = __expf(m[r] - mn);
      m[r] = mn;
      int prow = rg * 4 + r;
      float ps = 0.f;
#pragma unroll
      for (int nt = 0; nt < 4; ++nt) {
        float p = __expf(sc[nt][r] - mn);
        ps += p;
        int col = nt * 16 + l15;
        Ps[wid * 1024 + prow * 64 + ((((col >> 3) ^ (prow & 7))) << 3) + (col & 7)] = f2bf(p);
      }
#pragma unroll
      for (int o = 8; o; o >>= 1) ps += __shfl_xor(ps, o);
      lsum[r] = lsum[r] * al + ps;
#pragma unroll
      for (int nt = 0; nt < 4; ++nt) oacc[nt][r] *= al;
    }

    bfrag ap[2];
#pragma unroll
    for (int ks = 0; ks < 2; ++ks)
      ap[ks] = *(const bfrag*)&Ps[wid * 1024 + l15 * 64 + (((ks * 4 + rg) ^ l7) << 3)];
#pragma unroll
    for (int nt = 0; nt < 4; ++nt) {
#pragma unroll
      for (int ks = 0; ks < 2; ++ks) {
        bfrag bv = *(const bfrag*)&Vt[(nt * 16 + l15) * 64 + (((ks * 4 + rg) ^ l7) << 3)];
        oacc[nt] = __builtin_amdgcn_mfma_f32_16x16x32_bf16(ap[ks], bv, oacc[nt], 0, 0, 0);
      }
    }
    __syncthreads();
  }

#pragma unroll
  for (int r = 0; r < 4; ++r) {
    float inv = 1.f / lsum[r];
    int row = l0 + wid * 16 + rg * 4 + r;
    ushort_t* op = ao + ((size_t)(b * 1024 + row)) * 512 + hh * 64;
#pragma unroll
    for (int nt = 0; nt < 4; ++nt) op[nt * 16 + l15] = f2bf(oacc[nt][r] * inv);
  }
}

// ---------------------------------------------------------------------------
// Mean over L, two-pass.
// ---------------------------------------------------------------------------
__global__ __launch_bounds__(512) void mean_part(const float* __restrict__ h,
                                                 float* __restrict__ part) {
  int blk = blockIdx.x;                       // b*16 + lc
  int b = blk >> 4, lc = blk & 15, d = threadIdx.x;
  float s = 0.f;
  int l0 = lc * 64;
  for (int l = l0; l < l0 + 64; ++l) s += h[(((size_t)(b * 1024 + l)) << 9) + d];
  part[((size_t)blk << 9) + d] = s;
}
__global__ __launch_bounds__(256) void mean_final(const float* __restrict__ part,
                                                  float* __restrict__ out2) {
  int i = blockIdx.x * 256 + threadIdx.x;     // b*512 + d
  int b = i >> 9, d = i & 511;
  float s = 0.f;
#pragma unroll
  for (int c = 0; c < 16; ++c) s += part[(((size_t)(b * 16 + c)) << 9) + d];
  out2[i] = s * (1.f / 1024.f);
}

// ---------------------------------------------------------------------------
extern "C" void kernel_launch(void* const* d_in, const int* in_sizes, int n_in,
                              void* d_out, int out_size, void* d_ws, size_t ws_size,
                              hipStream_t stream) {
  const float* x        = (const float*)d_in[0];
  const float* proj_w   = (const float*)d_in[1];
  const float* proj_b   = (const float*)d_in[2];
  const float* m_in_w   = (const float*)d_in[3];
  const float* m_conv_w = (const float*)d_in[4];
  const float* m_conv_b = (const float*)d_in[5];
  const float* m_xproj_w= (const float*)d_in[6];
  const float* m_dt_w   = (const float*)d_in[7];
  const float* m_dt_b   = (const float*)d_in[8];
  const float* m_Alog   = (const float*)d_in[9];
  const float* m_D      = (const float*)d_in[10];
  const float* m_out_w  = (const float*)d_in[11];
  const float* m_ln_w   = (const float*)d_in[12];
  const float* m_ln_b   = (const float*)d_in[13];
  const float* t_qkv_w  = (const float*)d_in[14];
  const float* t_qkv_b  = (const float*)d_in[15];
  const float* t_ow     = (const float*)d_in[16];
  const float* t_ob     = (const float*)d_in[17];
  const float* t_l1w    = (const float*)d_in[18];
  const float* t_l1b    = (const float*)d_in[19];
  const float* t_l2w    = (const float*)d_in[20];
  const float* t_l2b    = (const float*)d_in[21];
  const float* t_ln1w   = (const float*)d_in[22];
  const float* t_ln1b   = (const float*)d_in[23];
  const float* t_ln2w   = (const float*)d_in[24];
  const float* t_ln2b   = (const float*)d_in[25];
  const float* no_w     = (const float*)d_in[26];
  const float* no_b     = (const float*)d_in[27];

  float* ws   = (float*)d_ws;
  float* h    = ws;                                   //  4M f
  ushort_t* h_bf = (ushort_t*)(ws + 4194304);         //  4M us (2M f)
  float* bufA = ws + 6291456;                         // 16M f (xz f32 / qkv_bf / ff1_bf)
  float* bufB = bufA + 16777216;                      //  8M f (xc_bf / ao_bf)
  float* bufC = bufB + 8388608;                       //  8M f (xproj partials / dt / split-K partials)
  float* bufE = bufC + 8388608;                       //  4M f (scan scratch / GEMM out)
  float* bufF = bufE + 4194304;                       //  0.5M f (xdb f32 / mean partials)
  ushort_t* y_bf = (ushort_t*)(bufF + 524288);        //  8M us (4M f)
  ushort_t* wbf  = (ushort_t*)(bufF + 524288 + 4194304);
  float* scrP = bufE;
  float* scrL = bufE + 2097152;

  // bf16 weight pool offsets (ushort units)
  ushort_t* wIN  = wbf;                 // 2 x 2048 x 512   = 2,097,152
  ushort_t* wOUT = wbf + 2097152;       // 2 x 512 x 1024   = 1,048,576
  ushort_t* wQKV = wbf + 3145728;       // 2 x 1536 x 512   = 1,572,864
  ushort_t* wOW  = wbf + 4718592;       // 2 x 512 x 512    =   524,288
  ushort_t* wL1  = wbf + 5242880;       // 2 x 2048 x 512   = 2,097,152
  ushort_t* wL2  = wbf + 7340032;       // 2 x 512 x 2048   = 2,097,152
  ushort_t* wXP  = wbf + 9437184;       // 2 x 64 x 1024    =   131,072
  ushort_t* wDT  = wbf + 9568256;       // 2 x 1024 x 32    =    65,536
  ushort_t* xdb_bf = wbf + 9633792;     // 8192 x 64        =   524,288

  cvt_bf16<<<2048, 256, 0, stream>>>(m_in_w,  wIN,  524288);
  cvt_bf16<<<1024, 256, 0, stream>>>(m_out_w, wOUT, 262144);
  cvt_bf16<<<1536, 256, 0, stream>>>(t_qkv_w, wQKV, 393216);
  cvt_bf16<<< 512, 256, 0, stream>>>(t_ow,    wOW,  131072);
  cvt_bf16<<<2048, 256, 0, stream>>>(t_l1w,   wL1,  524288);
  cvt_bf16<<<2048, 256, 0, stream>>>(t_l2w,   wL2,  524288);
  cvt_bf16<<< 128, 256, 0, stream>>>(m_xproj_w, wXP, 32768);
  cvt_bf16<<<  64, 256, 0, stream>>>(m_dt_w,  wDT,  16384);

  proj_kernel<<<16384, 256, 0, stream>>>(x, proj_w, proj_b, h, h_bf);

  for (int i = 0; i < 2; ++i) {
    // xz = h @ in_w^T   (8192 x 2048, K=512) -> fp32
    gemm_gll<0, 0, 1, 128><<<dim3(16, 64), 256, 0, stream>>>(
        h_bf, wIN + (size_t)i * 1048576, nullptr, bufA, DMODEL, DMODEL, 2 * DINNER);
    // xc = silu(causal_conv(xm)) -> bf16
    conv_silu_kernel<<<32768, 256, 0, stream>>>(bufA, m_conv_w + i * DINNER * 4,
                                                m_conv_b + i * DINNER, (ushort_t*)bufB);
    // xdb = xc @ xp_w^T  (8192 x 64, K=1024), MFMA split-K=8 -> partials bufC
    gemm_gll<0, 0, 8, 64><<<dim3(1, 64, 8), 256, 0, stream>>>(
        (const ushort_t*)bufB, wXP + (size_t)i * 65536, nullptr, bufC,
        DINNER, DINNER, 64);
    reduce8_xdb<<<512, 256, 0, stream>>>(bufC, bufF, xdb_bf);
    // dt = softplus(xdb[:, :32] @ dt_w^T + dt_b), MFMA K=32 -> bufC fp32
    gemm_gll<2, 0, 1, 128><<<dim3(8, 64), 256, 0, stream>>>(
        xdb_bf, wDT + (size_t)i * 32768, m_dt_b + i * DINNER, bufC,
        DTRANK, 64, DINNER);
    // chunked selective scan (state-split x4) -> y_bf (bf16)
    scan_pass1<<<2048, 256, 0, stream>>>(bufC, bufF, (const ushort_t*)bufB,
                                         m_Alog + (size_t)i * DINNER * DSTATE, scrP, scrL);
    scan_pass2<<<512, 256, 0, stream>>>(scrP, scrL);
    scan_pass3<<<2048, 256, 0, stream>>>(bufC, bufF, (const ushort_t*)bufB, bufA, y_bf,
                                         m_Alog + (size_t)i * DINNER * DSTATE,
                                         m_D + i * DINNER, scrL);
    // mamba_out = y @ out_w^T  (8192 x 512, K=1024), split-K=2 (dt dead)
    gemm_gll<0, 0, 2, 128><<<dim3(4, 64, 2), 256, 0, stream>>>(
        y_bf, wOUT + (size_t)i * 524288, nullptr, bufC, DINNER, DINNER, DMODEL);
    splitk_reduce<<<4096, 256, 0, stream>>>(bufC, nullptr, bufE);
    // h = LN(h + mamba_out), refresh h_bf
    resid_ln_kernel<<<8192, 128, 0, stream>>>(h, bufE, m_ln_w + i * DMODEL,
                                              m_ln_b + i * DMODEL, h, h_bf);
  }

  posenc_kernel<<<16384, 256, 0, stream>>>(h, h_bf);

  for (int i = 0; i < 2; ++i) {
    // qkv = h @ qkv_w^T + qkv_b  (8192 x 1536, K=512) -> bf16
    gemm_gll<0, 1, 1, 128><<<dim3(12, 64), 256, 0, stream>>>(
        h_bf, wQKV + (size_t)i * 786432, t_qkv_b + i * 3 * DMODEL, bufA,
        DMODEL, DMODEL, 3 * DMODEL);
    // MFMA flash attention -> ao bf16
    attn_mfma<<<1024, 256, 0, stream>>>((const ushort_t*)bufA, (ushort_t*)bufB);
    // attn_proj = ao @ ow^T + ob  (8192 x 512, K=512), split-K=2
    gemm_gll<0, 0, 2, 128><<<dim3(4, 64, 2), 256, 0, stream>>>(
        (const ushort_t*)bufB, wOW + (size_t)i * 262144, nullptr, bufC,
        DMODEL, DMODEL, DMODEL);
    splitk_reduce<<<4096, 256, 0, stream>>>(bufC, t_ob + i * DMODEL, bufE);
    // h = LN(h + attn_proj)
    resid_ln_kernel<<<8192, 128, 0, stream>>>(h, bufE, t_ln1w + i * DMODEL,
                                              t_ln1b + i * DMODEL, h, h_bf);
    // ff1 = relu(h @ l1w^T + l1b)  (8192 x 2048, K=512) -> bf16
    gemm_gll<1, 1, 1, 128><<<dim3(16, 64), 256, 0, stream>>>(
        h_bf, wL1 + (size_t)i * 1048576, t_l1b + i * DFF, bufA,
        DMODEL, DMODEL, DFF);
    // ff2 = ff1 @ l2w^T + l2b  (8192 x 512, K=2048), split-K=2
    gemm_gll<0, 0, 2, 128><<<dim3(4, 64, 2), 256, 0, stream>>>(
        (const ushort_t*)bufA, wL2 + (size_t)i * 1048576, nullptr, bufC,
        DFF, DFF, DMODEL);
    splitk_reduce<<<4096, 256, 0, stream>>>(bufC, t_l2b + i * DMODEL, bufE);
    // h = LN(h + ff2)
    resid_ln_kernel<<<8192, 128, 0, stream>>>(h, bufE, t_ln2w + i * DMODEL,
                                              t_ln2b + i * DMODEL, h, h_bf);
  }

  // final LN -> d_out, then mean over L -> d_out tail
  float* out_h = (float*)d_out;
  resid_ln_kernel<<<8192, 128, 0, stream>>>(h, nullptr, no_w, no_b, out_h, nullptr);
  mean_part<<<128, 512, 0, stream>>>(out_h, bufF);
  mean_final<<<16, 256, 0, stream>>>(bufF, out_h + 4194304);
}

// Round 9
// 963.777 us; speedup vs baseline: 1.5066x; 1.0245x over previous
//
#include <hip/hip_runtime.h>
#include <cstddef>

// Problem constants
#define BATCH 8
#define LSEQ 1024
#define DMODEL 512
#define DINNER 1024
#define DSTATE 16
#define DTRANK 32
#define NHEAD 8
#define DHEAD 64
#define DFF 2048
#define MTOK 8192   // BATCH*LSEQ
#define NCHUNK 16
#define CLEN 64     // LSEQ / NCHUNK

typedef __attribute__((ext_vector_type(8))) short bfrag;          // 8 bf16 = 16 B
typedef __attribute__((ext_vector_type(4))) float f32x4;          // MFMA acc
typedef __attribute__((ext_vector_type(4))) unsigned short us4;
typedef unsigned short ushort_t;

__device__ __forceinline__ float silu_f(float x) { return x / (1.f + __expf(-x)); }

__device__ __forceinline__ unsigned short f2bf(float f) {  // RNE fp32->bf16
  unsigned u = __float_as_uint(f);
  return (unsigned short)((u + 0x7FFFu + ((u >> 16) & 1u)) >> 16);
}
__device__ __forceinline__ float bf2f(ushort_t u) {
  return __uint_as_float((unsigned)u << 16);
}

// async global->LDS, 16B per lane. LDS dest = wave-uniform base + lane*16.
__device__ __forceinline__ void gll16(const ushort_t* g, ushort_t* l) {
  __builtin_amdgcn_global_load_lds(
      (const __attribute__((address_space(1))) unsigned int*)g,
      (__attribute__((address_space(3))) unsigned int*)l, 16, 0, 0);
}

// ---------------------------------------------------------------------------
// fp32 -> bf16 bulk convert (vectorized x4). n4 = element count / 4.
// ---------------------------------------------------------------------------
__global__ __launch_bounds__(256) void cvt_bf16(const float* __restrict__ s,
                                                ushort_t* __restrict__ d, int n4) {
  int i = blockIdx.x * 256 + threadIdx.x;
  if (i >= n4) return;
  float4 v = ((const float4*)s)[i];
  us4 o = {f2bf(v.x), f2bf(v.y), f2bf(v.z), f2bf(v.w)};
  ((us4*)d)[i] = o;
}

// ---------------------------------------------------------------------------
// Input projection: h[b,l,d] = sum_c x[b,c,l] * pw[d,c] + pb[d]; also bf16 copy.
// ---------------------------------------------------------------------------
__global__ __launch_bounds__(256) void proj_kernel(const float* __restrict__ x,
                                                   const float* __restrict__ pw,
                                                   const float* __restrict__ pb,
                                                   float* __restrict__ h,
                                                   ushort_t* __restrict__ hbf) {
  int idx = blockIdx.x * 256 + threadIdx.x;        // ((b*L)+l)*512 + d
  int d = idx & 511;
  int l = (idx >> 9) & 1023;
  int b = idx >> 19;
  const float* xb = x + (size_t)b * 3 * 1024 + l;
  float v = pb[d] + xb[0] * pw[d * 3] + xb[1024] * pw[d * 3 + 1] + xb[2048] * pw[d * 3 + 2];
  h[idx] = v;
  hbf[idx] = f2bf(v);
}

// ---------------------------------------------------------------------------
// bf16 MFMA GEMM, global_load_lds + double-buffered prefetch.
// C[m,n] = act( sum_k A[m,k]*W[n,k] + bias[n] ).  Tile 128 x BN, BK=32.
// BN=128: 4 waves 2x2 (64x64). BN=64: 4 waves 4x1 (32x64), 3 glls/stage.
// ACT: 0 none, 1 relu, 2 softplus. CBF: 1 bf16 C, 0 fp32 C.
// SPLITK: 1 direct; >1 -> fp32 partials at Cp + z*8192*ldc (no bias/act).
// ---------------------------------------------------------------------------
template <int ACT, int CBF, int SPLITK, int BN>
__global__ __launch_bounds__(256) void gemm_gll(const ushort_t* __restrict__ A,
                                                const ushort_t* __restrict__ W,
                                                const float* __restrict__ bias,
                                                void* __restrict__ Cp,
                                                int K, int lda, int ldc) {
  __shared__ ushort_t sA[2][4096];
  __shared__ ushort_t sB[2][BN * 32];
  constexpr int MREP = (BN == 128) ? 4 : 2;
  const int bm = blockIdx.y * 128, bn = blockIdx.x * BN;
  const int tid = threadIdx.x;
  const int wid = tid >> 6, lane = tid & 63;
  const int wrb = (BN == 128) ? (wid >> 1) * 64 : wid * 32;
  const int wcb = (BN == 128) ? (wid & 1) * 64 : 0;
  const int lr = lane & 15, ls = lane >> 4;
  const int sw = ls ^ ((lr >> 1) & 3);

  const int kseg = K / SPLITK;
  const int kbeg = (SPLITK > 1) ? blockIdx.z * kseg : 0;

  const int c0 = wid * 128 + lane;
  const int c1 = c0 + 64;
  const int r0 = c0 >> 2, s0 = (c0 & 3) ^ ((r0 >> 1) & 3);
  const int r1 = c1 >> 2, s1 = (c1 & 3) ^ ((r1 >> 1) & 3);
  const ushort_t* gA0 = A + (size_t)(bm + r0) * lda + kbeg + s0 * 8;
  const ushort_t* gA1 = A + (size_t)(bm + r1) * lda + kbeg + s1 * 8;
  const ushort_t* gB0;
  const ushort_t* gB1 = nullptr;
  if constexpr (BN == 128) {
    gB0 = W + (size_t)(bn + r0) * K + kbeg + s0 * 8;
    gB1 = W + (size_t)(bn + r1) * K + kbeg + s1 * 8;
  } else {
    const int cb = wid * 64 + lane;
    const int rb = cb >> 2, sb2 = (cb & 3) ^ ((rb >> 1) & 3);
    gB0 = W + (size_t)(bn + rb) * K + kbeg + sb2 * 8;
  }

  f32x4 acc[MREP][4];
#pragma unroll
  for (int i = 0; i < MREP; ++i)
#pragma unroll
    for (int j = 0; j < 4; ++j) acc[i][j] = (f32x4)(0.f);

#define STAGE(buf, step)                                             \
  do {                                                               \
    gll16(gA0 + (step) * 32, &sA[buf][wid * 1024]);                  \
    gll16(gA1 + (step) * 32, &sA[buf][wid * 1024 + 512]);            \
    if constexpr (BN == 128) {                                       \
      gll16(gB0 + (step) * 32, &sB[buf][wid * 1024]);                \
      gll16(gB1 + (step) * 32, &sB[buf][wid * 1024 + 512]);          \
    } else {                                                         \
      gll16(gB0 + (step) * 32, &sB[buf][wid * 512]);                 \
    }                                                                \
  } while (0)

  const int NT = kseg / 32;
  STAGE(0, 0);
  for (int t = 0; t < NT; ++t) {
    const int cur = t & 1;
    if (t + 1 < NT) {
      STAGE(cur ^ 1, t + 1);
      if constexpr (BN == 128)
        asm volatile("s_waitcnt vmcnt(4)" ::: "memory");
      else
        asm volatile("s_waitcnt vmcnt(3)" ::: "memory");
    } else {
      asm volatile("s_waitcnt vmcnt(0)" ::: "memory");
    }
    __builtin_amdgcn_sched_barrier(0);
    __builtin_amdgcn_s_barrier();
    __builtin_amdgcn_sched_barrier(0);

    bfrag af[MREP], bf[4];
#pragma unroll
    for (int mi = 0; mi < MREP; ++mi) {
      int row = wrb + mi * 16 + lr;
      af[mi] = *(const bfrag*)&sA[cur][(size_t)((row << 2) + sw) * 8];
    }
#pragma unroll
    for (int nj = 0; nj < 4; ++nj) {
      int col = wcb + nj * 16 + lr;
      bf[nj] = *(const bfrag*)&sB[cur][(size_t)((col << 2) + sw) * 8];
    }
#pragma unroll
    for (int mi = 0; mi < MREP; ++mi)
#pragma unroll
      for (int nj = 0; nj < 4; ++nj)
        acc[mi][nj] = __builtin_amdgcn_mfma_f32_16x16x32_bf16(af[mi], bf[nj], acc[mi][nj], 0, 0, 0);

    __builtin_amdgcn_s_barrier();
    __builtin_amdgcn_sched_barrier(0);
  }
#undef STAGE

  if (SPLITK > 1) {
    float* Cz = (float*)Cp + (size_t)blockIdx.z * 8192 * ldc;
#pragma unroll
    for (int nj = 0; nj < 4; ++nj) {
      int col = bn + wcb + nj * 16 + lr;
#pragma unroll
      for (int mi = 0; mi < MREP; ++mi) {
        int row0 = bm + wrb + mi * 16 + ls * 4;
#pragma unroll
        for (int r = 0; r < 4; ++r)
          Cz[(size_t)(row0 + r) * ldc + col] = acc[mi][nj][r];
      }
    }
  } else {
#pragma unroll
    for (int nj = 0; nj < 4; ++nj) {
      int col = bn + wcb + nj * 16 + lr;
      float bv = bias ? bias[col] : 0.f;
#pragma unroll
      for (int mi = 0; mi < MREP; ++mi) {
        int row0 = bm + wrb + mi * 16 + ls * 4;
#pragma unroll
        for (int r = 0; r < 4; ++r) {
          float v = acc[mi][nj][r] + bv;
          if (ACT == 1) v = fmaxf(v, 0.f);
          if (ACT == 2) v = (v > 20.f) ? v : log1pf(__expf(v));
          if (CBF)
            ((ushort_t*)Cp)[(size_t)(row0 + r) * ldc + col] = f2bf(v);
          else
            ((float*)Cp)[(size_t)(row0 + r) * ldc + col] = v;
        }
      }
    }
  }
}

// ---------------------------------------------------------------------------
// split-K=8 reduce for xproj: xdb fp32 + bf16 copy. 131072 float4 groups.
// ---------------------------------------------------------------------------
__global__ __launch_bounds__(256) void reduce8_xdb(const float* __restrict__ p,
                                                   float* __restrict__ xdb,
                                                   ushort_t* __restrict__ xdb_bf) {
  int i = blockIdx.x * 256 + threadIdx.x;
  float4 a = ((const float4*)p)[i];
#pragma unroll
  for (int z = 1; z < 8; ++z) {
    float4 b = ((const float4*)p)[i + z * 131072];
    a.x += b.x; a.y += b.y; a.z += b.z; a.w += b.w;
  }
  ((float4*)xdb)[i] = a;
  us4 o = {f2bf(a.x), f2bf(a.y), f2bf(a.z), f2bf(a.w)};
  ((us4*)xdb_bf)[i] = o;
}

// ---------------------------------------------------------------------------
// Depthwise causal conv (width 4) + SiLU. xz is bf16 (row stride 2048) -> bf16 xc.
// ---------------------------------------------------------------------------
__global__ __launch_bounds__(256) void conv_silu_kernel(const ushort_t* __restrict__ xz,
                                                        const float* __restrict__ cw,
                                                        const float* __restrict__ cb,
                                                        ushort_t* __restrict__ xc) {
  int idx = blockIdx.x * 256 + threadIdx.x;        // ((b*L)+t)*1024 + d
  int d = idx & 1023;
  int t = (idx >> 10) & 1023;
  int b = idx >> 20;
  float acc = cb[d];
#pragma unroll
  for (int w = 0; w < 4; ++w) {
    int tt = t - 3 + w;
    if (tt >= 0) acc += bf2f(xz[(((size_t)(b * 1024 + tt)) << 11) + d]) * cw[d * 4 + w];
  }
  xc[idx] = f2bf(silu_f(acc));
}

// ---------------------------------------------------------------------------
// Chunked selective scan, STATE-SPLIT x4. xc bf16.
// ---------------------------------------------------------------------------
__global__ __launch_bounds__(256) void scan_pass1(const float* __restrict__ dt,
                                                  const float* __restrict__ xdb,
                                                  const ushort_t* __restrict__ xc,
                                                  const float* __restrict__ Alog,
                                                  float* __restrict__ scrP,
                                                  float* __restrict__ scrL) {
  int idx = blockIdx.x * 256 + threadIdx.x;
  int sh = idx & 3;
  int d = (idx >> 2) & 1023;
  int c = (idx >> 12) & 15;
  int b = idx >> 16;
  float A[4], st[4], P[4];
#pragma unroll
  for (int s = 0; s < 4; ++s) {
    A[s] = -__expf(Alog[d * 16 + sh * 4 + s]);
    st[s] = 0.f;
    P[s] = 1.f;
  }
  int t0 = c * CLEN;
  size_t base = (((size_t)(b * 1024 + t0)) << 10) + d;
  const float* xb = xdb + (size_t)(b * 1024 + t0) * 64 + 32 + sh * 4;
  float dtv = dt[base], xv = bf2f(xc[base]);
  for (int t = 0; t < CLEN; ++t) {
    float dtn = 0.f, xvn = 0.f;
    if (t + 1 < CLEN) { dtn = dt[base + 1024]; xvn = bf2f(xc[base + 1024]); }
    float4 Bv = *(const float4*)xb;
    float dx = dtv * xv;
    float e0 = __expf(dtv * A[0]), e1 = __expf(dtv * A[1]);
    float e2 = __expf(dtv * A[2]), e3 = __expf(dtv * A[3]);
    st[0] = st[0] * e0 + dx * Bv.x; P[0] *= e0;
    st[1] = st[1] * e1 + dx * Bv.y; P[1] *= e1;
    st[2] = st[2] * e2 + dx * Bv.z; P[2] *= e2;
    st[3] = st[3] * e3 + dx * Bv.w; P[3] *= e3;
    base += 1024; xb += 64;
    dtv = dtn; xv = xvn;
  }
  size_t pbase = (((size_t)((b * 16 + c) * 16 + sh * 4)) << 10) + d;
#pragma unroll
  for (int s = 0; s < 4; ++s) {
    scrP[pbase + ((size_t)s << 10)] = P[s];
    scrL[pbase + ((size_t)s << 10)] = st[s];
  }
}

// ---------------------------------------------------------------------------
// Pass 2: combine chunks serially per (b,d,s).
// ---------------------------------------------------------------------------
__global__ __launch_bounds__(256) void scan_pass2(const float* __restrict__ scrP,
                                                  float* __restrict__ scrL) {
  int idx = blockIdx.x * 256 + threadIdx.x;        // ((b*16 + s)*1024 + d)
  int d = idx & 1023;
  int s = (idx >> 10) & 15;
  int b = idx >> 14;
  float cur = 0.f;
  for (int c = 0; c < 16; ++c) {
    size_t o = (((size_t)(((b * 16 + c) * 16) + s)) << 10) + d;
    float P = scrP[o];
    float loc = scrL[o];
    scrL[o] = cur;
    cur = cur * P + loc;
  }
}

// ---------------------------------------------------------------------------
// Pass 3: state-split x4 rescan; quad-reduce via shfl_xor; bf16 y out.
// z gate read from bf16 xz.
// ---------------------------------------------------------------------------
__global__ __launch_bounds__(256) void scan_pass3(const float* __restrict__ dt,
                                                  const float* __restrict__ xdb,
                                                  const ushort_t* __restrict__ xc,
                                                  const ushort_t* __restrict__ xz,
                                                  ushort_t* __restrict__ ybf,
                                                  const float* __restrict__ Alog,
                                                  const float* __restrict__ Dp,
                                                  const float* __restrict__ scrL) {
  int idx = blockIdx.x * 256 + threadIdx.x;
  int sh = idx & 3;
  int d = (idx >> 2) & 1023;
  int c = (idx >> 12) & 15;
  int b = idx >> 16;
  float A[4], st[4];
  size_t pbase = (((size_t)((b * 16 + c) * 16 + sh * 4)) << 10) + d;
#pragma unroll
  for (int s = 0; s < 4; ++s) {
    A[s] = -__expf(Alog[d * 16 + sh * 4 + s]);
    st[s] = scrL[pbase + ((size_t)s << 10)];
  }
  float Dv = Dp[d];
  int t0 = c * CLEN;
  size_t base = (((size_t)(b * 1024 + t0)) << 10) + d;
  size_t zoff = ((((size_t)(b * 1024 + t0)) << 11)) + 1024 + d;
  const float* xb = xdb + (size_t)(b * 1024 + t0) * 64 + 32 + sh * 4;
  float dtv = dt[base], xv = bf2f(xc[base]), zv = bf2f(xz[zoff]);
  for (int t = 0; t < CLEN; ++t) {
    float dtn = 0.f, xvn = 0.f, zvn = 0.f;
    if (t + 1 < CLEN) {
      dtn = dt[base + 1024]; xvn = bf2f(xc[base + 1024]); zvn = bf2f(xz[zoff + 2048]);
    }
    float4 Bv = *(const float4*)xb;
    float4 Cv = *(const float4*)(xb + 16);
    float dx = dtv * xv;
    float e0 = __expf(dtv * A[0]), e1 = __expf(dtv * A[1]);
    float e2 = __expf(dtv * A[2]), e3 = __expf(dtv * A[3]);
    st[0] = st[0] * e0 + dx * Bv.x;
    st[1] = st[1] * e1 + dx * Bv.y;
    st[2] = st[2] * e2 + dx * Bv.z;
    st[3] = st[3] * e3 + dx * Bv.w;
    float acc = st[0] * Cv.x + st[1] * Cv.y + st[2] * Cv.z + st[3] * Cv.w;
    acc += __shfl_xor(acc, 1);
    acc += __shfl_xor(acc, 2);
    if (sh == 0)
      ybf[base] = f2bf((acc + Dv * xv) * silu_f(zv));
    base += 1024; zoff += 2048; xb += 64;
    dtv = dtn; xv = xvn; zv = zvn;
  }
}

// ---------------------------------------------------------------------------
// Residual + LayerNorm. add / out_bf may be nullptr.
// ---------------------------------------------------------------------------
__global__ __launch_bounds__(128) void resid_ln_kernel(const float* __restrict__ x,
                                                       const float* __restrict__ add,
                                                       const float* __restrict__ w,
                                                       const float* __restrict__ bias,
                                                       float* __restrict__ out,
                                                       ushort_t* __restrict__ out_bf) {
  int row = blockIdx.x, tid = threadIdx.x;
  float4 v = ((const float4*)(x + (size_t)row * 512))[tid];
  if (add) {
    float4 a = ((const float4*)(add + (size_t)row * 512))[tid];
    v.x += a.x; v.y += a.y; v.z += a.z; v.w += a.w;
  }
  float s = v.x + v.y + v.z + v.w;
  float ss = v.x * v.x + v.y * v.y + v.z * v.z + v.w * v.w;
#pragma unroll
  for (int o = 32; o; o >>= 1) {
    s += __shfl_xor(s, o);
    ss += __shfl_xor(ss, o);
  }
  __shared__ float red[4];
  int wid = tid >> 6;
  if ((tid & 63) == 0) { red[wid] = s; red[2 + wid] = ss; }
  __syncthreads();
  s = red[0] + red[1];
  ss = red[2] + red[3];
  float mean = s * (1.f / 512.f);
  float var = ss * (1.f / 512.f) - mean * mean;
  float inv = rsqrtf(var + 1e-5f);
  float4 wv = ((const float4*)w)[tid];
  float4 bv = ((const float4*)bias)[tid];
  float4 ov;
  ov.x = (v.x - mean) * inv * wv.x + bv.x;
  ov.y = (v.y - mean) * inv * wv.y + bv.y;
  ov.z = (v.z - mean) * inv * wv.z + bv.z;
  ov.w = (v.w - mean) * inv * wv.w + bv.w;
  ((float4*)(out + (size_t)row * 512))[tid] = ov;
  if (out_bf) {
    us4 ob = {f2bf(ov.x), f2bf(ov.y), f2bf(ov.z), f2bf(ov.w)};
    ((us4*)(out_bf + (size_t)row * 512))[tid] = ob;
  }
}

// ---------------------------------------------------------------------------
// Residual + split-K2 sum + optional gemm-bias + LayerNorm, fused.
// v = x + p0 + p1 (+pbias); LN(v) -> out, out_bf.
// ---------------------------------------------------------------------------
__global__ __launch_bounds__(128) void resid_ln_sk(const float* __restrict__ x,
                                                   const float* __restrict__ p,
                                                   const float* __restrict__ pbias,
                                                   const float* __restrict__ w,
                                                   const float* __restrict__ bias,
                                                   float* __restrict__ out,
                                                   ushort_t* __restrict__ out_bf) {
  int row = blockIdx.x, tid = threadIdx.x;
  float4 v = ((const float4*)(x + (size_t)row * 512))[tid];
  float4 a = ((const float4*)(p + (size_t)row * 512))[tid];
  float4 c = ((const float4*)(p + 4194304 + (size_t)row * 512))[tid];
  v.x += a.x + c.x; v.y += a.y + c.y; v.z += a.z + c.z; v.w += a.w + c.w;
  if (pbias) {
    float4 pb = ((const float4*)pbias)[tid];
    v.x += pb.x; v.y += pb.y; v.z += pb.z; v.w += pb.w;
  }
  float s = v.x + v.y + v.z + v.w;
  float ss = v.x * v.x + v.y * v.y + v.z * v.z + v.w * v.w;
#pragma unroll
  for (int o = 32; o; o >>= 1) {
    s += __shfl_xor(s, o);
    ss += __shfl_xor(ss, o);
  }
  __shared__ float red[4];
  int wid = tid >> 6;
  if ((tid & 63) == 0) { red[wid] = s; red[2 + wid] = ss; }
  __syncthreads();
  s = red[0] + red[1];
  ss = red[2] + red[3];
  float mean = s * (1.f / 512.f);
  float var = ss * (1.f / 512.f) - mean * mean;
  float inv = rsqrtf(var + 1e-5f);
  float4 wv = ((const float4*)w)[tid];
  float4 bv = ((const float4*)bias)[tid];
  float4 ov;
  ov.x = (v.x - mean) * inv * wv.x + bv.x;
  ov.y = (v.y - mean) * inv * wv.y + bv.y;
  ov.z = (v.z - mean) * inv * wv.z + bv.z;
  ov.w = (v.w - mean) * inv * wv.w + bv.w;
  ((float4*)(out + (size_t)row * 512))[tid] = ov;
  us4 ob = {f2bf(ov.x), f2bf(ov.y), f2bf(ov.z), f2bf(ov.w)};
  ((us4*)(out_bf + (size_t)row * 512))[tid] = ob;
}

// ---------------------------------------------------------------------------
// Sinusoidal positional encoding add (in-place on h, refresh hbf)
// ---------------------------------------------------------------------------
__global__ __launch_bounds__(256) void posenc_kernel(float* __restrict__ h,
                                                     ushort_t* __restrict__ hbf) {
  int idx = blockIdx.x * 256 + threadIdx.x;
  int d = idx & 511;
  int l = (idx >> 9) & 1023;
  float freq = __expf(-(float)(d & ~1) * (9.210340371976184f / 512.f));
  float ang = (float)l * freq;
  float v = h[idx] + ((d & 1) ? cosf(ang) : sinf(ang));
  h[idx] = v;
  hbf[idx] = f2bf(v);
}

// ---------------------------------------------------------------------------
// MFMA flash attention v2: one block = (b, head, 128 q-rows); 4 waves x 2
// 16-row strips. K/V staged once per kv-tile, reused for 2x MFMA work.
// Q fragments hoisted out of the kv loop. LDS 40KB.
// ---------------------------------------------------------------------------
__global__ __launch_bounds__(256) void attn_mfma(const ushort_t* __restrict__ qkv,
                                                 ushort_t* __restrict__ ao) {
  __shared__ unsigned short Qs[8192];
  __shared__ unsigned short Ks[4096];
  __shared__ unsigned short Vt[4096];
  __shared__ unsigned short Ps[4096];
  const int tid = threadIdx.x;
  const int blk = blockIdx.x;                    // ((b*8 + h)*8 + qt)
  const int qt = blk & 7, hh = (blk >> 3) & 7, b = blk >> 6;
  const int l0 = qt * 128;
  const size_t bb = (size_t)b * 1024 * 1536;

  const int srow = tid >> 2;                     // staging row 0..63
  const int sdb = (tid & 3) << 4;                // staging d-block 0/16/32/48
  const int sc0 = sdb >> 3;

  // stage Q: 128 rows (two 64-row groups per thread)
  {
    const ushort_t* qp = qkv + bb + (size_t)(l0 + srow) * 1536 + hh * 64 + sdb;
    *(bfrag*)&Qs[srow * 64 + ((sc0 ^ (srow & 7)) << 3)] = *(const bfrag*)qp;
    *(bfrag*)&Qs[srow * 64 + (((sc0 + 1) ^ (srow & 7)) << 3)] = *(const bfrag*)(qp + 8);
    const ushort_t* qp2 = qp + (size_t)64 * 1536;
    *(bfrag*)&Qs[(srow + 64) * 64 + ((sc0 ^ (srow & 7)) << 3)] = *(const bfrag*)qp2;
    *(bfrag*)&Qs[(srow + 64) * 64 + (((sc0 + 1) ^ (srow & 7)) << 3)] = *(const bfrag*)(qp2 + 8);
  }
  __syncthreads();

  const int wid = tid >> 6, lane = tid & 63;
  const int l15 = lane & 15, rg = lane >> 4;
  const int l7 = l15 & 7;

  // hoist Q fragments: 2 strips x 2 k-chunks (loop-invariant)
  bfrag aq[2][2];
#pragma unroll
  for (int s = 0; s < 2; ++s)
#pragma unroll
    for (int ks = 0; ks < 2; ++ks) {
      int qr = wid * 32 + s * 16 + l15;
      aq[s][ks] = *(const bfrag*)&Qs[qr * 64 + (((ks * 4 + rg) ^ l7) << 3)];
    }

  float m[2][4], lsum[2][4];
  f32x4 oacc[2][4];
#pragma unroll
  for (int s = 0; s < 2; ++s)
#pragma unroll
    for (int r = 0; r < 4; ++r) { m[s][r] = -1e30f; lsum[s][r] = 0.f; }
#pragma unroll
  for (int s = 0; s < 2; ++s)
#pragma unroll
    for (int nt = 0; nt < 4; ++nt) oacc[s][nt] = (f32x4)(0.f);

  for (int jt = 0; jt < 16; ++jt) {
    // stage K row-major + V transposed
    {
      const ushort_t* kp = qkv + bb + (size_t)(jt * 64 + srow) * 1536 + hh * 64 + 512 + sdb;
      *(bfrag*)&Ks[srow * 64 + ((sc0 ^ (srow & 7)) << 3)] = *(const bfrag*)kp;
      *(bfrag*)&Ks[srow * 64 + (((sc0 + 1) ^ (srow & 7)) << 3)] = *(const bfrag*)(kp + 8);
      const ushort_t* vp = kp + 512;
      unsigned short vv[16];
      *(bfrag*)&vv[0] = *(const bfrag*)vp;
      *(bfrag*)&vv[8] = *(const bfrag*)(vp + 8);
#pragma unroll
      for (int j = 0; j < 16; ++j) {
        int dd = sdb + j;
        Vt[dd * 64 + (((srow >> 3) ^ (dd & 7)) << 3) + (srow & 7)] = vv[j];
      }
    }
    __syncthreads();

#pragma unroll
    for (int s = 0; s < 2; ++s) {
      // S = Q K^T for this strip
      f32x4 sc[4];
#pragma unroll
      for (int nt = 0; nt < 4; ++nt) {
        f32x4 sv = (f32x4)(0.f);
#pragma unroll
        for (int ks = 0; ks < 2; ++ks) {
          bfrag bk = *(const bfrag*)&Ks[(nt * 16 + l15) * 64 + (((ks * 4 + rg) ^ l7) << 3)];
          sv = __builtin_amdgcn_mfma_f32_16x16x32_bf16(aq[s][ks], bk, sv, 0, 0, 0);
        }
        sc[nt] = sv * 0.125f;
      }

      // online softmax; P -> bf16 LDS (per-wave region, same-wave r/w)
#pragma unroll
      for (int r = 0; r < 4; ++r) {
        float mc = fmaxf(fmaxf(sc[0][r], sc[1][r]), fmaxf(sc[2][r], sc[3][r]));
#pragma unroll
        for (int o = 8; o; o >>= 1) mc = fmaxf(mc, __shfl_xor(mc, o));
        float mn = fmaxf(m[s][r], mc);
        float al = __expf(m[s][r] - mn);
        m[s][r] = mn;
        int prow = rg * 4 + r;
        float ps = 0.f;
#pragma unroll
        for (int nt = 0; nt < 4; ++nt) {
          float p = __expf(sc[nt][r] - mn);
          ps += p;
          int col = nt * 16 + l15;
          Ps[wid * 1024 + prow * 64 + ((((col >> 3) ^ (prow & 7))) << 3) + (col & 7)] = f2bf(p);
        }
#pragma unroll
        for (int o = 8; o; o >>= 1) ps += __shfl_xor(ps, o);
        lsum[s][r] = lsum[s][r] * al + ps;
#pragma unroll
        for (int nt = 0; nt < 4; ++nt) oacc[s][nt][r] *= al;
      }

      // O += P V
      bfrag ap[2];
#pragma unroll
      for (int ks = 0; ks < 2; ++ks)
        ap[ks] = *(const bfrag*)&Ps[wid * 1024 + l15 * 64 + (((ks * 4 + rg) ^ l7) << 3)];
#pragma unroll
      for (int nt = 0; nt < 4; ++nt) {
#pragma unroll
        for (int ks = 0; ks < 2; ++ks) {
          bfrag bv = *(const bfrag*)&Vt[(nt * 16 + l15) * 64 + (((ks * 4 + rg) ^ l7) << 3)];
          oacc[s][nt] = __builtin_amdgcn_mfma_f32_16x16x32_bf16(ap[ks], bv, oacc[s][nt], 0, 0, 0);
        }
      }
    }
    __syncthreads();
  }

  // epilogue
#pragma unroll
  for (int s = 0; s < 2; ++s)
#pragma unroll
    for (int r = 0; r < 4; ++r) {
      float inv = 1.f / lsum[s][r];
      int row = l0 + wid * 32 + s * 16 + rg * 4 + r;
      ushort_t* op = ao + ((size_t)(b * 1024 + row)) * 512 + hh * 64;
#pragma unroll
      for (int nt = 0; nt < 4; ++nt) op[nt * 16 + l15] = f2bf(oacc[s][nt][r] * inv);
    }
}

// ---------------------------------------------------------------------------
// Mean over L, two-pass.
// ---------------------------------------------------------------------------
__global__ __launch_bounds__(512) void mean_part(const float* __restrict__ h,
                                                 float* __restrict__ part) {
  int blk = blockIdx.x;                       // b*16 + lc
  int b = blk >> 4, lc = blk & 15, d = threadIdx.x;
  float s = 0.f;
  int l0 = lc * 64;
  for (int l = l0; l < l0 + 64; ++l) s += h[(((size_t)(b * 1024 + l)) << 9) + d];
  part[((size_t)blk << 9) + d] = s;
}
__global__ __launch_bounds__(256) void mean_final(const float* __restrict__ part,
                                                  float* __restrict__ out2) {
  int i = blockIdx.x * 256 + threadIdx.x;     // b*512 + d
  int b = i >> 9, d = i & 511;
  float s = 0.f;
#pragma unroll
  for (int c = 0; c < 16; ++c) s += part[(((size_t)(b * 16 + c)) << 9) + d];
  out2[i] = s * (1.f / 1024.f);
}

// ---------------------------------------------------------------------------
extern "C" void kernel_launch(void* const* d_in, const int* in_sizes, int n_in,
                              void* d_out, int out_size, void* d_ws, size_t ws_size,
                              hipStream_t stream) {
  const float* x        = (const float*)d_in[0];
  const float* proj_w   = (const float*)d_in[1];
  const float* proj_b   = (const float*)d_in[2];
  const float* m_in_w   = (const float*)d_in[3];
  const float* m_conv_w = (const float*)d_in[4];
  const float* m_conv_b = (const float*)d_in[5];
  const float* m_xproj_w= (const float*)d_in[6];
  const float* m_dt_w   = (const float*)d_in[7];
  const float* m_dt_b   = (const float*)d_in[8];
  const float* m_Alog   = (const float*)d_in[9];
  const float* m_D      = (const float*)d_in[10];
  const float* m_out_w  = (const float*)d_in[11];
  const float* m_ln_w   = (const float*)d_in[12];
  const float* m_ln_b   = (const float*)d_in[13];
  const float* t_qkv_w  = (const float*)d_in[14];
  const float* t_qkv_b  = (const float*)d_in[15];
  const float* t_ow     = (const float*)d_in[16];
  const float* t_ob     = (const float*)d_in[17];
  const float* t_l1w    = (const float*)d_in[18];
  const float* t_l1b    = (const float*)d_in[19];
  const float* t_l2w    = (const float*)d_in[20];
  const float* t_l2b    = (const float*)d_in[21];
  const float* t_ln1w   = (const float*)d_in[22];
  const float* t_ln1b   = (const float*)d_in[23];
  const float* t_ln2w   = (const float*)d_in[24];
  const float* t_ln2b   = (const float*)d_in[25];
  const float* no_w     = (const float*)d_in[26];
  const float* no_b     = (const float*)d_in[27];

  float* ws   = (float*)d_ws;
  float* h    = ws;                                   //  4M f
  ushort_t* h_bf = (ushort_t*)(ws + 4194304);         //  4M us (2M f)
  float* bufA = ws + 6291456;                         // 16M f (xz_bf / qkv_bf / ff1_bf)
  float* bufB = bufA + 16777216;                      //  8M f (xc_bf / ao_bf)
  float* bufC = bufB + 8388608;                       //  8M f (xproj partials / dt / split-K partials)
  float* bufE = bufC + 8388608;                       //  4M f (scan scratch)
  float* bufF = bufE + 4194304;                       //  0.5M f (xdb f32 / mean partials)
  ushort_t* y_bf = (ushort_t*)(bufF + 524288);        //  8M us (4M f)
  ushort_t* wbf  = (ushort_t*)(bufF + 524288 + 4194304);
  float* scrP = bufE;
  float* scrL = bufE + 2097152;

  // bf16 weight pool offsets (ushort units)
  ushort_t* wIN  = wbf;                 // 2 x 2048 x 512   = 2,097,152
  ushort_t* wOUT = wbf + 2097152;       // 2 x 512 x 1024   = 1,048,576
  ushort_t* wQKV = wbf + 3145728;       // 2 x 1536 x 512   = 1,572,864
  ushort_t* wOW  = wbf + 4718592;       // 2 x 512 x 512    =   524,288
  ushort_t* wL1  = wbf + 5242880;       // 2 x 2048 x 512   = 2,097,152
  ushort_t* wL2  = wbf + 7340032;       // 2 x 512 x 2048   = 2,097,152
  ushort_t* wXP  = wbf + 9437184;       // 2 x 64 x 1024    =   131,072
  ushort_t* wDT  = wbf + 9568256;       // 2 x 1024 x 32    =    65,536
  ushort_t* xdb_bf = wbf + 9633792;     // 8192 x 64        =   524,288

  cvt_bf16<<<2048, 256, 0, stream>>>(m_in_w,  wIN,  524288);
  cvt_bf16<<<1024, 256, 0, stream>>>(m_out_w, wOUT, 262144);
  cvt_bf16<<<1536, 256, 0, stream>>>(t_qkv_w, wQKV, 393216);
  cvt_bf16<<< 512, 256, 0, stream>>>(t_ow,    wOW,  131072);
  cvt_bf16<<<2048, 256, 0, stream>>>(t_l1w,   wL1,  524288);
  cvt_bf16<<<2048, 256, 0, stream>>>(t_l2w,   wL2,  524288);
  cvt_bf16<<< 128, 256, 0, stream>>>(m_xproj_w, wXP, 32768);
  cvt_bf16<<<  64, 256, 0, stream>>>(m_dt_w,  wDT,  16384);

  proj_kernel<<<16384, 256, 0, stream>>>(x, proj_w, proj_b, h, h_bf);

  for (int i = 0; i < 2; ++i) {
    // xz = h @ in_w^T   (8192 x 2048, K=512) -> bf16
    gemm_gll<0, 1, 1, 128><<<dim3(16, 64), 256, 0, stream>>>(
        h_bf, wIN + (size_t)i * 1048576, nullptr, bufA, DMODEL, DMODEL, 2 * DINNER);
    // xc = silu(causal_conv(xm)) -> bf16
    conv_silu_kernel<<<32768, 256, 0, stream>>>((const ushort_t*)bufA,
                                                m_conv_w + i * DINNER * 4,
                                                m_conv_b + i * DINNER, (ushort_t*)bufB);
    // xdb = xc @ xp_w^T  (8192 x 64, K=1024), MFMA split-K=8 -> partials bufC
    gemm_gll<0, 0, 8, 64><<<dim3(1, 64, 8), 256, 0, stream>>>(
        (const ushort_t*)bufB, wXP + (size_t)i * 65536, nullptr, bufC,
        DINNER, DINNER, 64);
    reduce8_xdb<<<512, 256, 0, stream>>>(bufC, bufF, xdb_bf);
    // dt = softplus(xdb[:, :32] @ dt_w^T + dt_b), MFMA K=32 -> bufC fp32
    gemm_gll<2, 0, 1, 128><<<dim3(8, 64), 256, 0, stream>>>(
        xdb_bf, wDT + (size_t)i * 32768, m_dt_b + i * DINNER, bufC,
        DTRANK, 64, DINNER);
    // chunked selective scan (state-split x4) -> y_bf (bf16)
    scan_pass1<<<2048, 256, 0, stream>>>(bufC, bufF, (const ushort_t*)bufB,
                                         m_Alog + (size_t)i * DINNER * DSTATE, scrP, scrL);
    scan_pass2<<<512, 256, 0, stream>>>(scrP, scrL);
    scan_pass3<<<2048, 256, 0, stream>>>(bufC, bufF, (const ushort_t*)bufB,
                                         (const ushort_t*)bufA, y_bf,
                                         m_Alog + (size_t)i * DINNER * DSTATE,
                                         m_D + i * DINNER, scrL);
    // mamba_out = y @ out_w^T  (8192 x 512, K=1024), split-K=2 -> partials bufC
    gemm_gll<0, 0, 2, 128><<<dim3(4, 64, 2), 256, 0, stream>>>(
        y_bf, wOUT + (size_t)i * 524288, nullptr, bufC, DINNER, DINNER, DMODEL);
    // h = LN(h + p0 + p1), refresh h_bf (fused reduce)
    resid_ln_sk<<<8192, 128, 0, stream>>>(h, bufC, nullptr, m_ln_w + i * DMODEL,
                                          m_ln_b + i * DMODEL, h, h_bf);
  }

  posenc_kernel<<<16384, 256, 0, stream>>>(h, h_bf);

  for (int i = 0; i < 2; ++i) {
    // qkv = h @ qkv_w^T + qkv_b  (8192 x 1536, K=512) -> bf16
    gemm_gll<0, 1, 1, 128><<<dim3(12, 64), 256, 0, stream>>>(
        h_bf, wQKV + (size_t)i * 786432, t_qkv_b + i * 3 * DMODEL, bufA,
        DMODEL, DMODEL, 3 * DMODEL);
    // MFMA flash attention (128-q-row blocks) -> ao bf16
    attn_mfma<<<512, 256, 0, stream>>>((const ushort_t*)bufA, (ushort_t*)bufB);
    // attn_proj = ao @ ow^T  (8192 x 512, K=512), split-K=2 -> partials bufC
    gemm_gll<0, 0, 2, 128><<<dim3(4, 64, 2), 256, 0, stream>>>(
        (const ushort_t*)bufB, wOW + (size_t)i * 262144, nullptr, bufC,
        DMODEL, DMODEL, DMODEL);
    resid_ln_sk<<<8192, 128, 0, stream>>>(h, bufC, t_ob + i * DMODEL,
                                          t_ln1w + i * DMODEL, t_ln1b + i * DMODEL, h, h_bf);
    // ff1 = relu(h @ l1w^T + l1b)  (8192 x 2048, K=512) -> bf16
    gemm_gll<1, 1, 1, 128><<<dim3(16, 64), 256, 0, stream>>>(
        h_bf, wL1 + (size_t)i * 1048576, t_l1b + i * DFF, bufA,
        DMODEL, DMODEL, DFF);
    // ff2 = ff1 @ l2w^T  (8192 x 512, K=2048), split-K=2 -> partials bufC
    gemm_gll<0, 0, 2, 128><<<dim3(4, 64, 2), 256, 0, stream>>>(
        (const ushort_t*)bufA, wL2 + (size_t)i * 1048576, nullptr, bufC,
        DFF, DFF, DMODEL);
    resid_ln_sk<<<8192, 128, 0, stream>>>(h, bufC, t_l2b + i * DMODEL,
                                          t_ln2w + i * DMODEL, t_ln2b + i * DMODEL, h, h_bf);
  }

  // final LN -> d_out, then mean over L -> d_out tail
  float* out_h = (float*)d_out;
  resid_ln_kernel<<<8192, 128, 0, stream>>>(h, nullptr, no_w, no_b, out_h, nullptr);
  mean_part<<<128, 512, 0, stream>>>(out_h, bufF);
  mean_final<<<16, 256, 0, stream>>>(bufF, out_h + 4194304);
}

// Round 10
// 925.168 us; speedup vs baseline: 1.5695x; 1.0417x over previous
//
#include <hip/hip_runtime.h>
#include <cstddef>

// Problem constants
#define BATCH 8
#define LSEQ 1024
#define DMODEL 512
#define DINNER 1024
#define DSTATE 16
#define DTRANK 32
#define NHEAD 8
#define DHEAD 64
#define DFF 2048
#define MTOK 8192   // BATCH*LSEQ
#define NCHUNK 16
#define CLEN 64     // LSEQ / NCHUNK

typedef __attribute__((ext_vector_type(8))) short bfrag;          // 8 bf16 = 16 B
typedef __attribute__((ext_vector_type(4))) float f32x4;          // MFMA acc
typedef __attribute__((ext_vector_type(4))) unsigned short us4;
typedef unsigned short ushort_t;

__device__ __forceinline__ float silu_f(float x) { return x / (1.f + __expf(-x)); }

__device__ __forceinline__ unsigned short f2bf(float f) {  // RNE fp32->bf16
  unsigned u = __float_as_uint(f);
  return (unsigned short)((u + 0x7FFFu + ((u >> 16) & 1u)) >> 16);
}
__device__ __forceinline__ float bf2f(ushort_t u) {
  return __uint_as_float((unsigned)u << 16);
}

// async global->LDS, 16B per lane. LDS dest = wave-uniform base + lane*16.
__device__ __forceinline__ void gll16(const ushort_t* g, ushort_t* l) {
  __builtin_amdgcn_global_load_lds(
      (const __attribute__((address_space(1))) unsigned int*)g,
      (__attribute__((address_space(3))) unsigned int*)l, 16, 0, 0);
}

// ---------------------------------------------------------------------------
// 8-segment fp32 -> bf16 weight convert (single launch). Segment sizes are
// multiples of 256 float4s, so blocks tile segments exactly.
// ---------------------------------------------------------------------------
struct Cvt8Args {
  const float* s[8];
  ushort_t* d[8];
  int end[8];   // prefix-sum of blocks
};
__global__ __launch_bounds__(256) void cvt8(Cvt8Args a) {
  int blk = blockIdx.x;
  int seg = 0, start = 0;
#pragma unroll
  for (int i = 0; i < 7; ++i)
    if (blk >= a.end[i]) { seg = i + 1; start = a.end[i]; }
  int i4 = (blk - start) * 256 + threadIdx.x;
  float4 v = ((const float4*)a.s[seg])[i4];
  us4 o = {f2bf(v.x), f2bf(v.y), f2bf(v.z), f2bf(v.w)};
  ((us4*)a.d[seg])[i4] = o;
}

// ---------------------------------------------------------------------------
// Input projection: h[b,l,d] = sum_c x[b,c,l] * pw[d,c] + pb[d]; also bf16 copy.
// ---------------------------------------------------------------------------
__global__ __launch_bounds__(256) void proj_kernel(const float* __restrict__ x,
                                                   const float* __restrict__ pw,
                                                   const float* __restrict__ pb,
                                                   float* __restrict__ h,
                                                   ushort_t* __restrict__ hbf) {
  int idx = blockIdx.x * 256 + threadIdx.x;        // ((b*L)+l)*512 + d
  int d = idx & 511;
  int l = (idx >> 9) & 1023;
  int b = idx >> 19;
  const float* xb = x + (size_t)b * 3 * 1024 + l;
  float v = pb[d] + xb[0] * pw[d * 3] + xb[1024] * pw[d * 3 + 1] + xb[2048] * pw[d * 3 + 2];
  h[idx] = v;
  hbf[idx] = f2bf(v);
}

// ---------------------------------------------------------------------------
// bf16 MFMA GEMM, global_load_lds + double-buffered prefetch.
// C[m,n] = act( sum_k A[m,k]*W[n,k] + bias[n] ).  Tile 128 x BN, BK=32.
// BN=128: 4 waves 2x2 (64x64). BN=64: 4 waves 4x1 (32x64), 3 glls/stage.
// ACT: 0 none, 1 relu, 2 softplus. CBF: 1 bf16 C, 0 fp32 C.
// SPLITK: 1 direct; >1 -> fp32 partials at Cp + z*8192*ldc (no bias/act).
// ---------------------------------------------------------------------------
template <int ACT, int CBF, int SPLITK, int BN>
__global__ __launch_bounds__(256) void gemm_gll(const ushort_t* __restrict__ A,
                                                const ushort_t* __restrict__ W,
                                                const float* __restrict__ bias,
                                                void* __restrict__ Cp,
                                                int K, int lda, int ldc) {
  __shared__ ushort_t sA[2][4096];
  __shared__ ushort_t sB[2][BN * 32];
  constexpr int MREP = (BN == 128) ? 4 : 2;
  const int bm = blockIdx.y * 128, bn = blockIdx.x * BN;
  const int tid = threadIdx.x;
  const int wid = tid >> 6, lane = tid & 63;
  const int wrb = (BN == 128) ? (wid >> 1) * 64 : wid * 32;
  const int wcb = (BN == 128) ? (wid & 1) * 64 : 0;
  const int lr = lane & 15, ls = lane >> 4;
  const int sw = ls ^ ((lr >> 1) & 3);

  const int kseg = K / SPLITK;
  const int kbeg = (SPLITK > 1) ? blockIdx.z * kseg : 0;

  const int c0 = wid * 128 + lane;
  const int c1 = c0 + 64;
  const int r0 = c0 >> 2, s0 = (c0 & 3) ^ ((r0 >> 1) & 3);
  const int r1 = c1 >> 2, s1 = (c1 & 3) ^ ((r1 >> 1) & 3);
  const ushort_t* gA0 = A + (size_t)(bm + r0) * lda + kbeg + s0 * 8;
  const ushort_t* gA1 = A + (size_t)(bm + r1) * lda + kbeg + s1 * 8;
  const ushort_t* gB0;
  const ushort_t* gB1 = nullptr;
  if constexpr (BN == 128) {
    gB0 = W + (size_t)(bn + r0) * K + kbeg + s0 * 8;
    gB1 = W + (size_t)(bn + r1) * K + kbeg + s1 * 8;
  } else {
    const int cb = wid * 64 + lane;
    const int rb = cb >> 2, sb2 = (cb & 3) ^ ((rb >> 1) & 3);
    gB0 = W + (size_t)(bn + rb) * K + kbeg + sb2 * 8;
  }

  f32x4 acc[MREP][4];
#pragma unroll
  for (int i = 0; i < MREP; ++i)
#pragma unroll
    for (int j = 0; j < 4; ++j) acc[i][j] = (f32x4)(0.f);

#define STAGE(buf, step)                                             \
  do {                                                               \
    gll16(gA0 + (step) * 32, &sA[buf][wid * 1024]);                  \
    gll16(gA1 + (step) * 32, &sA[buf][wid * 1024 + 512]);            \
    if constexpr (BN == 128) {                                       \
      gll16(gB0 + (step) * 32, &sB[buf][wid * 1024]);                \
      gll16(gB1 + (step) * 32, &sB[buf][wid * 1024 + 512]);          \
    } else {                                                         \
      gll16(gB0 + (step) * 32, &sB[buf][wid * 512]);                 \
    }                                                                \
  } while (0)

  const int NT = kseg / 32;
  STAGE(0, 0);
  for (int t = 0; t < NT; ++t) {
    const int cur = t & 1;
    if (t + 1 < NT) {
      STAGE(cur ^ 1, t + 1);
      if constexpr (BN == 128)
        asm volatile("s_waitcnt vmcnt(4)" ::: "memory");
      else
        asm volatile("s_waitcnt vmcnt(3)" ::: "memory");
    } else {
      asm volatile("s_waitcnt vmcnt(0)" ::: "memory");
    }
    __builtin_amdgcn_sched_barrier(0);
    __builtin_amdgcn_s_barrier();
    __builtin_amdgcn_sched_barrier(0);

    bfrag af[MREP], bf[4];
#pragma unroll
    for (int mi = 0; mi < MREP; ++mi) {
      int row = wrb + mi * 16 + lr;
      af[mi] = *(const bfrag*)&sA[cur][(size_t)((row << 2) + sw) * 8];
    }
#pragma unroll
    for (int nj = 0; nj < 4; ++nj) {
      int col = wcb + nj * 16 + lr;
      bf[nj] = *(const bfrag*)&sB[cur][(size_t)((col << 2) + sw) * 8];
    }
#pragma unroll
    for (int mi = 0; mi < MREP; ++mi)
#pragma unroll
      for (int nj = 0; nj < 4; ++nj)
        acc[mi][nj] = __builtin_amdgcn_mfma_f32_16x16x32_bf16(af[mi], bf[nj], acc[mi][nj], 0, 0, 0);

    __builtin_amdgcn_s_barrier();
    __builtin_amdgcn_sched_barrier(0);
  }
#undef STAGE

  if (SPLITK > 1) {
    float* Cz = (float*)Cp + (size_t)blockIdx.z * 8192 * ldc;
#pragma unroll
    for (int nj = 0; nj < 4; ++nj) {
      int col = bn + wcb + nj * 16 + lr;
#pragma unroll
      for (int mi = 0; mi < MREP; ++mi) {
        int row0 = bm + wrb + mi * 16 + ls * 4;
#pragma unroll
        for (int r = 0; r < 4; ++r)
          Cz[(size_t)(row0 + r) * ldc + col] = acc[mi][nj][r];
      }
    }
  } else {
#pragma unroll
    for (int nj = 0; nj < 4; ++nj) {
      int col = bn + wcb + nj * 16 + lr;
      float bv = bias ? bias[col] : 0.f;
#pragma unroll
      for (int mi = 0; mi < MREP; ++mi) {
        int row0 = bm + wrb + mi * 16 + ls * 4;
#pragma unroll
        for (int r = 0; r < 4; ++r) {
          float v = acc[mi][nj][r] + bv;
          if (ACT == 1) v = fmaxf(v, 0.f);
          if (ACT == 2) v = (v > 20.f) ? v : log1pf(__expf(v));
          if (CBF)
            ((ushort_t*)Cp)[(size_t)(row0 + r) * ldc + col] = f2bf(v);
          else
            ((float*)Cp)[(size_t)(row0 + r) * ldc + col] = v;
        }
      }
    }
  }
}

// ---------------------------------------------------------------------------
// split-K=8 reduce for xproj: xdb fp32 + bf16 copy. 131072 float4 groups.
// ---------------------------------------------------------------------------
__global__ __launch_bounds__(256) void reduce8_xdb(const float* __restrict__ p,
                                                   float* __restrict__ xdb,
                                                   ushort_t* __restrict__ xdb_bf) {
  int i = blockIdx.x * 256 + threadIdx.x;
  float4 a = ((const float4*)p)[i];
#pragma unroll
  for (int z = 1; z < 8; ++z) {
    float4 b = ((const float4*)p)[i + z * 131072];
    a.x += b.x; a.y += b.y; a.z += b.z; a.w += b.w;
  }
  ((float4*)xdb)[i] = a;
  us4 o = {f2bf(a.x), f2bf(a.y), f2bf(a.z), f2bf(a.w)};
  ((us4*)xdb_bf)[i] = o;
}

// ---------------------------------------------------------------------------
// Depthwise causal conv (width 4) + SiLU. xz is bf16 (row stride 2048) -> bf16 xc.
// ---------------------------------------------------------------------------
__global__ __launch_bounds__(256) void conv_silu_kernel(const ushort_t* __restrict__ xz,
                                                        const float* __restrict__ cw,
                                                        const float* __restrict__ cb,
                                                        ushort_t* __restrict__ xc) {
  int idx = blockIdx.x * 256 + threadIdx.x;        // ((b*L)+t)*1024 + d
  int d = idx & 1023;
  int t = (idx >> 10) & 1023;
  int b = idx >> 20;
  float acc = cb[d];
#pragma unroll
  for (int w = 0; w < 4; ++w) {
    int tt = t - 3 + w;
    if (tt >= 0) acc += bf2f(xz[(((size_t)(b * 1024 + tt)) << 11) + d]) * cw[d * 4 + w];
  }
  xc[idx] = f2bf(silu_f(acc));
}

// ---------------------------------------------------------------------------
// Chunked selective scan, STATE-SPLIT x4. xc, dt bf16.
// ---------------------------------------------------------------------------
__global__ __launch_bounds__(256) void scan_pass1(const ushort_t* __restrict__ dt,
                                                  const float* __restrict__ xdb,
                                                  const ushort_t* __restrict__ xc,
                                                  const float* __restrict__ Alog,
                                                  float* __restrict__ scrP,
                                                  float* __restrict__ scrL) {
  int idx = blockIdx.x * 256 + threadIdx.x;
  int sh = idx & 3;
  int d = (idx >> 2) & 1023;
  int c = (idx >> 12) & 15;
  int b = idx >> 16;
  float A[4], st[4], P[4];
#pragma unroll
  for (int s = 0; s < 4; ++s) {
    A[s] = -__expf(Alog[d * 16 + sh * 4 + s]);
    st[s] = 0.f;
    P[s] = 1.f;
  }
  int t0 = c * CLEN;
  size_t base = (((size_t)(b * 1024 + t0)) << 10) + d;
  const float* xb = xdb + (size_t)(b * 1024 + t0) * 64 + 32 + sh * 4;
  float dtv = bf2f(dt[base]), xv = bf2f(xc[base]);
  for (int t = 0; t < CLEN; ++t) {
    float dtn = 0.f, xvn = 0.f;
    if (t + 1 < CLEN) { dtn = bf2f(dt[base + 1024]); xvn = bf2f(xc[base + 1024]); }
    float4 Bv = *(const float4*)xb;
    float dx = dtv * xv;
    float e0 = __expf(dtv * A[0]), e1 = __expf(dtv * A[1]);
    float e2 = __expf(dtv * A[2]), e3 = __expf(dtv * A[3]);
    st[0] = st[0] * e0 + dx * Bv.x; P[0] *= e0;
    st[1] = st[1] * e1 + dx * Bv.y; P[1] *= e1;
    st[2] = st[2] * e2 + dx * Bv.z; P[2] *= e2;
    st[3] = st[3] * e3 + dx * Bv.w; P[3] *= e3;
    base += 1024; xb += 64;
    dtv = dtn; xv = xvn;
  }
  size_t pbase = (((size_t)((b * 16 + c) * 16 + sh * 4)) << 10) + d;
#pragma unroll
  for (int s = 0; s < 4; ++s) {
    scrP[pbase + ((size_t)s << 10)] = P[s];
    scrL[pbase + ((size_t)s << 10)] = st[s];
  }
}

// ---------------------------------------------------------------------------
// Pass 2: combine chunks serially per (b,d,s).
// ---------------------------------------------------------------------------
__global__ __launch_bounds__(256) void scan_pass2(const float* __restrict__ scrP,
                                                  float* __restrict__ scrL) {
  int idx = blockIdx.x * 256 + threadIdx.x;        // ((b*16 + s)*1024 + d)
  int d = idx & 1023;
  int s = (idx >> 10) & 15;
  int b = idx >> 14;
  float cur = 0.f;
  for (int c = 0; c < 16; ++c) {
    size_t o = (((size_t)(((b * 16 + c) * 16) + s)) << 10) + d;
    float P = scrP[o];
    float loc = scrL[o];
    scrL[o] = cur;
    cur = cur * P + loc;
  }
}

// ---------------------------------------------------------------------------
// Pass 3: state-split x4 rescan; quad-reduce via shfl_xor; bf16 y out.
// ---------------------------------------------------------------------------
__global__ __launch_bounds__(256) void scan_pass3(const ushort_t* __restrict__ dt,
                                                  const float* __restrict__ xdb,
                                                  const ushort_t* __restrict__ xc,
                                                  const ushort_t* __restrict__ xz,
                                                  ushort_t* __restrict__ ybf,
                                                  const float* __restrict__ Alog,
                                                  const float* __restrict__ Dp,
                                                  const float* __restrict__ scrL) {
  int idx = blockIdx.x * 256 + threadIdx.x;
  int sh = idx & 3;
  int d = (idx >> 2) & 1023;
  int c = (idx >> 12) & 15;
  int b = idx >> 16;
  float A[4], st[4];
  size_t pbase = (((size_t)((b * 16 + c) * 16 + sh * 4)) << 10) + d;
#pragma unroll
  for (int s = 0; s < 4; ++s) {
    A[s] = -__expf(Alog[d * 16 + sh * 4 + s]);
    st[s] = scrL[pbase + ((size_t)s << 10)];
  }
  float Dv = Dp[d];
  int t0 = c * CLEN;
  size_t base = (((size_t)(b * 1024 + t0)) << 10) + d;
  size_t zoff = ((((size_t)(b * 1024 + t0)) << 11)) + 1024 + d;
  const float* xb = xdb + (size_t)(b * 1024 + t0) * 64 + 32 + sh * 4;
  float dtv = bf2f(dt[base]), xv = bf2f(xc[base]), zv = bf2f(xz[zoff]);
  for (int t = 0; t < CLEN; ++t) {
    float dtn = 0.f, xvn = 0.f, zvn = 0.f;
    if (t + 1 < CLEN) {
      dtn = bf2f(dt[base + 1024]); xvn = bf2f(xc[base + 1024]); zvn = bf2f(xz[zoff + 2048]);
    }
    float4 Bv = *(const float4*)xb;
    float4 Cv = *(const float4*)(xb + 16);
    float dx = dtv * xv;
    float e0 = __expf(dtv * A[0]), e1 = __expf(dtv * A[1]);
    float e2 = __expf(dtv * A[2]), e3 = __expf(dtv * A[3]);
    st[0] = st[0] * e0 + dx * Bv.x;
    st[1] = st[1] * e1 + dx * Bv.y;
    st[2] = st[2] * e2 + dx * Bv.z;
    st[3] = st[3] * e3 + dx * Bv.w;
    float acc = st[0] * Cv.x + st[1] * Cv.y + st[2] * Cv.z + st[3] * Cv.w;
    acc += __shfl_xor(acc, 1);
    acc += __shfl_xor(acc, 2);
    if (sh == 0)
      ybf[base] = f2bf((acc + Dv * xv) * silu_f(zv));
    base += 1024; zoff += 2048; xb += 64;
    dtv = dtn; xv = xvn; zv = zvn;
  }
}

// ---------------------------------------------------------------------------
// Residual + LayerNorm. add / out_bf may be nullptr.
// ---------------------------------------------------------------------------
__global__ __launch_bounds__(128) void resid_ln_kernel(const float* __restrict__ x,
                                                       const float* __restrict__ add,
                                                       const float* __restrict__ w,
                                                       const float* __restrict__ bias,
                                                       float* __restrict__ out,
                                                       ushort_t* __restrict__ out_bf) {
  int row = blockIdx.x, tid = threadIdx.x;
  float4 v = ((const float4*)(x + (size_t)row * 512))[tid];
  if (add) {
    float4 a = ((const float4*)(add + (size_t)row * 512))[tid];
    v.x += a.x; v.y += a.y; v.z += a.z; v.w += a.w;
  }
  float s = v.x + v.y + v.z + v.w;
  float ss = v.x * v.x + v.y * v.y + v.z * v.z + v.w * v.w;
#pragma unroll
  for (int o = 32; o; o >>= 1) {
    s += __shfl_xor(s, o);
    ss += __shfl_xor(ss, o);
  }
  __shared__ float red[4];
  int wid = tid >> 6;
  if ((tid & 63) == 0) { red[wid] = s; red[2 + wid] = ss; }
  __syncthreads();
  s = red[0] + red[1];
  ss = red[2] + red[3];
  float mean = s * (1.f / 512.f);
  float var = ss * (1.f / 512.f) - mean * mean;
  float inv = rsqrtf(var + 1e-5f);
  float4 wv = ((const float4*)w)[tid];
  float4 bv = ((const float4*)bias)[tid];
  float4 ov;
  ov.x = (v.x - mean) * inv * wv.x + bv.x;
  ov.y = (v.y - mean) * inv * wv.y + bv.y;
  ov.z = (v.z - mean) * inv * wv.z + bv.z;
  ov.w = (v.w - mean) * inv * wv.w + bv.w;
  ((float4*)(out + (size_t)row * 512))[tid] = ov;
  if (out_bf) {
    us4 ob = {f2bf(ov.x), f2bf(ov.y), f2bf(ov.z), f2bf(ov.w)};
    ((us4*)(out_bf + (size_t)row * 512))[tid] = ob;
  }
}

// ---------------------------------------------------------------------------
// Residual + split-K2 sum + optional gemm-bias + LayerNorm, fused.
// ---------------------------------------------------------------------------
__global__ __launch_bounds__(128) void resid_ln_sk(const float* __restrict__ x,
                                                   const float* __restrict__ p,
                                                   const float* __restrict__ pbias,
                                                   const float* __restrict__ w,
                                                   const float* __restrict__ bias,
                                                   float* __restrict__ out,
                                                   ushort_t* __restrict__ out_bf) {
  int row = blockIdx.x, tid = threadIdx.x;
  float4 v = ((const float4*)(x + (size_t)row * 512))[tid];
  float4 a = ((const float4*)(p + (size_t)row * 512))[tid];
  float4 c = ((const float4*)(p + 4194304 + (size_t)row * 512))[tid];
  v.x += a.x + c.x; v.y += a.y + c.y; v.z += a.z + c.z; v.w += a.w + c.w;
  if (pbias) {
    float4 pb = ((const float4*)pbias)[tid];
    v.x += pb.x; v.y += pb.y; v.z += pb.z; v.w += pb.w;
  }
  float s = v.x + v.y + v.z + v.w;
  float ss = v.x * v.x + v.y * v.y + v.z * v.z + v.w * v.w;
#pragma unroll
  for (int o = 32; o; o >>= 1) {
    s += __shfl_xor(s, o);
    ss += __shfl_xor(ss, o);
  }
  __shared__ float red[4];
  int wid = tid >> 6;
  if ((tid & 63) == 0) { red[wid] = s; red[2 + wid] = ss; }
  __syncthreads();
  s = red[0] + red[1];
  ss = red[2] + red[3];
  float mean = s * (1.f / 512.f);
  float var = ss * (1.f / 512.f) - mean * mean;
  float inv = rsqrtf(var + 1e-5f);
  float4 wv = ((const float4*)w)[tid];
  float4 bv = ((const float4*)bias)[tid];
  float4 ov;
  ov.x = (v.x - mean) * inv * wv.x + bv.x;
  ov.y = (v.y - mean) * inv * wv.y + bv.y;
  ov.z = (v.z - mean) * inv * wv.z + bv.z;
  ov.w = (v.w - mean) * inv * wv.w + bv.w;
  ((float4*)(out + (size_t)row * 512))[tid] = ov;
  us4 ob = {f2bf(ov.x), f2bf(ov.y), f2bf(ov.z), f2bf(ov.w)};
  ((us4*)(out_bf + (size_t)row * 512))[tid] = ob;
}

// ---------------------------------------------------------------------------
// Sinusoidal positional encoding add (in-place on h, refresh hbf)
// ---------------------------------------------------------------------------
__global__ __launch_bounds__(256) void posenc_kernel(float* __restrict__ h,
                                                     ushort_t* __restrict__ hbf) {
  int idx = blockIdx.x * 256 + threadIdx.x;
  int d = idx & 511;
  int l = (idx >> 9) & 1023;
  float freq = __expf(-(float)(d & ~1) * (9.210340371976184f / 512.f));
  float ang = (float)l * freq;
  float v = h[idx] + ((d & 1) ? cosf(ang) : sinf(ang));
  h[idx] = v;
  hbf[idx] = f2bf(v);
}

// ---------------------------------------------------------------------------
// MFMA flash attention v3: QBLK=64 (grid 1024), XCD-aware block decode so all
// 16 q-tiles of a (b,h) run on the same XCD (K/V L2-resident per XCD), and
// Vt swizzle includes ^((dd>>3)&7) to kill the 4-way transpose-write conflict.
// ---------------------------------------------------------------------------
__global__ __launch_bounds__(256) void attn_mfma(const ushort_t* __restrict__ qkv,
                                                 ushort_t* __restrict__ ao) {
  __shared__ unsigned short Qs[4096];
  __shared__ unsigned short Ks[4096];
  __shared__ unsigned short Vt[4096];
  __shared__ unsigned short Ps[4096];
  const int tid = threadIdx.x;
  // block w runs on XCD w%8 (round-robin); give it head-group bh ≡ w (mod 8)
  const int w = blockIdx.x;                      // 1024 blocks
  const int bh = (w & 7) + (w >> 7) * 8;         // b*8 + h
  const int qt = (w >> 3) & 15;
  const int hh = bh & 7, b = bh >> 3;
  const int l0 = qt * 64;
  const size_t bb = (size_t)b * 1024 * 1536;

  const int srow = tid >> 2;                     // staging row 0..63
  const int sdb = (tid & 3) << 4;                // staging d-block 0/16/32/48
  const int sc0 = sdb >> 3;

  {
    const ushort_t* qp = qkv + bb + (size_t)(l0 + srow) * 1536 + hh * 64 + sdb;
    *(bfrag*)&Qs[srow * 64 + ((sc0 ^ (srow & 7)) << 3)] = *(const bfrag*)qp;
    *(bfrag*)&Qs[srow * 64 + (((sc0 + 1) ^ (srow & 7)) << 3)] = *(const bfrag*)(qp + 8);
  }

  const int wid = tid >> 6, lane = tid & 63;
  const int l15 = lane & 15, rg = lane >> 4;
  const int l7 = l15 & 7;
  float m[4], lsum[4];
  f32x4 oacc[4];
#pragma unroll
  for (int r = 0; r < 4; ++r) { m[r] = -1e30f; lsum[r] = 0.f; }
#pragma unroll
  for (int nt = 0; nt < 4; ++nt) oacc[nt] = (f32x4)(0.f);

  for (int jt = 0; jt < 16; ++jt) {
    {
      const ushort_t* kp = qkv + bb + (size_t)(jt * 64 + srow) * 1536 + hh * 64 + 512 + sdb;
      *(bfrag*)&Ks[srow * 64 + ((sc0 ^ (srow & 7)) << 3)] = *(const bfrag*)kp;
      *(bfrag*)&Ks[srow * 64 + (((sc0 + 1) ^ (srow & 7)) << 3)] = *(const bfrag*)(kp + 8);
      const ushort_t* vp = kp + 512;
      unsigned short vv[16];
      *(bfrag*)&vv[0] = *(const bfrag*)vp;
      *(bfrag*)&vv[8] = *(const bfrag*)(vp + 8);
#pragma unroll
      for (int j = 0; j < 16; ++j) {
        int dd = sdb + j;
        Vt[dd * 64 + (((srow >> 3) ^ (dd & 7) ^ ((dd >> 3) & 7)) << 3) + (srow & 7)] = vv[j];
      }
    }
    __syncthreads();

    bfrag aq[2];
#pragma unroll
    for (int ks = 0; ks < 2; ++ks)
      aq[ks] = *(const bfrag*)&Qs[(wid * 16 + l15) * 64 + (((ks * 4 + rg) ^ l7) << 3)];
    f32x4 sc[4];
#pragma unroll
    for (int nt = 0; nt < 4; ++nt) {
      f32x4 s = (f32x4)(0.f);
#pragma unroll
      for (int ks = 0; ks < 2; ++ks) {
        bfrag bk = *(const bfrag*)&Ks[(nt * 16 + l15) * 64 + (((ks * 4 + rg) ^ l7) << 3)];
        s = __builtin_amdgcn_mfma_f32_16x16x32_bf16(aq[ks], bk, s, 0, 0, 0);
      }
      sc[nt] = s * 0.125f;
    }

#pragma unroll
    for (int r = 0; r < 4; ++r) {
      float mc = fmaxf(fmaxf(sc[0][r], sc[1][r]), fmaxf(sc[2][r], sc[3][r]));
#pragma unroll
      for (int o = 8; o; o >>= 1) mc = fmaxf(mc, __shfl_xor(mc, o));
      float mn = fmaxf(m[r], mc);
      float al = __expf(m[r] - mn);
      m[r] = mn;
      int prow = rg * 4 + r;
      float ps = 0.f;
#pragma unroll
      for (int nt = 0; nt < 4; ++nt) {
        float p = __expf(sc[nt][r] - mn);
        ps += p;
        int col = nt * 16 + l15;
        Ps[wid * 1024 + prow * 64 + ((((col >> 3) ^ (prow & 7))) << 3) + (col & 7)] = f2bf(p);
      }
#pragma unroll
      for (int o = 8; o; o >>= 1) ps += __shfl_xor(ps, o);
      lsum[r] = lsum[r] * al + ps;
#pragma unroll
      for (int nt = 0; nt < 4; ++nt) oacc[nt][r] *= al;
    }

    bfrag ap[2];
#pragma unroll
    for (int ks = 0; ks < 2; ++ks)
      ap[ks] = *(const bfrag*)&Ps[wid * 1024 + l15 * 64 + (((ks * 4 + rg) ^ l7) << 3)];
#pragma unroll
    for (int nt = 0; nt < 4; ++nt) {
      int vrow = nt * 16 + l15;
#pragma unroll
      for (int ks = 0; ks < 2; ++ks) {
        bfrag bv = *(const bfrag*)&Vt[vrow * 64 +
            (((ks * 4 + rg) ^ (vrow & 7) ^ ((vrow >> 3) & 7)) << 3)];
        oacc[nt] = __builtin_amdgcn_mfma_f32_16x16x32_bf16(ap[ks], bv, oacc[nt], 0, 0, 0);
      }
    }
    __syncthreads();
  }

#pragma unroll
  for (int r = 0; r < 4; ++r) {
    float inv = 1.f / lsum[r];
    int row = l0 + wid * 16 + rg * 4 + r;
    ushort_t* op = ao + ((size_t)(b * 1024 + row)) * 512 + hh * 64;
#pragma unroll
    for (int nt = 0; nt < 4; ++nt) op[nt * 16 + l15] = f2bf(oacc[nt][r] * inv);
  }
}

// ---------------------------------------------------------------------------
// Mean over L, two-pass.
// ---------------------------------------------------------------------------
__global__ __launch_bounds__(512) void mean_part(const float* __restrict__ h,
                                                 float* __restrict__ part) {
  int blk = blockIdx.x;                       // b*16 + lc
  int b = blk >> 4, lc = blk & 15, d = threadIdx.x;
  float s = 0.f;
  int l0 = lc * 64;
  for (int l = l0; l < l0 + 64; ++l) s += h[(((size_t)(b * 1024 + l)) << 9) + d];
  part[((size_t)blk << 9) + d] = s;
}
__global__ __launch_bounds__(256) void mean_final(const float* __restrict__ part,
                                                  float* __restrict__ out2) {
  int i = blockIdx.x * 256 + threadIdx.x;     // b*512 + d
  int b = i >> 9, d = i & 511;
  float s = 0.f;
#pragma unroll
  for (int c = 0; c < 16; ++c) s += part[(((size_t)(b * 16 + c)) << 9) + d];
  out2[i] = s * (1.f / 1024.f);
}

// ---------------------------------------------------------------------------
extern "C" void kernel_launch(void* const* d_in, const int* in_sizes, int n_in,
                              void* d_out, int out_size, void* d_ws, size_t ws_size,
                              hipStream_t stream) {
  const float* x        = (const float*)d_in[0];
  const float* proj_w   = (const float*)d_in[1];
  const float* proj_b   = (const float*)d_in[2];
  const float* m_in_w   = (const float*)d_in[3];
  const float* m_conv_w = (const float*)d_in[4];
  const float* m_conv_b = (const float*)d_in[5];
  const float* m_xproj_w= (const float*)d_in[6];
  const float* m_dt_w   = (const float*)d_in[7];
  const float* m_dt_b   = (const float*)d_in[8];
  const float* m_Alog   = (const float*)d_in[9];
  const float* m_D      = (const float*)d_in[10];
  const float* m_out_w  = (const float*)d_in[11];
  const float* m_ln_w   = (const float*)d_in[12];
  const float* m_ln_b   = (const float*)d_in[13];
  const float* t_qkv_w  = (const float*)d_in[14];
  const float* t_qkv_b  = (const float*)d_in[15];
  const float* t_ow     = (const float*)d_in[16];
  const float* t_ob     = (const float*)d_in[17];
  const float* t_l1w    = (const float*)d_in[18];
  const float* t_l1b    = (const float*)d_in[19];
  const float* t_l2w    = (const float*)d_in[20];
  const float* t_l2b    = (const float*)d_in[21];
  const float* t_ln1w   = (const float*)d_in[22];
  const float* t_ln1b   = (const float*)d_in[23];
  const float* t_ln2w   = (const float*)d_in[24];
  const float* t_ln2b   = (const float*)d_in[25];
  const float* no_w     = (const float*)d_in[26];
  const float* no_b     = (const float*)d_in[27];

  float* ws   = (float*)d_ws;
  float* h    = ws;                                   //  4M f
  ushort_t* h_bf = (ushort_t*)(ws + 4194304);         //  4M us (2M f)
  float* bufA = ws + 6291456;                         // 16M f (xz_bf / qkv_bf / ff1_bf)
  float* bufB = bufA + 16777216;                      //  8M f (xc_bf / ao_bf)
  float* bufC = bufB + 8388608;                       //  8M f (xproj partials / dt_bf / split-K partials)
  float* bufE = bufC + 8388608;                       //  4M f (scan scratch)
  float* bufF = bufE + 4194304;                       //  0.5M f (xdb f32 / mean partials)
  ushort_t* y_bf = (ushort_t*)(bufF + 524288);        //  8M us (4M f)
  ushort_t* wbf  = (ushort_t*)(bufF + 524288 + 4194304);
  float* scrP = bufE;
  float* scrL = bufE + 2097152;

  // bf16 weight pool offsets (ushort units)
  ushort_t* wIN  = wbf;                 // 2 x 2048 x 512   = 2,097,152
  ushort_t* wOUT = wbf + 2097152;       // 2 x 512 x 1024   = 1,048,576
  ushort_t* wQKV = wbf + 3145728;       // 2 x 1536 x 512   = 1,572,864
  ushort_t* wOW  = wbf + 4718592;       // 2 x 512 x 512    =   524,288
  ushort_t* wL1  = wbf + 5242880;       // 2 x 2048 x 512   = 2,097,152
  ushort_t* wL2  = wbf + 7340032;       // 2 x 512 x 2048   = 2,097,152
  ushort_t* wXP  = wbf + 9437184;       // 2 x 64 x 1024    =   131,072
  ushort_t* wDT  = wbf + 9568256;       // 2 x 1024 x 32    =    65,536
  ushort_t* xdb_bf = wbf + 9633792;     // 8192 x 64        =   524,288

  // single-launch weight conversion (8 segments)
  Cvt8Args ca;
  ca.s[0] = m_in_w;    ca.d[0] = wIN;  
  ca.s[1] = m_out_w;   ca.d[1] = wOUT;
  ca.s[2] = t_qkv_w;   ca.d[2] = wQKV;
  ca.s[3] = t_ow;      ca.d[3] = wOW;
  ca.s[4] = t_l1w;     ca.d[4] = wL1;
  ca.s[5] = t_l2w;     ca.d[5] = wL2;
  ca.s[6] = m_xproj_w; ca.d[6] = wXP;
  ca.s[7] = m_dt_w;    ca.d[7] = wDT;
  ca.end[0] = 2048; ca.end[1] = 3072; ca.end[2] = 4608; ca.end[3] = 5120;
  ca.end[4] = 7168; ca.end[5] = 9216; ca.end[6] = 9344; ca.end[7] = 9408;
  cvt8<<<9408, 256, 0, stream>>>(ca);

  proj_kernel<<<16384, 256, 0, stream>>>(x, proj_w, proj_b, h, h_bf);

  for (int i = 0; i < 2; ++i) {
    // xz = h @ in_w^T   (8192 x 2048, K=512) -> bf16
    gemm_gll<0, 1, 1, 128><<<dim3(16, 64), 256, 0, stream>>>(
        h_bf, wIN + (size_t)i * 1048576, nullptr, bufA, DMODEL, DMODEL, 2 * DINNER);
    // xc = silu(causal_conv(xm)) -> bf16
    conv_silu_kernel<<<32768, 256, 0, stream>>>((const ushort_t*)bufA,
                                                m_conv_w + i * DINNER * 4,
                                                m_conv_b + i * DINNER, (ushort_t*)bufB);
    // xdb = xc @ xp_w^T  (8192 x 64, K=1024), MFMA split-K=8 -> partials bufC
    gemm_gll<0, 0, 8, 64><<<dim3(1, 64, 8), 256, 0, stream>>>(
        (const ushort_t*)bufB, wXP + (size_t)i * 65536, nullptr, bufC,
        DINNER, DINNER, 64);
    reduce8_xdb<<<512, 256, 0, stream>>>(bufC, bufF, xdb_bf);
    // dt = softplus(xdb[:, :32] @ dt_w^T + dt_b), MFMA K=32 -> bufC bf16
    gemm_gll<2, 1, 1, 128><<<dim3(8, 64), 256, 0, stream>>>(
        xdb_bf, wDT + (size_t)i * 32768, m_dt_b + i * DINNER, bufC,
        DTRANK, 64, DINNER);
    // chunked selective scan (state-split x4) -> y_bf (bf16)
    scan_pass1<<<2048, 256, 0, stream>>>((const ushort_t*)bufC, bufF, (const ushort_t*)bufB,
                                         m_Alog + (size_t)i * DINNER * DSTATE, scrP, scrL);
    scan_pass2<<<512, 256, 0, stream>>>(scrP, scrL);
    scan_pass3<<<2048, 256, 0, stream>>>((const ushort_t*)bufC, bufF, (const ushort_t*)bufB,
                                         (const ushort_t*)bufA, y_bf,
                                         m_Alog + (size_t)i * DINNER * DSTATE,
                                         m_D + i * DINNER, scrL);
    // mamba_out = y @ out_w^T  (8192 x 512, K=1024), split-K=2 -> partials bufC
    gemm_gll<0, 0, 2, 128><<<dim3(4, 64, 2), 256, 0, stream>>>(
        y_bf, wOUT + (size_t)i * 524288, nullptr, bufC, DINNER, DINNER, DMODEL);
    // h = LN(h + p0 + p1), refresh h_bf (fused reduce)
    resid_ln_sk<<<8192, 128, 0, stream>>>(h, bufC, nullptr, m_ln_w + i * DMODEL,
                                          m_ln_b + i * DMODEL, h, h_bf);
  }

  posenc_kernel<<<16384, 256, 0, stream>>>(h, h_bf);

  for (int i = 0; i < 2; ++i) {
    // qkv = h @ qkv_w^T + qkv_b  (8192 x 1536, K=512) -> bf16
    gemm_gll<0, 1, 1, 128><<<dim3(12, 64), 256, 0, stream>>>(
        h_bf, wQKV + (size_t)i * 786432, t_qkv_b + i * 3 * DMODEL, bufA,
        DMODEL, DMODEL, 3 * DMODEL);
    // MFMA flash attention (XCD-swizzled, QBLK=64) -> ao bf16
    attn_mfma<<<1024, 256, 0, stream>>>((const ushort_t*)bufA, (ushort_t*)bufB);
    // attn_proj = ao @ ow^T  (8192 x 512, K=512), split-K=2 -> partials bufC
    gemm_gll<0, 0, 2, 128><<<dim3(4, 64, 2), 256, 0, stream>>>(
        (const ushort_t*)bufB, wOW + (size_t)i * 262144, nullptr, bufC,
        DMODEL, DMODEL, DMODEL);
    resid_ln_sk<<<8192, 128, 0, stream>>>(h, bufC, t_ob + i * DMODEL,
                                          t_ln1w + i * DMODEL, t_ln1b + i * DMODEL, h, h_bf);
    // ff1 = relu(h @ l1w^T + l1b)  (8192 x 2048, K=512) -> bf16
    gemm_gll<1, 1, 1, 128><<<dim3(16, 64), 256, 0, stream>>>(
        h_bf, wL1 + (size_t)i * 1048576, t_l1b + i * DFF, bufA,
        DMODEL, DMODEL, DFF);
    // ff2 = ff1 @ l2w^T  (8192 x 512, K=2048), split-K=2 -> partials bufC
    gemm_gll<0, 0, 2, 128><<<dim3(4, 64, 2), 256, 0, stream>>>(
        (const ushort_t*)bufA, wL2 + (size_t)i * 1048576, nullptr, bufC,
        DFF, DFF, DMODEL);
    resid_ln_sk<<<8192, 128, 0, stream>>>(h, bufC, t_l2b + i * DMODEL,
                                          t_ln2w + i * DMODEL, t_ln2b + i * DMODEL, h, h_bf);
  }

  // final LN -> d_out, then mean over L -> d_out tail
  float* out_h = (float*)d_out;
  resid_ln_kernel<<<8192, 128, 0, stream>>>(h, nullptr, no_w, no_b, out_h, nullptr);
  mean_part<<<128, 512, 0, stream>>>(out_h, bufF);
  mean_final<<<16, 256, 0, stream>>>(bufF, out_h + 4194304);
}